// Round 8
// baseline (1020.966 us; speedup 1.0000x reference)
//
#include <hip/hip_runtime.h>
#include <hip/hip_bf16.h>
#include <stdint.h>

typedef __hip_bfloat16 bf16;
typedef __attribute__((ext_vector_type(8))) short short8;
typedef __attribute__((ext_vector_type(4))) float f32x4;
typedef __attribute__((ext_vector_type(16))) float f32x16;
typedef __attribute__((ext_vector_type(8))) _Float16 half8;

__device__ __forceinline__ float bf2f(bf16 x){ return __bfloat162float(x); }
__device__ __forceinline__ bf16  f2bf(float x){ return __float2bfloat16(x); }
__device__ __forceinline__ short f2bfs(float x){ union { bf16 h; short s; } u; u.h = f2bf(x); return u.s; }
__device__ __forceinline__ float bfs2f(short s){ union { bf16 h; short t; } u; u.t = s; return bf2f(u.h); }

// R18: occupancy fixes.
//  - conv34: LDS 79872->53248 (EB1 overlays dead DB0|DB1 region, staged one phase
//    later) -> 3 blocks/CU via __launch_bounds__(256,3). Occupancy 22%->~33%.
//  - mlp: B-fragments read DIRECT from global (L2-hot 90KB) instead of 90KB LDS
//    stage -> LDS 158KB->70KB -> 2 blocks/CU.
// Batched layout (ws >= ~202MB): dT[4]@0x0 (16MiB slots, fmap32 overlays),
//   e1T[4]@0x4000000 (32MiB slots), weights@0xC000000.
// Fallback layout: dT/fmap@0x0, e1T@0x1000000, weights@0x3000000.
// Weight region (relative): wb1|wb2|wb3|wb4|wfmlp|zpage  (= 0xB0000 total)
#define WB1_R   0UL                          // 2*9*4*64*8*2   = 73728
#define WB2_R   73728UL                      // 4*9*8*64*8*2   = 294912
#define WB3_R   368640UL                     // 6*9*4*64*8*2   = 221184
#define WB4_R   589824UL                     // 4*9*64*8*2     = 36864
#define WMLP_R  626688UL                     // 45056 u16      = 90112
#define WZERO_R 716800UL                     // 4096 B zeros -> ends 720896 = 0xB0000
#define DT_BS   8388608UL                    // bf16 elems per batch slot (16 MiB)
#define E1_BS   16777216UL                   // bf16 elems per batch slot (32 MiB)
#define OUT_BS  786432UL                     // f32 elems per batch (3*512*512)

__global__ void zero_kernel(float* __restrict__ p){
  p[blockIdx.x*256 + threadIdx.x] = 0.f;
}

// ---------------- conv1 B-frags: OIHW f32 -> bf16 hi/lo per-lane MFMA layout ----------------
__global__ void wb1_kernel(const float* __restrict__ uk1, short* __restrict__ wb1){
  int idx = blockIdx.x*256 + threadIdx.x;
  if (idx >= 36864) return;
  int j = idx & 7, lane = (idx >> 3) & 63, n = (idx >> 9) & 3, ch = idx >> 11; // ch=hl*9+t
  int t = ch % 9, hl = ch / 9;
  int co = n*16 + (lane & 15);
  int ci = (lane >> 4)*8 + j;
  float val = (ci < 29) ? uk1[(co*29 + ci)*9 + t] : 0.f;
  short hi = f2bfs(val);
  wb1[idx] = hl ? f2bfs(val - bfs2f(hi)) : hi;
}

// ---------------- conv2 B-frags: OIHW f32 -> bf16 hi/lo per-lane MFMA layout ----------
__global__ void wb2_kernel(const float* __restrict__ uk2, short* __restrict__ wb2){
  int idx = blockIdx.x*256 + threadIdx.x;
  if (idx >= 147456) return;
  int j    = idx & 7;
  int lane = (idx >> 3) & 63;
  int n    = (idx >> 9) & 7;
  int kt   = idx >> 12;            // kk*9 + t, 0..35
  int t = kt % 9, kk = kt / 9;
  int co = n*16 + (lane & 15);
  int ci = (kk & 1)*32 + (lane >> 4)*8 + j;
  float val = uk2[(co*64 + ci)*9 + t];
  short hi = f2bfs(val);
  wb2[idx] = (kk < 2) ? hi : f2bfs(val - bfs2f(hi));
}

// ---------------- conv3 B-frags: OIHW f32 -> per-lane MFMA layout bf16 ----------------
__global__ void wb3_kernel(const float* __restrict__ uk3, short* __restrict__ wb3){
  int idx = blockIdx.x*256 + threadIdx.x;
  if (idx >= 110592) return;
  int j    = idx & 7;
  int lane = (idx >> 3) & 63;
  int n0   = (idx >> 9) & 3;
  int kt   = idx >> 11;            // kc*9 + t
  int t = kt % 9, kc = kt / 9;
  int co = n0*16 + (lane & 15);
  int ci = kc*32 + (lane >> 4)*8 + j;
  wb3[idx] = f2bfs(uk3[(co*192 + ci)*9 + t]);
}

// ---------------- conv4 B-frags: OIHW f32 -> bf16 hi/lo per-lane MFMA layout ----------------
__global__ void wb4_kernel(const float* __restrict__ uk4, short* __restrict__ wb4){
  int idx = blockIdx.x*256 + threadIdx.x;
  if (idx >= 18432) return;
  int j = idx & 7, lane = (idx >> 3) & 63, rt = idx >> 9;   // rt = (hl*2+kc)*9+t
  int t = rt % 9, r = rt / 9;
  int kc = r & 1, hl = r >> 1;
  int co = lane & 15;
  int ci = kc*32 + (lane >> 4)*8 + j;
  float val = (co < 3) ? uk4[(co*64 + ci)*9 + t] : 0.f;
  short hi = f2bfs(val);
  wb4[idx] = hl ? f2bfs(val - bfs2f(hi)) : hi;
}

// ---------------- MLP weight frag prep: f32 -> f16 hi/lo per-lane MFMA B-fragments ----------
__global__ void mlp_frag_kernel(const float* __restrict__ w0, const float* __restrict__ w1,
                                const float* __restrict__ w2, unsigned short* __restrict__ wf){
  int idx = blockIdx.x*256 + threadIdx.x;
  if (idx >= 45056) return;
  int j = idx & 7;
  int chunk = idx >> 3;
  int lane = chunk & 63;
  int hi5 = lane >> 5, l31 = lane & 31;
  int rest = chunk >> 6;
  float val; int hl;
  if (rest < 8){
    hl = rest & 1; int n = rest >> 1;
    int k = hi5*8 + j, co = n*32 + l31;
    val = (k < 6) ? w0[k*128 + co] : 0.f;
  } else if (rest < 72){
    int r = rest - 8; hl = r & 1; int n = (r>>1)&3, ks = r>>3;
    int k = ks*16 + hi5*8 + j, co = n*32 + l31;
    val = w1[k*128 + co];
  } else {
    int r = rest - 72; hl = r & 1; int ks = r>>1;
    int k = ks*16 + hi5*8 + j, co = l31;
    val = w2[k*32 + co];
  }
  _Float16 h = (_Float16)val;
  _Float16 o = hl ? (_Float16)(val - (float)h) : h;
  union { _Float16 f; unsigned short u; } cv; cv.f = o;
  wf[idx] = cv.u;
}

// ---------------- per-pixel MLP on MFMA: 6 -> 128 -> 128 -> 32 (fmap NHWC-32) ----------------
// B-fragments read directly from global wf (L2-hot, 90KB); LDS = hbuf only -> 2 blocks/CU.
__global__ __launch_bounds__(256,2) void mlp_mfma(
    const float* __restrict__ zbuf, const float* __restrict__ ray,
    const unsigned short* __restrict__ wf,
    bf16* __restrict__ fmap, float* __restrict__ outrgb,
    size_t fmap_bs, size_t out_bs){
  __shared__ __align__(16) float hbuf[4][32][140];     // 71680 B
  const int tid = threadIdx.x;
  const int wv = tid >> 6, lane = tid & 63, h5 = lane >> 5, l31 = lane & 31;
  const int mbase = (blockIdx.x*4 + wv)*32;
  const int bz = mbase >> 18;
  const int prel = mbase & 262143;

  const float* rp = ray + (size_t)(mbase + l31)*7;
  float z  = zbuf[mbase + l31];
  float d0 = rp[3], d1 = rp[4], d2 = rp[5];
  float inv = z / rp[6];
  half8 a1h = {}; half8 a1l = {};
  if (h5 == 0){
    float f[6] = { rp[0]+d0*inv, rp[1]+d1*inv, rp[2]+d2*inv, d0, d1, d2 };
    #pragma unroll
    for (int j = 0; j < 6; ++j){
      _Float16 hi = (_Float16)f[j];
      a1h[j] = hi;
      a1l[j] = (_Float16)(f[j] - (float)hi);
    }
  }
  hbuf[wv][l31][137] = z;

  // ---- layer 1
  f32x16 acc[4];
  #pragma unroll
  for (int n = 0; n < 4; ++n){
    half8 bh = *(const half8*)&wf[((n*2+0)*64 + lane)*8];
    half8 bl = *(const half8*)&wf[((n*2+1)*64 + lane)*8];
    f32x16 a = {};
    a = __builtin_amdgcn_mfma_f32_32x32x16_f16(a1h, bh, a, 0, 0, 0);
    a = __builtin_amdgcn_mfma_f32_32x32x16_f16(a1l, bh, a, 0, 0, 0);
    a = __builtin_amdgcn_mfma_f32_32x32x16_f16(a1h, bl, a, 0, 0, 0);
    acc[n] = a;
  }
  #pragma unroll
  for (int n = 0; n < 4; ++n)
    #pragma unroll
    for (int reg = 0; reg < 16; ++reg)
      hbuf[wv][(reg&3) + 8*(reg>>2) + 4*h5][n*32 + l31] = fmaxf(acc[n][reg], 0.f);

  // ---- layer 2
  f32x16 acc2[4];
  #pragma unroll
  for (int n = 0; n < 4; ++n) acc2[n] = (f32x16){};
  #pragma unroll
  for (int ks = 0; ks < 8; ++ks){
    const float4* hp = (const float4*)&hbuf[wv][l31][ks*16 + h5*8];
    float4 v0 = hp[0], v1 = hp[1];
    float hv[8] = { v0.x, v0.y, v0.z, v0.w, v1.x, v1.y, v1.z, v1.w };
    half8 ah, al;
    #pragma unroll
    for (int j = 0; j < 8; ++j){
      _Float16 hi = (_Float16)hv[j];
      ah[j] = hi;
      al[j] = (_Float16)(hv[j] - (float)hi);
    }
    #pragma unroll
    for (int n = 0; n < 4; ++n){
      half8 bh = *(const half8*)&wf[(512 + ((ks*4+n)*2+0)*64 + lane)*8];
      half8 bl = *(const half8*)&wf[(512 + ((ks*4+n)*2+1)*64 + lane)*8];
      acc2[n] = __builtin_amdgcn_mfma_f32_32x32x16_f16(ah, bh, acc2[n], 0, 0, 0);
      acc2[n] = __builtin_amdgcn_mfma_f32_32x32x16_f16(al, bh, acc2[n], 0, 0, 0);
      acc2[n] = __builtin_amdgcn_mfma_f32_32x32x16_f16(ah, bl, acc2[n], 0, 0, 0);
    }
  }
  #pragma unroll
  for (int n = 0; n < 4; ++n)
    #pragma unroll
    for (int reg = 0; reg < 16; ++reg)
      hbuf[wv][(reg&3) + 8*(reg>>2) + 4*h5][n*32 + l31] = fmaxf(acc2[n][reg], 0.f);

  // ---- layer 3
  f32x16 a3 = {};
  #pragma unroll
  for (int ks = 0; ks < 8; ++ks){
    const float4* hp = (const float4*)&hbuf[wv][l31][ks*16 + h5*8];
    float4 v0 = hp[0], v1 = hp[1];
    float hv[8] = { v0.x, v0.y, v0.z, v0.w, v1.x, v1.y, v1.z, v1.w };
    half8 ah, al;
    #pragma unroll
    for (int j = 0; j < 8; ++j){
      _Float16 hi = (_Float16)hv[j];
      ah[j] = hi;
      al[j] = (_Float16)(hv[j] - (float)hi);
    }
    half8 bh = *(const half8*)&wf[(4608 + (ks*2+0)*64 + lane)*8];
    half8 bl = *(const half8*)&wf[(4608 + (ks*2+1)*64 + lane)*8];
    a3 = __builtin_amdgcn_mfma_f32_32x32x16_f16(ah, bh, a3, 0, 0, 0);
    a3 = __builtin_amdgcn_mfma_f32_32x32x16_f16(al, bh, a3, 0, 0, 0);
    a3 = __builtin_amdgcn_mfma_f32_32x32x16_f16(ah, bl, a3, 0, 0, 0);
  }

  // ---- store: fmap NHWC-32 (c29..31 zero-padded), rgb residual to out
  bf16* fb = fmap + (size_t)bz*fmap_bs;
  float* ob = outrgb + (size_t)bz*out_bs;
  const int c = l31;
  #pragma unroll
  for (int g = 0; g < 4; ++g){
    const int r0 = 8*g + 4*h5;
    float vs[4];
    #pragma unroll
    for (int k = 0; k < 4; ++k){
      float zz = hbuf[wv][r0 + k][137];
      vs[k] = (zz > 0.f) ? a3[g*4 + k] : 1.0f;
    }
    const size_t p = (size_t)(prel + r0);
    if (c < 29){
      #pragma unroll
      for (int k = 0; k < 4; ++k)
        fb[(p + k)*32 + c] = f2bf(vs[k]);         // half-wave writes a full 64B line
    } else {
      float4 fv = { vs[0], vs[1], vs[2], vs[3] };
      *(float4*)(&ob[((size_t)(c - 29) << 18) + p]) = fv;
      #pragma unroll
      for (int k = 0; k < 4; ++k)
        fb[(p + k)*32 + c] = f2bf(0.f);           // K-pad channels
    }
  }
}

// ---------------- conv1 (MFMA): fmap NHWC-32 -> e1T NHWC-64, 3x3 pad1, relu ----------------
__global__ __launch_bounds__(256,2) void conv1_mfma(
    const bf16* __restrict__ fmap32, const short8* __restrict__ wb1,
    bf16* __restrict__ e1T, const float* __restrict__ zpage,
    size_t fmap_bs, size_t e1_bs){
  __shared__ short lds[8192];   // 16384 B (tin 5760 shorts; out-stage 8192)
  const int tid = threadIdx.x;
  const int wv = tid >> 6, lane = tid & 63;
  const int quad = lane >> 4, l15 = lane & 15;

  // bijective XCD swizzle (gridDim.x % 8 == 0: 8192 or 2048)
  const int L = blockIdx.x;
  const int cpx = gridDim.x >> 3;
  const int o = (L & 7)*cpx + (L >> 3);
  const int bx = o & 31;
  const int r2 = o >> 5;
  const int by = r2 & 63;
  const int bz = r2 >> 6;

  const bf16* fb = fmap32 + (size_t)bz*fmap_bs;
  bf16* eb = e1T + (size_t)bz*e1_bs;
  const int oy0 = by*8, ox0 = bx*16;

  // ---- stage tin: 720 x 16B async loads (10 rows x 18 cols x 4 ch-groups)
  for (int r = 0; r < 3; ++r){
    const int d = r*256 + tid;
    const int pairI = d >> 3, slot = d & 7;
    const int sel = slot ^ (pairI & 7);
    const int p = pairI*2 + (sel >> 2);
    const int g = sel & 3;
    const int row = p / 18, col = p - row*18;
    const int gy = oy0 - 1 + row, gx = ox0 - 1 + col;
    const bool ok = (d < 720) && ((unsigned)gy < 512u) && ((unsigned)gx < 512u);
    const void* src = ok
      ? (const void*)&fb[((size_t)((gy<<9) + gx))*32 + g*8]
      : (const void*)zpage;
    __builtin_amdgcn_global_load_lds(
      (const __attribute__((address_space(1))) void*)src,
      (__attribute__((address_space(3))) void*)&lds[d*8],
      16, 0, 0);
  }
  __syncthreads();

  // ---- MFMA: wave wv owns out rows {wv*2, wv*2+1}; 4 co-tiles
  f32x4 acc[2][4];
  #pragma unroll
  for (int i=0;i<2;++i)
    #pragma unroll
    for (int n=0;n<4;++n) acc[i][n] = (f32x4){0.f,0.f,0.f,0.f};

  for (int t = 0; t < 9; ++t){
    const short8* bp = wb1 + ((0*9 + t)*4)*64 + lane;
    const short8* bq = wb1 + ((1*9 + t)*4)*64 + lane;
    short8 bh0 = bp[0], bh1 = bp[64], bh2 = bp[128], bh3 = bp[192];
    short8 bl0 = bq[0], bl1 = bq[64], bl2 = bq[128], bl3 = bq[192];
    const int dy = t/3, dx = t - dy*3;
    #pragma unroll
    for (int i = 0; i < 2; ++i){
      const int py = wv*2 + i + dy;
      const int px = l15 + dx;
      const int p = py*18 + px;
      const int slot = (quad + 4*(p & 1)) ^ ((p >> 1) & 7);
      short8 a = *(const short8*)&lds[((p >> 1)*8 + slot)*8];
      acc[i][0] = __builtin_amdgcn_mfma_f32_16x16x32_bf16(a, bh0, acc[i][0], 0, 0, 0);
      acc[i][1] = __builtin_amdgcn_mfma_f32_16x16x32_bf16(a, bh1, acc[i][1], 0, 0, 0);
      acc[i][2] = __builtin_amdgcn_mfma_f32_16x16x32_bf16(a, bh2, acc[i][2], 0, 0, 0);
      acc[i][3] = __builtin_amdgcn_mfma_f32_16x16x32_bf16(a, bh3, acc[i][3], 0, 0, 0);
      acc[i][0] = __builtin_amdgcn_mfma_f32_16x16x32_bf16(a, bl0, acc[i][0], 0, 0, 0);
      acc[i][1] = __builtin_amdgcn_mfma_f32_16x16x32_bf16(a, bl1, acc[i][1], 0, 0, 0);
      acc[i][2] = __builtin_amdgcn_mfma_f32_16x16x32_bf16(a, bl2, acc[i][2], 0, 0, 0);
      acc[i][3] = __builtin_amdgcn_mfma_f32_16x16x32_bf16(a, bl3, acc[i][3], 0, 0, 0);
    }
  }
  __syncthreads();   // tin dead -> out staging

  // ---- epilogue: relu -> bf16, swizzled LDS out [128px][8slot][8ch]
  #pragma unroll
  for (int i = 0; i < 2; ++i){
    const int rowp = wv*2 + i;
    #pragma unroll
    for (int n = 0; n < 4; ++n){
      const int gq = n*2 + (l15 >> 3);
      #pragma unroll
      for (int reg = 0; reg < 4; ++reg){
        const int px = rowp*16 + quad*4 + reg;
        const int slot = gq ^ (px & 7);
        lds[(px*8 + slot)*8 + (l15 & 7)] = f2bfs(fmaxf(acc[i][n][reg], 0.f));
      }
    }
  }
  __syncthreads();
  // ---- coalesced NHWC stores: 4 x short8 per thread
  #pragma unroll
  for (int w = 0; w < 4; ++w){
    const int s = w*256 + tid;
    const int px = s >> 3, g8 = s & 7;
    const int slot = g8 ^ (px & 7);
    short8 v = *(const short8*)&lds[(px*8 + slot)*8];
    const int gy = oy0 + (px >> 4), gx = ox0 + (px & 15);
    *(short8*)((void*)&eb[((size_t)((gy<<9) + gx))*64 + g8*8]) = v;
  }
}

// ---------------- conv2 (MFMA): e1T NHWC -> dT NHWC, 3x3 stride2 SAME (pad_lo=0), relu ----------
__global__ __launch_bounds__(256,2) void conv2_mfma(
    const bf16* __restrict__ e1T, const short8* __restrict__ wb2,
    bf16* __restrict__ dT, const float* __restrict__ zpage,
    size_t e1_bs, size_t dt_bs){
  __shared__ short lds[36864];   // 73728 B
  const int tid = threadIdx.x;
  const int wv = tid >> 6, lane = tid & 63;
  const int quad = lane >> 4, l15 = lane & 15;

  const int L = blockIdx.x;
  const int cpx = gridDim.x >> 3;
  const int o = (L & 7)*cpx + (L >> 3);
  const int bx = o & 15;
  const int r2 = o >> 4;
  const int by = r2 & 31;
  const int bz = r2 >> 5;

  const bf16* eb = e1T + (size_t)bz*e1_bs;
  bf16* db = dT + (size_t)bz*dt_bs;
  const int oy0 = by*8, ox0 = bx*16;
  const int iy0 = oy0*2, ix0 = ox0*2;

  for (int r = 0; r < 18; ++r){
    const int idx = r*256 + tid;
    const int g = idx & 7, p = idx >> 3;
    const int row = p / 33, col = p - row*33;
    const int gy = iy0 + row, gx = ix0 + col;
    const int gs = g ^ ((col >> 1) & 7);
    const bool ok = (p < 561) && (gy < 512) && (gx < 512);
    const void* src = ok
      ? (const void*)&eb[((size_t)((gy<<9) + gx))*64 + gs*8]
      : (const void*)zpage;
    __builtin_amdgcn_global_load_lds(
      (const __attribute__((address_space(1))) void*)src,
      (__attribute__((address_space(3))) void*)&lds[idx*8],
      16, 0, 0);
  }
  __syncthreads();

  f32x4 acc[2][8];
  #pragma unroll
  for (int i=0;i<2;++i)
    #pragma unroll
    for (int n=0;n<8;++n) acc[i][n] = (f32x4){0.f,0.f,0.f,0.f};

  for (int ks = 0; ks < 4; ++ks){
    const int cg = (ks & 1)*4 + quad;
    for (int t = 0; t < 9; ++t){
      const short8* bp = wb2 + ((ks*9 + t)*8)*64 + lane;
      short8 b0 = bp[0],   b1 = bp[64],  b2 = bp[128], b3 = bp[192];
      short8 b4 = bp[256], b5 = bp[320], b6 = bp[384], b7 = bp[448];
      const int dy = t/3, dx = t - dy*3;
      #pragma unroll
      for (int i = 0; i < 2; ++i){
        const int m = wv*2 + i;
        const int py = 2*m + dy;
        const int px = 2*l15 + dx;
        const int slot = cg ^ ((px >> 1) & 7);
        short8 a = *(const short8*)&lds[((py*33 + px)*8 + slot)*8];
        acc[i][0] = __builtin_amdgcn_mfma_f32_16x16x32_bf16(a, b0, acc[i][0], 0, 0, 0);
        acc[i][1] = __builtin_amdgcn_mfma_f32_16x16x32_bf16(a, b1, acc[i][1], 0, 0, 0);
        acc[i][2] = __builtin_amdgcn_mfma_f32_16x16x32_bf16(a, b2, acc[i][2], 0, 0, 0);
        acc[i][3] = __builtin_amdgcn_mfma_f32_16x16x32_bf16(a, b3, acc[i][3], 0, 0, 0);
        acc[i][4] = __builtin_amdgcn_mfma_f32_16x16x32_bf16(a, b4, acc[i][4], 0, 0, 0);
        acc[i][5] = __builtin_amdgcn_mfma_f32_16x16x32_bf16(a, b5, acc[i][5], 0, 0, 0);
        acc[i][6] = __builtin_amdgcn_mfma_f32_16x16x32_bf16(a, b6, acc[i][6], 0, 0, 0);
        acc[i][7] = __builtin_amdgcn_mfma_f32_16x16x32_bf16(a, b7, acc[i][7], 0, 0, 0);
      }
    }
  }
  __syncthreads();

  #pragma unroll
  for (int i = 0; i < 2; ++i){
    const int m = wv*2 + i;
    #pragma unroll
    for (int n = 0; n < 8; ++n){
      #pragma unroll
      for (int reg = 0; reg < 4; ++reg){
        const int col = quad*4 + reg;
        const int px = m*16 + col;
        const int g16 = n*2 + (l15 >> 3);
        const int slot = g16 ^ (px & 15);
        lds[(px*16 + slot)*8 + (l15 & 7)] = f2bfs(fmaxf(acc[i][n][reg], 0.f));
      }
    }
  }
  __syncthreads();
  #pragma unroll
  for (int w = 0; w < 8; ++w){
    const int s = w*256 + tid;
    const int px = s >> 4, g16 = s & 15;
    const int slot = g16 ^ (px & 15);
    short8 v = *(const short8*)&lds[(px*16 + slot)*8];
    const int gy = oy0 + (px >> 4), gx = ox0 + (px & 15);
    *(short8*)((void*)&db[((size_t)((gy<<8) + gx))*128 + g16*8]) = v;
  }
}

// ---------------- conv3 + conv4, both MFMA; 53248B LDS -> 3 blocks/CU ----------------
// conv3: K = 192ch as 3 x 64-ch chunks (2 dT compact + 1 e1 m-space).
// EB1 overlays the dead DB0|DB1 region (exactly 13312 shorts), staged one phase later.
// conv4: MFMA over msh: M = out px (16 tiles), K = 64ch x 9t x hi/lo, N = 3 co (pad 16).
__global__ __launch_bounds__(256,3) void conv34_mfma(
    const bf16* __restrict__ dT, const bf16* __restrict__ e1T,
    const short8* __restrict__ wb3, const short8* __restrict__ wb4,
    float* __restrict__ out, const float* __restrict__ zpage,
    size_t dt_bs, size_t e1_bs, size_t out_bs){
  __shared__ short lds[26624];   // 53248 B
  const int tid = threadIdx.x;
  const int wv = tid >> 6, lane = tid & 63;
  const int quad = lane >> 4, l15 = lane & 15;

  const int L = blockIdx.x;
  const int cpx = gridDim.x >> 3;              // gridDim.x % 8 == 0 (4608 or 1152)
  const int o = (L & 7)*cpx + (L >> 3);
  const int bx = o % 18;
  const int rem = o / 18;
  const int by = rem & 63;
  const int bz = rem >> 6;

  const bf16* dTb = dT + (size_t)bz*dt_bs;
  const bf16* e1b = e1T + (size_t)bz*e1_bs;
  float* outb = out + (size_t)bz*out_bs;
  const int gy0 = by * 8;
  const int gx0 = bx * 30;
  const int dy0 = (gy0 >> 1) - 1;
  const int dx0 = (gx0 >> 1) - 1;
  f32x4 acc[5][4];
  #pragma unroll
  for (int i=0;i<5;++i)
    #pragma unroll
    for (int n=0;n<4;++n) acc[i][n] = (f32x4){0.f,0.f,0.f,0.f};

  short* DB0 = lds;            // 6656 shorts
  short* DB1 = lds + 6656;     // 6656 shorts
  short* EB0 = lds + 13312;    // 13312 shorts
  short* EB1 = lds;            // overlays DB0|DB1 (dead by then)

  auto stage_dT = [&](int c, short* db){
    #pragma unroll
    for (int r = 0; r < 4; ++r){
      const int idxb = r*256 + wv*64;
      if (idxb >= 832) continue;
      const int idx = idxb + lane;
      const int p = idx >> 3, g = idx & 7;
      const int prow = p / 17, pcol = p - prow*17;
      const int gyD = dy0 + prow, gxD = dx0 + pcol;
      const int gs = g ^ (pcol & 7);
      const bool ok = (p < 102) && ((unsigned)gyD < 256u) && ((unsigned)gxD < 256u);
      const void* src = ok
        ? (const void*)&dTb[((size_t)((gyD<<8) + gxD))*128 + c*64 + gs*8]
        : (const void*)zpage;
      __builtin_amdgcn_global_load_lds(
        (const __attribute__((address_space(1))) void*)src,
        (__attribute__((address_space(3))) void*)&db[idxb*8],
        16, 0, 0);
    }
  };

  auto stage_e1 = [&](int j, short* eb){
    #pragma unroll
    for (int r = 0; r < 7; ++r){
      const int idxb = r*256 + wv*64;
      if (idxb >= 1664) continue;
      const int idx = idxb + lane;
      const int pos = idx >> 2, cg = idx & 3;
      const int yy = pos / 34, xx = pos - yy*34;
      const int gy = gy0 - 2 + yy, gx = gx0 - 2 + xx;
      const int cs = cg ^ (xx & 3);
      const bool ok = ((unsigned)gy < 512u) && ((unsigned)gx < 512u) && (pos < 408);
      const int pyc = gy & 511, pxc = gx & 511;
      const void* src = ok
        ? (const void*)&e1b[((size_t)((pyc<<9) + pxc))*64 + j*32 + cs*8]
        : (const void*)zpage;
      __builtin_amdgcn_global_load_lds(
        (const __attribute__((address_space(1))) void*)src,
        (__attribute__((address_space(3))) void*)&eb[idxb*8],
        16, 0, 0);
    }
  };

  auto compute_D = [&](int c, const short* db){
    #pragma unroll
    for (int ks = 0; ks < 2; ++ks){
      const int kc = c*2 + ks;
      int bb = (kc*9*4)*64 + lane;
      short8 bc0 = wb3[bb], bc1 = wb3[bb+64], bc2 = wb3[bb+128], bc3 = wb3[bb+192];
      for (int t = 0; t < 9; ++t){
        short8 bn0, bn1, bn2, bn3;
        if (t < 8){
          const int b2 = bb + 256;
          bn0 = wb3[b2]; bn1 = wb3[b2+64]; bn2 = wb3[b2+128]; bn3 = wb3[b2+192];
        }
        const int dy = t/3, dx = t - dy*3;
        #pragma unroll
        for (int i = 0; i < 5; ++i){
          const int mt = wv*5 + i;
          const int r = mt >> 1, h = mt & 1;
          const int px = h*16 + l15 + dx;
          const int py = r + dy;
          const int p = (py >> 1)*17 + (px >> 1);
          const int g = (ks*4 + quad) ^ ((px >> 1) & 7);
          short8 a = *(const short8*)&db[p*64 + g*8];
          acc[i][0] = __builtin_amdgcn_mfma_f32_16x16x32_bf16(a, bc0, acc[i][0], 0, 0, 0);
          acc[i][1] = __builtin_amdgcn_mfma_f32_16x16x32_bf16(a, bc1, acc[i][1], 0, 0, 0);
          acc[i][2] = __builtin_amdgcn_mfma_f32_16x16x32_bf16(a, bc2, acc[i][2], 0, 0, 0);
          acc[i][3] = __builtin_amdgcn_mfma_f32_16x16x32_bf16(a, bc3, acc[i][3], 0, 0, 0);
        }
        if (t < 8){ bc0 = bn0; bc1 = bn1; bc2 = bn2; bc3 = bn3; bb += 256; }
      }
    }
  };

  auto compute_E = [&](int j, const short* tb){
    const int kc = 4 + j;
    int bb = (kc*9*4)*64 + lane;
    short8 bc0 = wb3[bb], bc1 = wb3[bb+64], bc2 = wb3[bb+128], bc3 = wb3[bb+192];
    for (int t = 0; t < 9; ++t){
      short8 bn0, bn1, bn2, bn3;
      if (t < 8){
        const int b2 = bb + 256;
        bn0 = wb3[b2]; bn1 = wb3[b2+64]; bn2 = wb3[b2+128]; bn3 = wb3[b2+192];
      }
      const int dy = t/3, dx = t - dy*3;
      #pragma unroll
      for (int i = 0; i < 5; ++i){
        const int mt = wv*5 + i;
        const int r = mt >> 1, h = mt & 1;
        const int px = h*16 + l15 + dx;
        const int py = r + dy;
        const int g = quad ^ (px & 3);
        short8 a = *(const short8*)&tb[(py*34 + px)*32 + g*8];
        acc[i][0] = __builtin_amdgcn_mfma_f32_16x16x32_bf16(a, bc0, acc[i][0], 0, 0, 0);
        acc[i][1] = __builtin_amdgcn_mfma_f32_16x16x32_bf16(a, bc1, acc[i][1], 0, 0, 0);
        acc[i][2] = __builtin_amdgcn_mfma_f32_16x16x32_bf16(a, bc2, acc[i][2], 0, 0, 0);
        acc[i][3] = __builtin_amdgcn_mfma_f32_16x16x32_bf16(a, bc3, acc[i][3], 0, 0, 0);
      }
      if (t < 8){ bc0 = bn0; bc1 = bn1; bc2 = bn2; bc3 = bn3; bb += 256; }
    }
  };

  stage_dT(0, DB0);
  __syncthreads();                              // D0 ready

  stage_dT(1, DB1);                             // prefetch D1
  __builtin_amdgcn_sched_barrier(0);
  compute_D(0, DB0);
  __syncthreads();                              // D1 ready

  stage_e1(0, EB0);                             // prefetch E0
  __builtin_amdgcn_sched_barrier(0);
  compute_D(1, DB1);
  __syncthreads();                              // E0 ready; DB0/DB1 dead

  stage_e1(1, EB1);                             // prefetch E1 into dead DB region
  __builtin_amdgcn_sched_barrier(0);
  compute_E(0, EB0);
  __syncthreads();                              // E1 ready

  compute_E(1, EB1);

  __syncthreads();   // staging dead -> msh[10][32][64] (swizzled groups)
  // conv3 epilogue: relu + border-zero, write msh
  #pragma unroll
  for (int i = 0; i < 5; ++i){
    const int mt = wv*5 + i;
    const int r = mt >> 1, h = mt & 1;
    const int gym = gy0 - 1 + r;
    #pragma unroll
    for (int reg = 0; reg < 4; ++reg){
      const int mxd = h*16 + quad*4 + reg;
      const int gxm = gx0 - 1 + mxd;
      const bool inim = ((unsigned)gym < 512u) && ((unsigned)gxm < 512u);
      const int key = (mxd & 7) << 3;
      #pragma unroll
      for (int n = 0; n < 4; ++n){
        float v = inim ? fmaxf(acc[i][n][reg], 0.f) : 0.f;
        int c = n*16 + l15;
        lds[(r*32 + mxd)*64 + (c ^ key)] = f2bfs(v);
      }
    }
  }
  __syncthreads();

  // conv4 on MFMA: wave wv owns M-tiles {wv*4..wv*4+3} = (row ly, half h)
  f32x4 a4[4];
  #pragma unroll
  for (int ii = 0; ii < 4; ++ii) a4[ii] = (f32x4){0.f,0.f,0.f,0.f};
  for (int kc = 0; kc < 2; ++kc){
    for (int t = 0; t < 9; ++t){
      short8 bh = wb4[((kc*9) + t)*64 + lane];        // hl=0
      short8 bl = wb4[(((2 + kc)*9) + t)*64 + lane];  // hl=1
      const int dy = t/3, dx = t - dy*3;
      #pragma unroll
      for (int ii = 0; ii < 4; ++ii){
        const int mt4 = wv*4 + ii;
        const int ly = mt4 >> 1, h = mt4 & 1;
        const int r = ly + dy;                 // msh row 0..9
        const int mxd = h*16 + l15 + dx;       // cols >31 read stale LDS; rows masked at store
        const int sg = (kc*4 + quad) ^ (mxd & 7);
        short8 a = *(const short8*)&lds[(r*32 + mxd)*64 + sg*8];
        a4[ii] = __builtin_amdgcn_mfma_f32_16x16x32_bf16(a, bh, a4[ii], 0, 0, 0);
        a4[ii] = __builtin_amdgcn_mfma_f32_16x16x32_bf16(a, bl, a4[ii], 0, 0, 0);
      }
    }
  }
  // store: channel = l15 (0..2), rows = out x; residual already in out
  if (l15 < 3){
    #pragma unroll
    for (int ii = 0; ii < 4; ++ii){
      const int mt4 = wv*4 + ii;
      const int ly = mt4 >> 1, h = mt4 & 1;
      const int oy = gy0 + ly;
      float* op = outb + (((size_t)l15) << 18) + ((size_t)oy << 9);
      #pragma unroll
      for (int reg = 0; reg < 4; ++reg){
        const int lx = h*16 + quad*4 + reg;
        const int ox = gx0 + lx;
        if (lx < 30 && ox < 512)
          op[ox] += a4[ii][reg];
      }
    }
  }
}

static const void* find_by_size(void* const* d_in, const int* in_sizes, int n_in,
                                int want, int occurrence, int fallback_idx){
  int seen = 0;
  for (int i = 0; i < n_in; ++i){
    if (in_sizes[i] == want){
      if (seen == occurrence) return d_in[i];
      ++seen;
    }
  }
  return d_in[fallback_idx];
}

extern "C" void kernel_launch(void* const* d_in, const int* in_sizes, int n_in,
                              void* d_out, int out_size, void* d_ws, size_t ws_size,
                              hipStream_t stream) {
  const float* zbuf = (const float*)find_by_size(d_in, in_sizes, n_in, 1048576, 0, 0);
  const float* ray  = (const float*)find_by_size(d_in, in_sizes, n_in, 7340032, 0, 1);
  const float* w0   = (const float*)find_by_size(d_in, in_sizes, n_in, 768,     0, 4);
  const float* w1   = (const float*)find_by_size(d_in, in_sizes, n_in, 16384,   0, 6);
  const float* w2   = (const float*)find_by_size(d_in, in_sizes, n_in, 4096,    0, 8);
  const float* uk1  = (const float*)find_by_size(d_in, in_sizes, n_in, 16704,   0, 10);
  const float* uk2  = (const float*)find_by_size(d_in, in_sizes, n_in, 73728,   0, 11);
  const float* uk3  = (const float*)find_by_size(d_in, in_sizes, n_in, 110592,  0, 12);
  const float* uk4  = (const float*)find_by_size(d_in, in_sizes, n_in, 1728,    0, 13);

  uint8_t* ws = (uint8_t*)d_ws;
  const int batched = (ws_size >= 0xC000000UL + 0xB0000UL);
  const size_t dt_off = 0;
  const size_t e1_off = batched ? 0x4000000UL : 0x1000000UL;
  const size_t w_off  = batched ? 0xC000000UL : 0x3000000UL;

  bf16* fmapB = (bf16*)(ws + dt_off);      // fmap32 NHWC overlays dT slots
  bf16* dTB   = (bf16*)(ws + dt_off);
  bf16* e1B   = (bf16*)(ws + e1_off);
  short* wb1  = (short*)(ws + w_off + WB1_R);
  short* wb2  = (short*)(ws + w_off + WB2_R);
  short* wb3  = (short*)(ws + w_off + WB3_R);
  short* wb4  = (short*)(ws + w_off + WB4_R);
  unsigned short* wfmlp = (unsigned short*)(ws + w_off + WMLP_R);
  float* zp   = (float*)(ws + w_off + WZERO_R);
  float* outp = (float*)d_out;

  wb1_kernel<<<144, 256, 0, stream>>>(uk1, wb1);
  wb2_kernel<<<576, 256, 0, stream>>>(uk2, wb2);
  wb3_kernel<<<432, 256, 0, stream>>>(uk3, wb3);
  wb4_kernel<<<72, 256, 0, stream>>>(uk4, wb4);
  mlp_frag_kernel<<<176, 256, 0, stream>>>(w0, w1, w2, wfmlp);
  zero_kernel<<<4, 256, 0, stream>>>(zp);

  if (batched){
    mlp_mfma<<<8192, 256, 0, stream>>>(zbuf, ray, wfmlp, fmapB, outp, DT_BS, OUT_BS);
    conv1_mfma<<<8192, 256, 0, stream>>>(fmapB, (const short8*)wb1, e1B, zp, DT_BS, E1_BS);
    conv2_mfma<<<2048, 256, 0, stream>>>(e1B, (const short8*)wb2, dTB, zp, E1_BS, DT_BS);
    conv34_mfma<<<4608, 256, 0, stream>>>(dTB, e1B, (const short8*)wb3, (const short8*)wb4,
                                          outp, zp, DT_BS, E1_BS, OUT_BS);
  } else {
    for (int b = 0; b < 4; ++b){
      float* outb = outp + (size_t)b*OUT_BS;
      mlp_mfma<<<2048, 256, 0, stream>>>(zbuf + (size_t)b*262144,
                                         ray  + (size_t)b*262144*7,
                                         wfmlp, fmapB, outb, DT_BS, OUT_BS);
      conv1_mfma<<<2048, 256, 0, stream>>>(fmapB, (const short8*)wb1, e1B, zp, DT_BS, E1_BS);
      conv2_mfma<<<512, 256, 0, stream>>>(e1B, (const short8*)wb2, dTB, zp, E1_BS, DT_BS);
      conv34_mfma<<<1152, 256, 0, stream>>>(dTB, e1B, (const short8*)wb3, (const short8*)wb4,
                                            outb, zp, DT_BS, E1_BS, OUT_BS);
    }
  }
}

// Round 9
// 812.138 us; speedup vs baseline: 1.2571x; 1.2571x over previous
//
#include <hip/hip_runtime.h>
#include <hip/hip_bf16.h>
#include <stdint.h>

typedef __hip_bfloat16 bf16;
typedef __attribute__((ext_vector_type(8))) short short8;
typedef __attribute__((ext_vector_type(4))) float f32x4;
typedef __attribute__((ext_vector_type(16))) float f32x16;
typedef __attribute__((ext_vector_type(8))) _Float16 half8;

__device__ __forceinline__ float bf2f(bf16 x){ return __bfloat162float(x); }
__device__ __forceinline__ bf16  f2bf(float x){ return __float2bfloat16(x); }
__device__ __forceinline__ short f2bfs(float x){ union { bf16 h; short s; } u; u.h = f2bf(x); return u.s; }
__device__ __forceinline__ float bfs2f(short s){ union { bf16 h; short t; } u; u.t = s; return bf2f(u.h); }

// R19: fix R18's spill regression. launch_bounds(256,3) clamped conv34 to 84 VGPR
// -> accumulator spills -> 1.1GB scratch traffic (FETCH 562MB + WRITE 667MB).
// Revert to (256,2) [R17-proven 128 VGPR, no spill]; LDS stays 53248B so occupancy
// is LDS-capped at 3 blocks/CU. Keep R18's EB1-overlay schedule + mlp direct-global
// weights (non-conv34 time improved 567->487us).
// Batched layout (ws >= ~202MB): dT[4]@0x0 (16MiB slots, fmap32 overlays),
//   e1T[4]@0x4000000 (32MiB slots), weights@0xC000000.
// Fallback layout: dT/fmap@0x0, e1T@0x1000000, weights@0x3000000.
// Weight region (relative): wb1|wb2|wb3|wb4|wfmlp|zpage  (= 0xB0000 total)
#define WB1_R   0UL                          // 2*9*4*64*8*2   = 73728
#define WB2_R   73728UL                      // 4*9*8*64*8*2   = 294912
#define WB3_R   368640UL                     // 6*9*4*64*8*2   = 221184
#define WB4_R   589824UL                     // 4*9*64*8*2     = 36864
#define WMLP_R  626688UL                     // 45056 u16      = 90112
#define WZERO_R 716800UL                     // 4096 B zeros -> ends 720896 = 0xB0000
#define DT_BS   8388608UL                    // bf16 elems per batch slot (16 MiB)
#define E1_BS   16777216UL                   // bf16 elems per batch slot (32 MiB)
#define OUT_BS  786432UL                     // f32 elems per batch (3*512*512)

__global__ void zero_kernel(float* __restrict__ p){
  p[blockIdx.x*256 + threadIdx.x] = 0.f;
}

// ---------------- conv1 B-frags: OIHW f32 -> bf16 hi/lo per-lane MFMA layout ----------------
__global__ void wb1_kernel(const float* __restrict__ uk1, short* __restrict__ wb1){
  int idx = blockIdx.x*256 + threadIdx.x;
  if (idx >= 36864) return;
  int j = idx & 7, lane = (idx >> 3) & 63, n = (idx >> 9) & 3, ch = idx >> 11; // ch=hl*9+t
  int t = ch % 9, hl = ch / 9;
  int co = n*16 + (lane & 15);
  int ci = (lane >> 4)*8 + j;
  float val = (ci < 29) ? uk1[(co*29 + ci)*9 + t] : 0.f;
  short hi = f2bfs(val);
  wb1[idx] = hl ? f2bfs(val - bfs2f(hi)) : hi;
}

// ---------------- conv2 B-frags: OIHW f32 -> bf16 hi/lo per-lane MFMA layout ----------
__global__ void wb2_kernel(const float* __restrict__ uk2, short* __restrict__ wb2){
  int idx = blockIdx.x*256 + threadIdx.x;
  if (idx >= 147456) return;
  int j    = idx & 7;
  int lane = (idx >> 3) & 63;
  int n    = (idx >> 9) & 7;
  int kt   = idx >> 12;            // kk*9 + t, 0..35
  int t = kt % 9, kk = kt / 9;
  int co = n*16 + (lane & 15);
  int ci = (kk & 1)*32 + (lane >> 4)*8 + j;
  float val = uk2[(co*64 + ci)*9 + t];
  short hi = f2bfs(val);
  wb2[idx] = (kk < 2) ? hi : f2bfs(val - bfs2f(hi));
}

// ---------------- conv3 B-frags: OIHW f32 -> per-lane MFMA layout bf16 ----------------
__global__ void wb3_kernel(const float* __restrict__ uk3, short* __restrict__ wb3){
  int idx = blockIdx.x*256 + threadIdx.x;
  if (idx >= 110592) return;
  int j    = idx & 7;
  int lane = (idx >> 3) & 63;
  int n0   = (idx >> 9) & 3;
  int kt   = idx >> 11;            // kc*9 + t
  int t = kt % 9, kc = kt / 9;
  int co = n0*16 + (lane & 15);
  int ci = kc*32 + (lane >> 4)*8 + j;
  wb3[idx] = f2bfs(uk3[(co*192 + ci)*9 + t]);
}

// ---------------- conv4 B-frags: OIHW f32 -> bf16 hi/lo per-lane MFMA layout ----------------
__global__ void wb4_kernel(const float* __restrict__ uk4, short* __restrict__ wb4){
  int idx = blockIdx.x*256 + threadIdx.x;
  if (idx >= 18432) return;
  int j = idx & 7, lane = (idx >> 3) & 63, rt = idx >> 9;   // rt = (hl*2+kc)*9+t
  int t = rt % 9, r = rt / 9;
  int kc = r & 1, hl = r >> 1;
  int co = lane & 15;
  int ci = kc*32 + (lane >> 4)*8 + j;
  float val = (co < 3) ? uk4[(co*64 + ci)*9 + t] : 0.f;
  short hi = f2bfs(val);
  wb4[idx] = hl ? f2bfs(val - bfs2f(hi)) : hi;
}

// ---------------- MLP weight frag prep: f32 -> f16 hi/lo per-lane MFMA B-fragments ----------
__global__ void mlp_frag_kernel(const float* __restrict__ w0, const float* __restrict__ w1,
                                const float* __restrict__ w2, unsigned short* __restrict__ wf){
  int idx = blockIdx.x*256 + threadIdx.x;
  if (idx >= 45056) return;
  int j = idx & 7;
  int chunk = idx >> 3;
  int lane = chunk & 63;
  int hi5 = lane >> 5, l31 = lane & 31;
  int rest = chunk >> 6;
  float val; int hl;
  if (rest < 8){
    hl = rest & 1; int n = rest >> 1;
    int k = hi5*8 + j, co = n*32 + l31;
    val = (k < 6) ? w0[k*128 + co] : 0.f;
  } else if (rest < 72){
    int r = rest - 8; hl = r & 1; int n = (r>>1)&3, ks = r>>3;
    int k = ks*16 + hi5*8 + j, co = n*32 + l31;
    val = w1[k*128 + co];
  } else {
    int r = rest - 72; hl = r & 1; int ks = r>>1;
    int k = ks*16 + hi5*8 + j, co = l31;
    val = w2[k*32 + co];
  }
  _Float16 h = (_Float16)val;
  _Float16 o = hl ? (_Float16)(val - (float)h) : h;
  union { _Float16 f; unsigned short u; } cv; cv.f = o;
  wf[idx] = cv.u;
}

// ---------------- per-pixel MLP on MFMA: 6 -> 128 -> 128 -> 32 (fmap NHWC-32) ----------------
// B-fragments read directly from global wf (L2-hot, 90KB); LDS = hbuf only -> 2 blocks/CU.
__global__ __launch_bounds__(256,2) void mlp_mfma(
    const float* __restrict__ zbuf, const float* __restrict__ ray,
    const unsigned short* __restrict__ wf,
    bf16* __restrict__ fmap, float* __restrict__ outrgb,
    size_t fmap_bs, size_t out_bs){
  __shared__ __align__(16) float hbuf[4][32][140];     // 71680 B
  const int tid = threadIdx.x;
  const int wv = tid >> 6, lane = tid & 63, h5 = lane >> 5, l31 = lane & 31;
  const int mbase = (blockIdx.x*4 + wv)*32;
  const int bz = mbase >> 18;
  const int prel = mbase & 262143;

  const float* rp = ray + (size_t)(mbase + l31)*7;
  float z  = zbuf[mbase + l31];
  float d0 = rp[3], d1 = rp[4], d2 = rp[5];
  float inv = z / rp[6];
  half8 a1h = {}; half8 a1l = {};
  if (h5 == 0){
    float f[6] = { rp[0]+d0*inv, rp[1]+d1*inv, rp[2]+d2*inv, d0, d1, d2 };
    #pragma unroll
    for (int j = 0; j < 6; ++j){
      _Float16 hi = (_Float16)f[j];
      a1h[j] = hi;
      a1l[j] = (_Float16)(f[j] - (float)hi);
    }
  }
  hbuf[wv][l31][137] = z;

  // ---- layer 1
  f32x16 acc[4];
  #pragma unroll
  for (int n = 0; n < 4; ++n){
    half8 bh = *(const half8*)&wf[((n*2+0)*64 + lane)*8];
    half8 bl = *(const half8*)&wf[((n*2+1)*64 + lane)*8];
    f32x16 a = {};
    a = __builtin_amdgcn_mfma_f32_32x32x16_f16(a1h, bh, a, 0, 0, 0);
    a = __builtin_amdgcn_mfma_f32_32x32x16_f16(a1l, bh, a, 0, 0, 0);
    a = __builtin_amdgcn_mfma_f32_32x32x16_f16(a1h, bl, a, 0, 0, 0);
    acc[n] = a;
  }
  #pragma unroll
  for (int n = 0; n < 4; ++n)
    #pragma unroll
    for (int reg = 0; reg < 16; ++reg)
      hbuf[wv][(reg&3) + 8*(reg>>2) + 4*h5][n*32 + l31] = fmaxf(acc[n][reg], 0.f);

  // ---- layer 2
  f32x16 acc2[4];
  #pragma unroll
  for (int n = 0; n < 4; ++n) acc2[n] = (f32x16){};
  #pragma unroll
  for (int ks = 0; ks < 8; ++ks){
    const float4* hp = (const float4*)&hbuf[wv][l31][ks*16 + h5*8];
    float4 v0 = hp[0], v1 = hp[1];
    float hv[8] = { v0.x, v0.y, v0.z, v0.w, v1.x, v1.y, v1.z, v1.w };
    half8 ah, al;
    #pragma unroll
    for (int j = 0; j < 8; ++j){
      _Float16 hi = (_Float16)hv[j];
      ah[j] = hi;
      al[j] = (_Float16)(hv[j] - (float)hi);
    }
    #pragma unroll
    for (int n = 0; n < 4; ++n){
      half8 bh = *(const half8*)&wf[(512 + ((ks*4+n)*2+0)*64 + lane)*8];
      half8 bl = *(const half8*)&wf[(512 + ((ks*4+n)*2+1)*64 + lane)*8];
      acc2[n] = __builtin_amdgcn_mfma_f32_32x32x16_f16(ah, bh, acc2[n], 0, 0, 0);
      acc2[n] = __builtin_amdgcn_mfma_f32_32x32x16_f16(al, bh, acc2[n], 0, 0, 0);
      acc2[n] = __builtin_amdgcn_mfma_f32_32x32x16_f16(ah, bl, acc2[n], 0, 0, 0);
    }
  }
  #pragma unroll
  for (int n = 0; n < 4; ++n)
    #pragma unroll
    for (int reg = 0; reg < 16; ++reg)
      hbuf[wv][(reg&3) + 8*(reg>>2) + 4*h5][n*32 + l31] = fmaxf(acc2[n][reg], 0.f);

  // ---- layer 3
  f32x16 a3 = {};
  #pragma unroll
  for (int ks = 0; ks < 8; ++ks){
    const float4* hp = (const float4*)&hbuf[wv][l31][ks*16 + h5*8];
    float4 v0 = hp[0], v1 = hp[1];
    float hv[8] = { v0.x, v0.y, v0.z, v0.w, v1.x, v1.y, v1.z, v1.w };
    half8 ah, al;
    #pragma unroll
    for (int j = 0; j < 8; ++j){
      _Float16 hi = (_Float16)hv[j];
      ah[j] = hi;
      al[j] = (_Float16)(hv[j] - (float)hi);
    }
    half8 bh = *(const half8*)&wf[(4608 + (ks*2+0)*64 + lane)*8];
    half8 bl = *(const half8*)&wf[(4608 + (ks*2+1)*64 + lane)*8];
    a3 = __builtin_amdgcn_mfma_f32_32x32x16_f16(ah, bh, a3, 0, 0, 0);
    a3 = __builtin_amdgcn_mfma_f32_32x32x16_f16(al, bh, a3, 0, 0, 0);
    a3 = __builtin_amdgcn_mfma_f32_32x32x16_f16(ah, bl, a3, 0, 0, 0);
  }

  // ---- store: fmap NHWC-32 (c29..31 zero-padded), rgb residual to out
  bf16* fb = fmap + (size_t)bz*fmap_bs;
  float* ob = outrgb + (size_t)bz*out_bs;
  const int c = l31;
  #pragma unroll
  for (int g = 0; g < 4; ++g){
    const int r0 = 8*g + 4*h5;
    float vs[4];
    #pragma unroll
    for (int k = 0; k < 4; ++k){
      float zz = hbuf[wv][r0 + k][137];
      vs[k] = (zz > 0.f) ? a3[g*4 + k] : 1.0f;
    }
    const size_t p = (size_t)(prel + r0);
    if (c < 29){
      #pragma unroll
      for (int k = 0; k < 4; ++k)
        fb[(p + k)*32 + c] = f2bf(vs[k]);         // half-wave writes a full 64B line
    } else {
      float4 fv = { vs[0], vs[1], vs[2], vs[3] };
      *(float4*)(&ob[((size_t)(c - 29) << 18) + p]) = fv;
      #pragma unroll
      for (int k = 0; k < 4; ++k)
        fb[(p + k)*32 + c] = f2bf(0.f);           // K-pad channels
    }
  }
}

// ---------------- conv1 (MFMA): fmap NHWC-32 -> e1T NHWC-64, 3x3 pad1, relu ----------------
__global__ __launch_bounds__(256,2) void conv1_mfma(
    const bf16* __restrict__ fmap32, const short8* __restrict__ wb1,
    bf16* __restrict__ e1T, const float* __restrict__ zpage,
    size_t fmap_bs, size_t e1_bs){
  __shared__ short lds[8192];   // 16384 B (tin 5760 shorts; out-stage 8192)
  const int tid = threadIdx.x;
  const int wv = tid >> 6, lane = tid & 63;
  const int quad = lane >> 4, l15 = lane & 15;

  // bijective XCD swizzle (gridDim.x % 8 == 0: 8192 or 2048)
  const int L = blockIdx.x;
  const int cpx = gridDim.x >> 3;
  const int o = (L & 7)*cpx + (L >> 3);
  const int bx = o & 31;
  const int r2 = o >> 5;
  const int by = r2 & 63;
  const int bz = r2 >> 6;

  const bf16* fb = fmap32 + (size_t)bz*fmap_bs;
  bf16* eb = e1T + (size_t)bz*e1_bs;
  const int oy0 = by*8, ox0 = bx*16;

  // ---- stage tin: 720 x 16B async loads (10 rows x 18 cols x 4 ch-groups)
  for (int r = 0; r < 3; ++r){
    const int d = r*256 + tid;
    const int pairI = d >> 3, slot = d & 7;
    const int sel = slot ^ (pairI & 7);
    const int p = pairI*2 + (sel >> 2);
    const int g = sel & 3;
    const int row = p / 18, col = p - row*18;
    const int gy = oy0 - 1 + row, gx = ox0 - 1 + col;
    const bool ok = (d < 720) && ((unsigned)gy < 512u) && ((unsigned)gx < 512u);
    const void* src = ok
      ? (const void*)&fb[((size_t)((gy<<9) + gx))*32 + g*8]
      : (const void*)zpage;
    __builtin_amdgcn_global_load_lds(
      (const __attribute__((address_space(1))) void*)src,
      (__attribute__((address_space(3))) void*)&lds[d*8],
      16, 0, 0);
  }
  __syncthreads();

  // ---- MFMA: wave wv owns out rows {wv*2, wv*2+1}; 4 co-tiles
  f32x4 acc[2][4];
  #pragma unroll
  for (int i=0;i<2;++i)
    #pragma unroll
    for (int n=0;n<4;++n) acc[i][n] = (f32x4){0.f,0.f,0.f,0.f};

  for (int t = 0; t < 9; ++t){
    const short8* bp = wb1 + ((0*9 + t)*4)*64 + lane;
    const short8* bq = wb1 + ((1*9 + t)*4)*64 + lane;
    short8 bh0 = bp[0], bh1 = bp[64], bh2 = bp[128], bh3 = bp[192];
    short8 bl0 = bq[0], bl1 = bq[64], bl2 = bq[128], bl3 = bq[192];
    const int dy = t/3, dx = t - dy*3;
    #pragma unroll
    for (int i = 0; i < 2; ++i){
      const int py = wv*2 + i + dy;
      const int px = l15 + dx;
      const int p = py*18 + px;
      const int slot = (quad + 4*(p & 1)) ^ ((p >> 1) & 7);
      short8 a = *(const short8*)&lds[((p >> 1)*8 + slot)*8];
      acc[i][0] = __builtin_amdgcn_mfma_f32_16x16x32_bf16(a, bh0, acc[i][0], 0, 0, 0);
      acc[i][1] = __builtin_amdgcn_mfma_f32_16x16x32_bf16(a, bh1, acc[i][1], 0, 0, 0);
      acc[i][2] = __builtin_amdgcn_mfma_f32_16x16x32_bf16(a, bh2, acc[i][2], 0, 0, 0);
      acc[i][3] = __builtin_amdgcn_mfma_f32_16x16x32_bf16(a, bh3, acc[i][3], 0, 0, 0);
      acc[i][0] = __builtin_amdgcn_mfma_f32_16x16x32_bf16(a, bl0, acc[i][0], 0, 0, 0);
      acc[i][1] = __builtin_amdgcn_mfma_f32_16x16x32_bf16(a, bl1, acc[i][1], 0, 0, 0);
      acc[i][2] = __builtin_amdgcn_mfma_f32_16x16x32_bf16(a, bl2, acc[i][2], 0, 0, 0);
      acc[i][3] = __builtin_amdgcn_mfma_f32_16x16x32_bf16(a, bl3, acc[i][3], 0, 0, 0);
    }
  }
  __syncthreads();   // tin dead -> out staging

  // ---- epilogue: relu -> bf16, swizzled LDS out [128px][8slot][8ch]
  #pragma unroll
  for (int i = 0; i < 2; ++i){
    const int rowp = wv*2 + i;
    #pragma unroll
    for (int n = 0; n < 4; ++n){
      const int gq = n*2 + (l15 >> 3);
      #pragma unroll
      for (int reg = 0; reg < 4; ++reg){
        const int px = rowp*16 + quad*4 + reg;
        const int slot = gq ^ (px & 7);
        lds[(px*8 + slot)*8 + (l15 & 7)] = f2bfs(fmaxf(acc[i][n][reg], 0.f));
      }
    }
  }
  __syncthreads();
  // ---- coalesced NHWC stores: 4 x short8 per thread
  #pragma unroll
  for (int w = 0; w < 4; ++w){
    const int s = w*256 + tid;
    const int px = s >> 3, g8 = s & 7;
    const int slot = g8 ^ (px & 7);
    short8 v = *(const short8*)&lds[(px*8 + slot)*8];
    const int gy = oy0 + (px >> 4), gx = ox0 + (px & 15);
    *(short8*)((void*)&eb[((size_t)((gy<<9) + gx))*64 + g8*8]) = v;
  }
}

// ---------------- conv2 (MFMA): e1T NHWC -> dT NHWC, 3x3 stride2 SAME (pad_lo=0), relu ----------
__global__ __launch_bounds__(256,2) void conv2_mfma(
    const bf16* __restrict__ e1T, const short8* __restrict__ wb2,
    bf16* __restrict__ dT, const float* __restrict__ zpage,
    size_t e1_bs, size_t dt_bs){
  __shared__ short lds[36864];   // 73728 B
  const int tid = threadIdx.x;
  const int wv = tid >> 6, lane = tid & 63;
  const int quad = lane >> 4, l15 = lane & 15;

  const int L = blockIdx.x;
  const int cpx = gridDim.x >> 3;
  const int o = (L & 7)*cpx + (L >> 3);
  const int bx = o & 15;
  const int r2 = o >> 4;
  const int by = r2 & 31;
  const int bz = r2 >> 5;

  const bf16* eb = e1T + (size_t)bz*e1_bs;
  bf16* db = dT + (size_t)bz*dt_bs;
  const int oy0 = by*8, ox0 = bx*16;
  const int iy0 = oy0*2, ix0 = ox0*2;

  for (int r = 0; r < 18; ++r){
    const int idx = r*256 + tid;
    const int g = idx & 7, p = idx >> 3;
    const int row = p / 33, col = p - row*33;
    const int gy = iy0 + row, gx = ix0 + col;
    const int gs = g ^ ((col >> 1) & 7);
    const bool ok = (p < 561) && (gy < 512) && (gx < 512);
    const void* src = ok
      ? (const void*)&eb[((size_t)((gy<<9) + gx))*64 + gs*8]
      : (const void*)zpage;
    __builtin_amdgcn_global_load_lds(
      (const __attribute__((address_space(1))) void*)src,
      (__attribute__((address_space(3))) void*)&lds[idx*8],
      16, 0, 0);
  }
  __syncthreads();

  f32x4 acc[2][8];
  #pragma unroll
  for (int i=0;i<2;++i)
    #pragma unroll
    for (int n=0;n<8;++n) acc[i][n] = (f32x4){0.f,0.f,0.f,0.f};

  for (int ks = 0; ks < 4; ++ks){
    const int cg = (ks & 1)*4 + quad;
    for (int t = 0; t < 9; ++t){
      const short8* bp = wb2 + ((ks*9 + t)*8)*64 + lane;
      short8 b0 = bp[0],   b1 = bp[64],  b2 = bp[128], b3 = bp[192];
      short8 b4 = bp[256], b5 = bp[320], b6 = bp[384], b7 = bp[448];
      const int dy = t/3, dx = t - dy*3;
      #pragma unroll
      for (int i = 0; i < 2; ++i){
        const int m = wv*2 + i;
        const int py = 2*m + dy;
        const int px = 2*l15 + dx;
        const int slot = cg ^ ((px >> 1) & 7);
        short8 a = *(const short8*)&lds[((py*33 + px)*8 + slot)*8];
        acc[i][0] = __builtin_amdgcn_mfma_f32_16x16x32_bf16(a, b0, acc[i][0], 0, 0, 0);
        acc[i][1] = __builtin_amdgcn_mfma_f32_16x16x32_bf16(a, b1, acc[i][1], 0, 0, 0);
        acc[i][2] = __builtin_amdgcn_mfma_f32_16x16x32_bf16(a, b2, acc[i][2], 0, 0, 0);
        acc[i][3] = __builtin_amdgcn_mfma_f32_16x16x32_bf16(a, b3, acc[i][3], 0, 0, 0);
        acc[i][4] = __builtin_amdgcn_mfma_f32_16x16x32_bf16(a, b4, acc[i][4], 0, 0, 0);
        acc[i][5] = __builtin_amdgcn_mfma_f32_16x16x32_bf16(a, b5, acc[i][5], 0, 0, 0);
        acc[i][6] = __builtin_amdgcn_mfma_f32_16x16x32_bf16(a, b6, acc[i][6], 0, 0, 0);
        acc[i][7] = __builtin_amdgcn_mfma_f32_16x16x32_bf16(a, b7, acc[i][7], 0, 0, 0);
      }
    }
  }
  __syncthreads();

  #pragma unroll
  for (int i = 0; i < 2; ++i){
    const int m = wv*2 + i;
    #pragma unroll
    for (int n = 0; n < 8; ++n){
      #pragma unroll
      for (int reg = 0; reg < 4; ++reg){
        const int col = quad*4 + reg;
        const int px = m*16 + col;
        const int g16 = n*2 + (l15 >> 3);
        const int slot = g16 ^ (px & 15);
        lds[(px*16 + slot)*8 + (l15 & 7)] = f2bfs(fmaxf(acc[i][n][reg], 0.f));
      }
    }
  }
  __syncthreads();
  #pragma unroll
  for (int w = 0; w < 8; ++w){
    const int s = w*256 + tid;
    const int px = s >> 4, g16 = s & 15;
    const int slot = g16 ^ (px & 15);
    short8 v = *(const short8*)&lds[(px*16 + slot)*8];
    const int gy = oy0 + (px >> 4), gx = ox0 + (px & 15);
    *(short8*)((void*)&db[((size_t)((gy<<8) + gx))*128 + g16*8]) = v;
  }
}

// ---------------- conv3 + conv4, both MFMA; 53248B LDS, no reg clamp ----------------
// conv3: K = 192ch as 3 x 64-ch chunks (2 dT compact + 1 e1 m-space).
// EB1 overlays the dead DB0|DB1 region (exactly 13312 shorts), staged one phase later.
// conv4: MFMA over msh: M = out px (16 tiles), K = 64ch x 9t x hi/lo, N = 3 co (pad 16).
// launch_bounds(256,2): R17-proven 128 VGPR no-spill; LDS caps occupancy at 3 blocks/CU.
__global__ __launch_bounds__(256,2) void conv34_mfma(
    const bf16* __restrict__ dT, const bf16* __restrict__ e1T,
    const short8* __restrict__ wb3, const short8* __restrict__ wb4,
    float* __restrict__ out, const float* __restrict__ zpage,
    size_t dt_bs, size_t e1_bs, size_t out_bs){
  __shared__ short lds[26624];   // 53248 B
  const int tid = threadIdx.x;
  const int wv = tid >> 6, lane = tid & 63;
  const int quad = lane >> 4, l15 = lane & 15;

  const int L = blockIdx.x;
  const int cpx = gridDim.x >> 3;              // gridDim.x % 8 == 0 (4608 or 1152)
  const int o = (L & 7)*cpx + (L >> 3);
  const int bx = o % 18;
  const int rem = o / 18;
  const int by = rem & 63;
  const int bz = rem >> 6;

  const bf16* dTb = dT + (size_t)bz*dt_bs;
  const bf16* e1b = e1T + (size_t)bz*e1_bs;
  float* outb = out + (size_t)bz*out_bs;
  const int gy0 = by * 8;
  const int gx0 = bx * 30;
  const int dy0 = (gy0 >> 1) - 1;
  const int dx0 = (gx0 >> 1) - 1;
  f32x4 acc[5][4];
  #pragma unroll
  for (int i=0;i<5;++i)
    #pragma unroll
    for (int n=0;n<4;++n) acc[i][n] = (f32x4){0.f,0.f,0.f,0.f};

  short* DB0 = lds;            // 6656 shorts
  short* DB1 = lds + 6656;     // 6656 shorts
  short* EB0 = lds + 13312;    // 13312 shorts
  short* EB1 = lds;            // overlays DB0|DB1 (dead by then)

  auto stage_dT = [&](int c, short* db){
    #pragma unroll
    for (int r = 0; r < 4; ++r){
      const int idxb = r*256 + wv*64;
      if (idxb >= 832) continue;
      const int idx = idxb + lane;
      const int p = idx >> 3, g = idx & 7;
      const int prow = p / 17, pcol = p - prow*17;
      const int gyD = dy0 + prow, gxD = dx0 + pcol;
      const int gs = g ^ (pcol & 7);
      const bool ok = (p < 102) && ((unsigned)gyD < 256u) && ((unsigned)gxD < 256u);
      const void* src = ok
        ? (const void*)&dTb[((size_t)((gyD<<8) + gxD))*128 + c*64 + gs*8]
        : (const void*)zpage;
      __builtin_amdgcn_global_load_lds(
        (const __attribute__((address_space(1))) void*)src,
        (__attribute__((address_space(3))) void*)&db[idxb*8],
        16, 0, 0);
    }
  };

  auto stage_e1 = [&](int j, short* eb){
    #pragma unroll
    for (int r = 0; r < 7; ++r){
      const int idxb = r*256 + wv*64;
      if (idxb >= 1664) continue;
      const int idx = idxb + lane;
      const int pos = idx >> 2, cg = idx & 3;
      const int yy = pos / 34, xx = pos - yy*34;
      const int gy = gy0 - 2 + yy, gx = gx0 - 2 + xx;
      const int cs = cg ^ (xx & 3);
      const bool ok = ((unsigned)gy < 512u) && ((unsigned)gx < 512u) && (pos < 408);
      const int pyc = gy & 511, pxc = gx & 511;
      const void* src = ok
        ? (const void*)&e1b[((size_t)((pyc<<9) + pxc))*64 + j*32 + cs*8]
        : (const void*)zpage;
      __builtin_amdgcn_global_load_lds(
        (const __attribute__((address_space(1))) void*)src,
        (__attribute__((address_space(3))) void*)&eb[idxb*8],
        16, 0, 0);
    }
  };

  auto compute_D = [&](int c, const short* db){
    #pragma unroll
    for (int ks = 0; ks < 2; ++ks){
      const int kc = c*2 + ks;
      int bb = (kc*9*4)*64 + lane;
      short8 bc0 = wb3[bb], bc1 = wb3[bb+64], bc2 = wb3[bb+128], bc3 = wb3[bb+192];
      for (int t = 0; t < 9; ++t){
        short8 bn0, bn1, bn2, bn3;
        if (t < 8){
          const int b2 = bb + 256;
          bn0 = wb3[b2]; bn1 = wb3[b2+64]; bn2 = wb3[b2+128]; bn3 = wb3[b2+192];
        }
        const int dy = t/3, dx = t - dy*3;
        #pragma unroll
        for (int i = 0; i < 5; ++i){
          const int mt = wv*5 + i;
          const int r = mt >> 1, h = mt & 1;
          const int px = h*16 + l15 + dx;
          const int py = r + dy;
          const int p = (py >> 1)*17 + (px >> 1);
          const int g = (ks*4 + quad) ^ ((px >> 1) & 7);
          short8 a = *(const short8*)&db[p*64 + g*8];
          acc[i][0] = __builtin_amdgcn_mfma_f32_16x16x32_bf16(a, bc0, acc[i][0], 0, 0, 0);
          acc[i][1] = __builtin_amdgcn_mfma_f32_16x16x32_bf16(a, bc1, acc[i][1], 0, 0, 0);
          acc[i][2] = __builtin_amdgcn_mfma_f32_16x16x32_bf16(a, bc2, acc[i][2], 0, 0, 0);
          acc[i][3] = __builtin_amdgcn_mfma_f32_16x16x32_bf16(a, bc3, acc[i][3], 0, 0, 0);
        }
        if (t < 8){ bc0 = bn0; bc1 = bn1; bc2 = bn2; bc3 = bn3; bb += 256; }
      }
    }
  };

  auto compute_E = [&](int j, const short* tb){
    const int kc = 4 + j;
    int bb = (kc*9*4)*64 + lane;
    short8 bc0 = wb3[bb], bc1 = wb3[bb+64], bc2 = wb3[bb+128], bc3 = wb3[bb+192];
    for (int t = 0; t < 9; ++t){
      short8 bn0, bn1, bn2, bn3;
      if (t < 8){
        const int b2 = bb + 256;
        bn0 = wb3[b2]; bn1 = wb3[b2+64]; bn2 = wb3[b2+128]; bn3 = wb3[b2+192];
      }
      const int dy = t/3, dx = t - dy*3;
      #pragma unroll
      for (int i = 0; i < 5; ++i){
        const int mt = wv*5 + i;
        const int r = mt >> 1, h = mt & 1;
        const int px = h*16 + l15 + dx;
        const int py = r + dy;
        const int g = quad ^ (px & 3);
        short8 a = *(const short8*)&tb[(py*34 + px)*32 + g*8];
        acc[i][0] = __builtin_amdgcn_mfma_f32_16x16x32_bf16(a, bc0, acc[i][0], 0, 0, 0);
        acc[i][1] = __builtin_amdgcn_mfma_f32_16x16x32_bf16(a, bc1, acc[i][1], 0, 0, 0);
        acc[i][2] = __builtin_amdgcn_mfma_f32_16x16x32_bf16(a, bc2, acc[i][2], 0, 0, 0);
        acc[i][3] = __builtin_amdgcn_mfma_f32_16x16x32_bf16(a, bc3, acc[i][3], 0, 0, 0);
      }
      if (t < 8){ bc0 = bn0; bc1 = bn1; bc2 = bn2; bc3 = bn3; bb += 256; }
    }
  };

  stage_dT(0, DB0);
  __syncthreads();                              // D0 ready

  stage_dT(1, DB1);                             // prefetch D1
  __builtin_amdgcn_sched_barrier(0);
  compute_D(0, DB0);
  __syncthreads();                              // D1 ready

  stage_e1(0, EB0);                             // prefetch E0
  __builtin_amdgcn_sched_barrier(0);
  compute_D(1, DB1);
  __syncthreads();                              // E0 ready; DB0/DB1 dead

  stage_e1(1, EB1);                             // prefetch E1 into dead DB region
  __builtin_amdgcn_sched_barrier(0);
  compute_E(0, EB0);
  __syncthreads();                              // E1 ready

  compute_E(1, EB1);

  __syncthreads();   // staging dead -> msh[10][32][64] (swizzled groups)
  // conv3 epilogue: relu + border-zero, write msh
  #pragma unroll
  for (int i = 0; i < 5; ++i){
    const int mt = wv*5 + i;
    const int r = mt >> 1, h = mt & 1;
    const int gym = gy0 - 1 + r;
    #pragma unroll
    for (int reg = 0; reg < 4; ++reg){
      const int mxd = h*16 + quad*4 + reg;
      const int gxm = gx0 - 1 + mxd;
      const bool inim = ((unsigned)gym < 512u) && ((unsigned)gxm < 512u);
      const int key = (mxd & 7) << 3;
      #pragma unroll
      for (int n = 0; n < 4; ++n){
        float v = inim ? fmaxf(acc[i][n][reg], 0.f) : 0.f;
        int c = n*16 + l15;
        lds[(r*32 + mxd)*64 + (c ^ key)] = f2bfs(v);
      }
    }
  }
  __syncthreads();

  // conv4 on MFMA: wave wv owns M-tiles {wv*4..wv*4+3} = (row ly, half h)
  f32x4 a4[4];
  #pragma unroll
  for (int ii = 0; ii < 4; ++ii) a4[ii] = (f32x4){0.f,0.f,0.f,0.f};
  for (int kc = 0; kc < 2; ++kc){
    for (int t = 0; t < 9; ++t){
      short8 bh = wb4[((kc*9) + t)*64 + lane];        // hl=0
      short8 bl = wb4[(((2 + kc)*9) + t)*64 + lane];  // hl=1
      const int dy = t/3, dx = t - dy*3;
      #pragma unroll
      for (int ii = 0; ii < 4; ++ii){
        const int mt4 = wv*4 + ii;
        const int ly = mt4 >> 1, h = mt4 & 1;
        const int r = ly + dy;                 // msh row 0..9
        const int mxd = h*16 + l15 + dx;       // cols >31 read stale LDS; rows masked at store
        const int sg = (kc*4 + quad) ^ (mxd & 7);
        short8 a = *(const short8*)&lds[(r*32 + mxd)*64 + sg*8];
        a4[ii] = __builtin_amdgcn_mfma_f32_16x16x32_bf16(a, bh, a4[ii], 0, 0, 0);
        a4[ii] = __builtin_amdgcn_mfma_f32_16x16x32_bf16(a, bl, a4[ii], 0, 0, 0);
      }
    }
  }
  // store: channel = l15 (0..2), rows = out x; residual already in out
  if (l15 < 3){
    #pragma unroll
    for (int ii = 0; ii < 4; ++ii){
      const int mt4 = wv*4 + ii;
      const int ly = mt4 >> 1, h = mt4 & 1;
      const int oy = gy0 + ly;
      float* op = outb + (((size_t)l15) << 18) + ((size_t)oy << 9);
      #pragma unroll
      for (int reg = 0; reg < 4; ++reg){
        const int lx = h*16 + quad*4 + reg;
        const int ox = gx0 + lx;
        if (lx < 30 && ox < 512)
          op[ox] += a4[ii][reg];
      }
    }
  }
}

static const void* find_by_size(void* const* d_in, const int* in_sizes, int n_in,
                                int want, int occurrence, int fallback_idx){
  int seen = 0;
  for (int i = 0; i < n_in; ++i){
    if (in_sizes[i] == want){
      if (seen == occurrence) return d_in[i];
      ++seen;
    }
  }
  return d_in[fallback_idx];
}

extern "C" void kernel_launch(void* const* d_in, const int* in_sizes, int n_in,
                              void* d_out, int out_size, void* d_ws, size_t ws_size,
                              hipStream_t stream) {
  const float* zbuf = (const float*)find_by_size(d_in, in_sizes, n_in, 1048576, 0, 0);
  const float* ray  = (const float*)find_by_size(d_in, in_sizes, n_in, 7340032, 0, 1);
  const float* w0   = (const float*)find_by_size(d_in, in_sizes, n_in, 768,     0, 4);
  const float* w1   = (const float*)find_by_size(d_in, in_sizes, n_in, 16384,   0, 6);
  const float* w2   = (const float*)find_by_size(d_in, in_sizes, n_in, 4096,    0, 8);
  const float* uk1  = (const float*)find_by_size(d_in, in_sizes, n_in, 16704,   0, 10);
  const float* uk2  = (const float*)find_by_size(d_in, in_sizes, n_in, 73728,   0, 11);
  const float* uk3  = (const float*)find_by_size(d_in, in_sizes, n_in, 110592,  0, 12);
  const float* uk4  = (const float*)find_by_size(d_in, in_sizes, n_in, 1728,    0, 13);

  uint8_t* ws = (uint8_t*)d_ws;
  const int batched = (ws_size >= 0xC000000UL + 0xB0000UL);
  const size_t dt_off = 0;
  const size_t e1_off = batched ? 0x4000000UL : 0x1000000UL;
  const size_t w_off  = batched ? 0xC000000UL : 0x3000000UL;

  bf16* fmapB = (bf16*)(ws + dt_off);      // fmap32 NHWC overlays dT slots
  bf16* dTB   = (bf16*)(ws + dt_off);
  bf16* e1B   = (bf16*)(ws + e1_off);
  short* wb1  = (short*)(ws + w_off + WB1_R);
  short* wb2  = (short*)(ws + w_off + WB2_R);
  short* wb3  = (short*)(ws + w_off + WB3_R);
  short* wb4  = (short*)(ws + w_off + WB4_R);
  unsigned short* wfmlp = (unsigned short*)(ws + w_off + WMLP_R);
  float* zp   = (float*)(ws + w_off + WZERO_R);
  float* outp = (float*)d_out;

  wb1_kernel<<<144, 256, 0, stream>>>(uk1, wb1);
  wb2_kernel<<<576, 256, 0, stream>>>(uk2, wb2);
  wb3_kernel<<<432, 256, 0, stream>>>(uk3, wb3);
  wb4_kernel<<<72, 256, 0, stream>>>(uk4, wb4);
  mlp_frag_kernel<<<176, 256, 0, stream>>>(w0, w1, w2, wfmlp);
  zero_kernel<<<4, 256, 0, stream>>>(zp);

  if (batched){
    mlp_mfma<<<8192, 256, 0, stream>>>(zbuf, ray, wfmlp, fmapB, outp, DT_BS, OUT_BS);
    conv1_mfma<<<8192, 256, 0, stream>>>(fmapB, (const short8*)wb1, e1B, zp, DT_BS, E1_BS);
    conv2_mfma<<<2048, 256, 0, stream>>>(e1B, (const short8*)wb2, dTB, zp, E1_BS, DT_BS);
    conv34_mfma<<<4608, 256, 0, stream>>>(dTB, e1B, (const short8*)wb3, (const short8*)wb4,
                                          outp, zp, DT_BS, E1_BS, OUT_BS);
  } else {
    for (int b = 0; b < 4; ++b){
      float* outb = outp + (size_t)b*OUT_BS;
      mlp_mfma<<<2048, 256, 0, stream>>>(zbuf + (size_t)b*262144,
                                         ray  + (size_t)b*262144*7,
                                         wfmlp, fmapB, outb, DT_BS, OUT_BS);
      conv1_mfma<<<2048, 256, 0, stream>>>(fmapB, (const short8*)wb1, e1B, zp, DT_BS, E1_BS);
      conv2_mfma<<<512, 256, 0, stream>>>(e1B, (const short8*)wb2, dTB, zp, E1_BS, DT_BS);
      conv34_mfma<<<1152, 256, 0, stream>>>(dTB, e1B, (const short8*)wb3, (const short8*)wb4,
                                            outb, zp, DT_BS, E1_BS, OUT_BS);
    }
  }
}

// Round 10
// 748.516 us; speedup vs baseline: 1.3640x; 1.0850x over previous
//
#include <hip/hip_runtime.h>
#include <hip/hip_bf16.h>
#include <stdint.h>

typedef __hip_bfloat16 bf16;
typedef __attribute__((ext_vector_type(8))) short short8;
typedef __attribute__((ext_vector_type(4))) float f32x4;
typedef __attribute__((ext_vector_type(16))) float f32x16;
typedef __attribute__((ext_vector_type(8))) _Float16 half8;

__device__ __forceinline__ float bf2f(bf16 x){ return __bfloat162float(x); }
__device__ __forceinline__ bf16  f2bf(float x){ return __float2bfloat16(x); }
__device__ __forceinline__ short f2bfs(float x){ union { bf16 h; short s; } u; u.h = f2bf(x); return u.s; }
__device__ __forceinline__ float bfs2f(short s){ union { bf16 h; short t; } u; u.t = s; return bf2f(u.h); }

// R20: revert conv34 to R17-exact (4-buffer 79872B LDS, paired E0/E1 staging,
// launch_bounds(256,2) -> 128 VGPR no spill; measured 320us, FETCH 106MB WRITE 12MB).
// R19's EB1-overlay schedule was a proven regression (402us, +32MB fetch from lost
// E line-pairing, +97MB write, MfmaUtil 52.6->40) with NO occupancy gain (22.6 vs 22.4
// -> LDS was not the limiter). Keep mlp direct-global weights (non-conv34 567->410us).
// New: single fused prep_kernel replaces 6 tiny launches.
// Batched layout (ws >= ~202MB): dT[4]@0x0 (16MiB slots, fmap32 overlays),
//   e1T[4]@0x4000000 (32MiB slots), weights@0xC000000.
// Fallback layout: dT/fmap@0x0, e1T@0x1000000, weights@0x3000000.
// Weight region (relative): wb1|wb2|wb3|wb4|wfmlp|zpage  (= 0xB0000 total)
#define WB1_R   0UL                          // 2*9*4*64*8*2   = 73728
#define WB2_R   73728UL                      // 4*9*8*64*8*2   = 294912
#define WB3_R   368640UL                     // 6*9*4*64*8*2   = 221184
#define WB4_R   589824UL                     // 4*9*64*8*2     = 36864
#define WMLP_R  626688UL                     // 45056 u16      = 90112
#define WZERO_R 716800UL                     // 4096 B zeros -> ends 720896 = 0xB0000
#define DT_BS   8388608UL                    // bf16 elems per batch slot (16 MiB)
#define E1_BS   16777216UL                   // bf16 elems per batch slot (32 MiB)
#define OUT_BS  786432UL                     // f32 elems per batch (3*512*512)

// ---------------- fused prep: wb1|wb2|wb3|wb4|mlp_frag|zero in one launch ----------------
__global__ void prep_kernel(const float* __restrict__ uk1, const float* __restrict__ uk2,
                            const float* __restrict__ uk3, const float* __restrict__ uk4,
                            const float* __restrict__ w0, const float* __restrict__ w1,
                            const float* __restrict__ w2,
                            short* __restrict__ wb1, short* __restrict__ wb2,
                            short* __restrict__ wb3, short* __restrict__ wb4,
                            unsigned short* __restrict__ wfmlp, float* __restrict__ zp){
  int gidx = blockIdx.x*256 + threadIdx.x;
  if (gidx < 36864){
    // conv1 B-frags: co=n*16+(lane&15), ci=(lane>>4)*8+j (0 if ci>=29); hl split
    int idx = gidx;
    int j = idx & 7, lane = (idx >> 3) & 63, n = (idx >> 9) & 3, ch = idx >> 11;
    int t = ch % 9, hl = ch / 9;
    int co = n*16 + (lane & 15);
    int ci = (lane >> 4)*8 + j;
    float val = (ci < 29) ? uk1[(co*29 + ci)*9 + t] : 0.f;
    short hi = f2bfs(val);
    wb1[idx] = hl ? f2bfs(val - bfs2f(hi)) : hi;
  } else if (gidx < 184320){
    // conv2 B-frags
    int idx = gidx - 36864;
    int j    = idx & 7;
    int lane = (idx >> 3) & 63;
    int n    = (idx >> 9) & 7;
    int kt   = idx >> 12;            // kk*9 + t
    int t = kt % 9, kk = kt / 9;
    int co = n*16 + (lane & 15);
    int ci = (kk & 1)*32 + (lane >> 4)*8 + j;
    float val = uk2[(co*64 + ci)*9 + t];
    short hi = f2bfs(val);
    wb2[idx] = (kk < 2) ? hi : f2bfs(val - bfs2f(hi));
  } else if (gidx < 294912){
    // conv3 B-frags
    int idx = gidx - 184320;
    int j    = idx & 7;
    int lane = (idx >> 3) & 63;
    int n0   = (idx >> 9) & 3;
    int kt   = idx >> 11;            // kc*9 + t
    int t = kt % 9, kc = kt / 9;
    int co = n0*16 + (lane & 15);
    int ci = kc*32 + (lane >> 4)*8 + j;
    wb3[idx] = f2bfs(uk3[(co*192 + ci)*9 + t]);
  } else if (gidx < 313344){
    // conv4 B-frags
    int idx = gidx - 294912;
    int j = idx & 7, lane = (idx >> 3) & 63, rt = idx >> 9;   // rt = (hl*2+kc)*9+t
    int t = rt % 9, r = rt / 9;
    int kc = r & 1, hl = r >> 1;
    int co = lane & 15;
    int ci = kc*32 + (lane >> 4)*8 + j;
    float val = (co < 3) ? uk4[(co*64 + ci)*9 + t] : 0.f;
    short hi = f2bfs(val);
    wb4[idx] = hl ? f2bfs(val - bfs2f(hi)) : hi;
  } else if (gidx < 358400){
    // MLP f16 hi/lo B-frags
    int idx = gidx - 313344;
    int j = idx & 7;
    int chunk = idx >> 3;
    int lane = chunk & 63;
    int hi5 = lane >> 5, l31 = lane & 31;
    int rest = chunk >> 6;
    float val; int hl;
    if (rest < 8){
      hl = rest & 1; int n = rest >> 1;
      int k = hi5*8 + j, co = n*32 + l31;
      val = (k < 6) ? w0[k*128 + co] : 0.f;
    } else if (rest < 72){
      int r = rest - 8; hl = r & 1; int n = (r>>1)&3, ks = r>>3;
      int k = ks*16 + hi5*8 + j, co = n*32 + l31;
      val = w1[k*128 + co];
    } else {
      int r = rest - 72; hl = r & 1; int ks = r>>1;
      int k = ks*16 + hi5*8 + j, co = l31;
      val = w2[k*32 + co];
    }
    _Float16 h = (_Float16)val;
    _Float16 o = hl ? (_Float16)(val - (float)h) : h;
    union { _Float16 f; unsigned short u; } cv; cv.f = o;
    wfmlp[idx] = cv.u;
  } else if (gidx < 359424){
    zp[gidx - 358400] = 0.f;
  }
}

// ---------------- per-pixel MLP on MFMA: 6 -> 128 -> 128 -> 32 (fmap NHWC-32) ----------------
// B-fragments read directly from global wf (L2-hot, 90KB); LDS = hbuf only -> 2 blocks/CU.
__global__ __launch_bounds__(256,2) void mlp_mfma(
    const float* __restrict__ zbuf, const float* __restrict__ ray,
    const unsigned short* __restrict__ wf,
    bf16* __restrict__ fmap, float* __restrict__ outrgb,
    size_t fmap_bs, size_t out_bs){
  __shared__ __align__(16) float hbuf[4][32][140];     // 71680 B
  const int tid = threadIdx.x;
  const int wv = tid >> 6, lane = tid & 63, h5 = lane >> 5, l31 = lane & 31;
  const int mbase = (blockIdx.x*4 + wv)*32;
  const int bz = mbase >> 18;
  const int prel = mbase & 262143;

  const float* rp = ray + (size_t)(mbase + l31)*7;
  float z  = zbuf[mbase + l31];
  float d0 = rp[3], d1 = rp[4], d2 = rp[5];
  float inv = z / rp[6];
  half8 a1h = {}; half8 a1l = {};
  if (h5 == 0){
    float f[6] = { rp[0]+d0*inv, rp[1]+d1*inv, rp[2]+d2*inv, d0, d1, d2 };
    #pragma unroll
    for (int j = 0; j < 6; ++j){
      _Float16 hi = (_Float16)f[j];
      a1h[j] = hi;
      a1l[j] = (_Float16)(f[j] - (float)hi);
    }
  }
  hbuf[wv][l31][137] = z;

  // ---- layer 1
  f32x16 acc[4];
  #pragma unroll
  for (int n = 0; n < 4; ++n){
    half8 bh = *(const half8*)&wf[((n*2+0)*64 + lane)*8];
    half8 bl = *(const half8*)&wf[((n*2+1)*64 + lane)*8];
    f32x16 a = {};
    a = __builtin_amdgcn_mfma_f32_32x32x16_f16(a1h, bh, a, 0, 0, 0);
    a = __builtin_amdgcn_mfma_f32_32x32x16_f16(a1l, bh, a, 0, 0, 0);
    a = __builtin_amdgcn_mfma_f32_32x32x16_f16(a1h, bl, a, 0, 0, 0);
    acc[n] = a;
  }
  #pragma unroll
  for (int n = 0; n < 4; ++n)
    #pragma unroll
    for (int reg = 0; reg < 16; ++reg)
      hbuf[wv][(reg&3) + 8*(reg>>2) + 4*h5][n*32 + l31] = fmaxf(acc[n][reg], 0.f);

  // ---- layer 2
  f32x16 acc2[4];
  #pragma unroll
  for (int n = 0; n < 4; ++n) acc2[n] = (f32x16){};
  #pragma unroll
  for (int ks = 0; ks < 8; ++ks){
    const float4* hp = (const float4*)&hbuf[wv][l31][ks*16 + h5*8];
    float4 v0 = hp[0], v1 = hp[1];
    float hv[8] = { v0.x, v0.y, v0.z, v0.w, v1.x, v1.y, v1.z, v1.w };
    half8 ah, al;
    #pragma unroll
    for (int j = 0; j < 8; ++j){
      _Float16 hi = (_Float16)hv[j];
      ah[j] = hi;
      al[j] = (_Float16)(hv[j] - (float)hi);
    }
    #pragma unroll
    for (int n = 0; n < 4; ++n){
      half8 bh = *(const half8*)&wf[(512 + ((ks*4+n)*2+0)*64 + lane)*8];
      half8 bl = *(const half8*)&wf[(512 + ((ks*4+n)*2+1)*64 + lane)*8];
      acc2[n] = __builtin_amdgcn_mfma_f32_32x32x16_f16(ah, bh, acc2[n], 0, 0, 0);
      acc2[n] = __builtin_amdgcn_mfma_f32_32x32x16_f16(al, bh, acc2[n], 0, 0, 0);
      acc2[n] = __builtin_amdgcn_mfma_f32_32x32x16_f16(ah, bl, acc2[n], 0, 0, 0);
    }
  }
  #pragma unroll
  for (int n = 0; n < 4; ++n)
    #pragma unroll
    for (int reg = 0; reg < 16; ++reg)
      hbuf[wv][(reg&3) + 8*(reg>>2) + 4*h5][n*32 + l31] = fmaxf(acc2[n][reg], 0.f);

  // ---- layer 3
  f32x16 a3 = {};
  #pragma unroll
  for (int ks = 0; ks < 8; ++ks){
    const float4* hp = (const float4*)&hbuf[wv][l31][ks*16 + h5*8];
    float4 v0 = hp[0], v1 = hp[1];
    float hv[8] = { v0.x, v0.y, v0.z, v0.w, v1.x, v1.y, v1.z, v1.w };
    half8 ah, al;
    #pragma unroll
    for (int j = 0; j < 8; ++j){
      _Float16 hi = (_Float16)hv[j];
      ah[j] = hi;
      al[j] = (_Float16)(hv[j] - (float)hi);
    }
    half8 bh = *(const half8*)&wf[(4608 + (ks*2+0)*64 + lane)*8];
    half8 bl = *(const half8*)&wf[(4608 + (ks*2+1)*64 + lane)*8];
    a3 = __builtin_amdgcn_mfma_f32_32x32x16_f16(ah, bh, a3, 0, 0, 0);
    a3 = __builtin_amdgcn_mfma_f32_32x32x16_f16(al, bh, a3, 0, 0, 0);
    a3 = __builtin_amdgcn_mfma_f32_32x32x16_f16(ah, bl, a3, 0, 0, 0);
  }

  // ---- store: fmap NHWC-32 (c29..31 zero-padded), rgb residual to out
  bf16* fb = fmap + (size_t)bz*fmap_bs;
  float* ob = outrgb + (size_t)bz*out_bs;
  const int c = l31;
  #pragma unroll
  for (int g = 0; g < 4; ++g){
    const int r0 = 8*g + 4*h5;
    float vs[4];
    #pragma unroll
    for (int k = 0; k < 4; ++k){
      float zz = hbuf[wv][r0 + k][137];
      vs[k] = (zz > 0.f) ? a3[g*4 + k] : 1.0f;
    }
    const size_t p = (size_t)(prel + r0);
    if (c < 29){
      #pragma unroll
      for (int k = 0; k < 4; ++k)
        fb[(p + k)*32 + c] = f2bf(vs[k]);         // half-wave writes a full 64B line
    } else {
      float4 fv = { vs[0], vs[1], vs[2], vs[3] };
      *(float4*)(&ob[((size_t)(c - 29) << 18) + p]) = fv;
      #pragma unroll
      for (int k = 0; k < 4; ++k)
        fb[(p + k)*32 + c] = f2bf(0.f);           // K-pad channels
    }
  }
}

// ---------------- conv1 (MFMA): fmap NHWC-32 -> e1T NHWC-64, 3x3 pad1, relu ----------------
__global__ __launch_bounds__(256,2) void conv1_mfma(
    const bf16* __restrict__ fmap32, const short8* __restrict__ wb1,
    bf16* __restrict__ e1T, const float* __restrict__ zpage,
    size_t fmap_bs, size_t e1_bs){
  __shared__ short lds[8192];   // 16384 B (tin 5760 shorts; out-stage 8192)
  const int tid = threadIdx.x;
  const int wv = tid >> 6, lane = tid & 63;
  const int quad = lane >> 4, l15 = lane & 15;

  // bijective XCD swizzle (gridDim.x % 8 == 0: 8192 or 2048)
  const int L = blockIdx.x;
  const int cpx = gridDim.x >> 3;
  const int o = (L & 7)*cpx + (L >> 3);
  const int bx = o & 31;
  const int r2 = o >> 5;
  const int by = r2 & 63;
  const int bz = r2 >> 6;

  const bf16* fb = fmap32 + (size_t)bz*fmap_bs;
  bf16* eb = e1T + (size_t)bz*e1_bs;
  const int oy0 = by*8, ox0 = bx*16;

  // ---- stage tin: 720 x 16B async loads (10 rows x 18 cols x 4 ch-groups)
  for (int r = 0; r < 3; ++r){
    const int d = r*256 + tid;
    const int pairI = d >> 3, slot = d & 7;
    const int sel = slot ^ (pairI & 7);
    const int p = pairI*2 + (sel >> 2);
    const int g = sel & 3;
    const int row = p / 18, col = p - row*18;
    const int gy = oy0 - 1 + row, gx = ox0 - 1 + col;
    const bool ok = (d < 720) && ((unsigned)gy < 512u) && ((unsigned)gx < 512u);
    const void* src = ok
      ? (const void*)&fb[((size_t)((gy<<9) + gx))*32 + g*8]
      : (const void*)zpage;
    __builtin_amdgcn_global_load_lds(
      (const __attribute__((address_space(1))) void*)src,
      (__attribute__((address_space(3))) void*)&lds[d*8],
      16, 0, 0);
  }
  __syncthreads();

  // ---- MFMA: wave wv owns out rows {wv*2, wv*2+1}; 4 co-tiles
  f32x4 acc[2][4];
  #pragma unroll
  for (int i=0;i<2;++i)
    #pragma unroll
    for (int n=0;n<4;++n) acc[i][n] = (f32x4){0.f,0.f,0.f,0.f};

  for (int t = 0; t < 9; ++t){
    const short8* bp = wb1 + ((0*9 + t)*4)*64 + lane;
    const short8* bq = wb1 + ((1*9 + t)*4)*64 + lane;
    short8 bh0 = bp[0], bh1 = bp[64], bh2 = bp[128], bh3 = bp[192];
    short8 bl0 = bq[0], bl1 = bq[64], bl2 = bq[128], bl3 = bq[192];
    const int dy = t/3, dx = t - dy*3;
    #pragma unroll
    for (int i = 0; i < 2; ++i){
      const int py = wv*2 + i + dy;
      const int px = l15 + dx;
      const int p = py*18 + px;
      const int slot = (quad + 4*(p & 1)) ^ ((p >> 1) & 7);
      short8 a = *(const short8*)&lds[((p >> 1)*8 + slot)*8];
      acc[i][0] = __builtin_amdgcn_mfma_f32_16x16x32_bf16(a, bh0, acc[i][0], 0, 0, 0);
      acc[i][1] = __builtin_amdgcn_mfma_f32_16x16x32_bf16(a, bh1, acc[i][1], 0, 0, 0);
      acc[i][2] = __builtin_amdgcn_mfma_f32_16x16x32_bf16(a, bh2, acc[i][2], 0, 0, 0);
      acc[i][3] = __builtin_amdgcn_mfma_f32_16x16x32_bf16(a, bh3, acc[i][3], 0, 0, 0);
      acc[i][0] = __builtin_amdgcn_mfma_f32_16x16x32_bf16(a, bl0, acc[i][0], 0, 0, 0);
      acc[i][1] = __builtin_amdgcn_mfma_f32_16x16x32_bf16(a, bl1, acc[i][1], 0, 0, 0);
      acc[i][2] = __builtin_amdgcn_mfma_f32_16x16x32_bf16(a, bl2, acc[i][2], 0, 0, 0);
      acc[i][3] = __builtin_amdgcn_mfma_f32_16x16x32_bf16(a, bl3, acc[i][3], 0, 0, 0);
    }
  }
  __syncthreads();   // tin dead -> out staging

  // ---- epilogue: relu -> bf16, swizzled LDS out [128px][8slot][8ch]
  #pragma unroll
  for (int i = 0; i < 2; ++i){
    const int rowp = wv*2 + i;
    #pragma unroll
    for (int n = 0; n < 4; ++n){
      const int gq = n*2 + (l15 >> 3);
      #pragma unroll
      for (int reg = 0; reg < 4; ++reg){
        const int px = rowp*16 + quad*4 + reg;
        const int slot = gq ^ (px & 7);
        lds[(px*8 + slot)*8 + (l15 & 7)] = f2bfs(fmaxf(acc[i][n][reg], 0.f));
      }
    }
  }
  __syncthreads();
  // ---- coalesced NHWC stores: 4 x short8 per thread
  #pragma unroll
  for (int w = 0; w < 4; ++w){
    const int s = w*256 + tid;
    const int px = s >> 3, g8 = s & 7;
    const int slot = g8 ^ (px & 7);
    short8 v = *(const short8*)&lds[(px*8 + slot)*8];
    const int gy = oy0 + (px >> 4), gx = ox0 + (px & 15);
    *(short8*)((void*)&eb[((size_t)((gy<<9) + gx))*64 + g8*8]) = v;
  }
}

// ---------------- conv2 (MFMA): e1T NHWC -> dT NHWC, 3x3 stride2 SAME (pad_lo=0), relu ----------
__global__ __launch_bounds__(256,2) void conv2_mfma(
    const bf16* __restrict__ e1T, const short8* __restrict__ wb2,
    bf16* __restrict__ dT, const float* __restrict__ zpage,
    size_t e1_bs, size_t dt_bs){
  __shared__ short lds[36864];   // 73728 B
  const int tid = threadIdx.x;
  const int wv = tid >> 6, lane = tid & 63;
  const int quad = lane >> 4, l15 = lane & 15;

  const int L = blockIdx.x;
  const int cpx = gridDim.x >> 3;
  const int o = (L & 7)*cpx + (L >> 3);
  const int bx = o & 15;
  const int r2 = o >> 4;
  const int by = r2 & 31;
  const int bz = r2 >> 5;

  const bf16* eb = e1T + (size_t)bz*e1_bs;
  bf16* db = dT + (size_t)bz*dt_bs;
  const int oy0 = by*8, ox0 = bx*16;
  const int iy0 = oy0*2, ix0 = ox0*2;

  for (int r = 0; r < 18; ++r){
    const int idx = r*256 + tid;
    const int g = idx & 7, p = idx >> 3;
    const int row = p / 33, col = p - row*33;
    const int gy = iy0 + row, gx = ix0 + col;
    const int gs = g ^ ((col >> 1) & 7);
    const bool ok = (p < 561) && (gy < 512) && (gx < 512);
    const void* src = ok
      ? (const void*)&eb[((size_t)((gy<<9) + gx))*64 + gs*8]
      : (const void*)zpage;
    __builtin_amdgcn_global_load_lds(
      (const __attribute__((address_space(1))) void*)src,
      (__attribute__((address_space(3))) void*)&lds[idx*8],
      16, 0, 0);
  }
  __syncthreads();

  f32x4 acc[2][8];
  #pragma unroll
  for (int i=0;i<2;++i)
    #pragma unroll
    for (int n=0;n<8;++n) acc[i][n] = (f32x4){0.f,0.f,0.f,0.f};

  for (int ks = 0; ks < 4; ++ks){
    const int cg = (ks & 1)*4 + quad;
    for (int t = 0; t < 9; ++t){
      const short8* bp = wb2 + ((ks*9 + t)*8)*64 + lane;
      short8 b0 = bp[0],   b1 = bp[64],  b2 = bp[128], b3 = bp[192];
      short8 b4 = bp[256], b5 = bp[320], b6 = bp[384], b7 = bp[448];
      const int dy = t/3, dx = t - dy*3;
      #pragma unroll
      for (int i = 0; i < 2; ++i){
        const int m = wv*2 + i;
        const int py = 2*m + dy;
        const int px = 2*l15 + dx;
        const int slot = cg ^ ((px >> 1) & 7);
        short8 a = *(const short8*)&lds[((py*33 + px)*8 + slot)*8];
        acc[i][0] = __builtin_amdgcn_mfma_f32_16x16x32_bf16(a, b0, acc[i][0], 0, 0, 0);
        acc[i][1] = __builtin_amdgcn_mfma_f32_16x16x32_bf16(a, b1, acc[i][1], 0, 0, 0);
        acc[i][2] = __builtin_amdgcn_mfma_f32_16x16x32_bf16(a, b2, acc[i][2], 0, 0, 0);
        acc[i][3] = __builtin_amdgcn_mfma_f32_16x16x32_bf16(a, b3, acc[i][3], 0, 0, 0);
        acc[i][4] = __builtin_amdgcn_mfma_f32_16x16x32_bf16(a, b4, acc[i][4], 0, 0, 0);
        acc[i][5] = __builtin_amdgcn_mfma_f32_16x16x32_bf16(a, b5, acc[i][5], 0, 0, 0);
        acc[i][6] = __builtin_amdgcn_mfma_f32_16x16x32_bf16(a, b6, acc[i][6], 0, 0, 0);
        acc[i][7] = __builtin_amdgcn_mfma_f32_16x16x32_bf16(a, b7, acc[i][7], 0, 0, 0);
      }
    }
  }
  __syncthreads();

  #pragma unroll
  for (int i = 0; i < 2; ++i){
    const int m = wv*2 + i;
    #pragma unroll
    for (int n = 0; n < 8; ++n){
      #pragma unroll
      for (int reg = 0; reg < 4; ++reg){
        const int col = quad*4 + reg;
        const int px = m*16 + col;
        const int g16 = n*2 + (l15 >> 3);
        const int slot = g16 ^ (px & 15);
        lds[(px*16 + slot)*8 + (l15 & 7)] = f2bfs(fmaxf(acc[i][n][reg], 0.f));
      }
    }
  }
  __syncthreads();
  #pragma unroll
  for (int w = 0; w < 8; ++w){
    const int s = w*256 + tid;
    const int px = s >> 4, g16 = s & 15;
    const int slot = g16 ^ (px & 15);
    short8 v = *(const short8*)&lds[(px*16 + slot)*8];
    const int gy = oy0 + (px >> 4), gx = ox0 + (px & 15);
    *(short8*)((void*)&db[((size_t)((gy<<8) + gx))*128 + g16*8]) = v;
  }
}

// ---------------- conv3 + conv4, both MFMA (R17-exact structure) ----------------
// conv3: K = 192ch as 3 x 64-ch chunks (2 dT compact + 1 e1 m-space, E0+E1 paired).
// LDS: D0|D1|E0|E1 = 6656+6656+13312+13312 = 39936 shorts = 79872 B -> 2 blocks/CU.
// conv4: MFMA over msh: M = out px (16 tiles), K = 64ch x 9t x hi/lo, N = 3 co (pad 16).
__global__ __launch_bounds__(256,2) void conv34_mfma(
    const bf16* __restrict__ dT, const bf16* __restrict__ e1T,
    const short8* __restrict__ wb3, const short8* __restrict__ wb4,
    float* __restrict__ out, const float* __restrict__ zpage,
    size_t dt_bs, size_t e1_bs, size_t out_bs){
  __shared__ short lds[39936];   // 79872 B
  const int tid = threadIdx.x;
  const int wv = tid >> 6, lane = tid & 63;
  const int quad = lane >> 4, l15 = lane & 15;

  const int L = blockIdx.x;
  const int cpx = gridDim.x >> 3;              // gridDim.x % 8 == 0 (4608 or 1152)
  const int o = (L & 7)*cpx + (L >> 3);
  const int bx = o % 18;
  const int rem = o / 18;
  const int by = rem & 63;
  const int bz = rem >> 6;

  const bf16* dTb = dT + (size_t)bz*dt_bs;
  const bf16* e1b = e1T + (size_t)bz*e1_bs;
  float* outb = out + (size_t)bz*out_bs;
  const int gy0 = by * 8;
  const int gx0 = bx * 30;
  const int dy0 = (gy0 >> 1) - 1;
  const int dx0 = (gx0 >> 1) - 1;
  f32x4 acc[5][4];
  #pragma unroll
  for (int i=0;i<5;++i)
    #pragma unroll
    for (int n=0;n<4;++n) acc[i][n] = (f32x4){0.f,0.f,0.f,0.f};

  short* DB0 = lds;
  short* DB1 = lds + 6656;
  short* EB0 = lds + 13312;
  short* EB1 = lds + 26624;

  auto stage_dT = [&](int c, short* db){
    #pragma unroll
    for (int r = 0; r < 4; ++r){
      const int idxb = r*256 + wv*64;
      if (idxb >= 832) continue;
      const int idx = idxb + lane;
      const int p = idx >> 3, g = idx & 7;
      const int prow = p / 17, pcol = p - prow*17;
      const int gyD = dy0 + prow, gxD = dx0 + pcol;
      const int gs = g ^ (pcol & 7);
      const bool ok = (p < 102) && ((unsigned)gyD < 256u) && ((unsigned)gxD < 256u);
      const void* src = ok
        ? (const void*)&dTb[((size_t)((gyD<<8) + gxD))*128 + c*64 + gs*8]
        : (const void*)zpage;
      __builtin_amdgcn_global_load_lds(
        (const __attribute__((address_space(1))) void*)src,
        (__attribute__((address_space(3))) void*)&db[idxb*8],
        16, 0, 0);
    }
  };

  auto stage_e1 = [&](int j, short* eb){
    #pragma unroll
    for (int r = 0; r < 7; ++r){
      const int idxb = r*256 + wv*64;
      if (idxb >= 1664) continue;
      const int idx = idxb + lane;
      const int pos = idx >> 2, cg = idx & 3;
      const int yy = pos / 34, xx = pos - yy*34;
      const int gy = gy0 - 2 + yy, gx = gx0 - 2 + xx;
      const int cs = cg ^ (xx & 3);
      const bool ok = ((unsigned)gy < 512u) && ((unsigned)gx < 512u) && (pos < 408);
      const int pyc = gy & 511, pxc = gx & 511;
      const void* src = ok
        ? (const void*)&e1b[((size_t)((pyc<<9) + pxc))*64 + j*32 + cs*8]
        : (const void*)zpage;
      __builtin_amdgcn_global_load_lds(
        (const __attribute__((address_space(1))) void*)src,
        (__attribute__((address_space(3))) void*)&eb[idxb*8],
        16, 0, 0);
    }
  };

  auto compute_D = [&](int c, const short* db){
    #pragma unroll
    for (int ks = 0; ks < 2; ++ks){
      const int kc = c*2 + ks;
      int bb = (kc*9*4)*64 + lane;
      short8 bc0 = wb3[bb], bc1 = wb3[bb+64], bc2 = wb3[bb+128], bc3 = wb3[bb+192];
      for (int t = 0; t < 9; ++t){
        short8 bn0, bn1, bn2, bn3;
        if (t < 8){
          const int b2 = bb + 256;
          bn0 = wb3[b2]; bn1 = wb3[b2+64]; bn2 = wb3[b2+128]; bn3 = wb3[b2+192];
        }
        const int dy = t/3, dx = t - dy*3;
        #pragma unroll
        for (int i = 0; i < 5; ++i){
          const int mt = wv*5 + i;
          const int r = mt >> 1, h = mt & 1;
          const int px = h*16 + l15 + dx;
          const int py = r + dy;
          const int p = (py >> 1)*17 + (px >> 1);
          const int g = (ks*4 + quad) ^ ((px >> 1) & 7);
          short8 a = *(const short8*)&db[p*64 + g*8];
          acc[i][0] = __builtin_amdgcn_mfma_f32_16x16x32_bf16(a, bc0, acc[i][0], 0, 0, 0);
          acc[i][1] = __builtin_amdgcn_mfma_f32_16x16x32_bf16(a, bc1, acc[i][1], 0, 0, 0);
          acc[i][2] = __builtin_amdgcn_mfma_f32_16x16x32_bf16(a, bc2, acc[i][2], 0, 0, 0);
          acc[i][3] = __builtin_amdgcn_mfma_f32_16x16x32_bf16(a, bc3, acc[i][3], 0, 0, 0);
        }
        if (t < 8){ bc0 = bn0; bc1 = bn1; bc2 = bn2; bc3 = bn3; bb += 256; }
      }
    }
  };

  auto compute_E = [&](int j, const short* tb){
    const int kc = 4 + j;
    int bb = (kc*9*4)*64 + lane;
    short8 bc0 = wb3[bb], bc1 = wb3[bb+64], bc2 = wb3[bb+128], bc3 = wb3[bb+192];
    for (int t = 0; t < 9; ++t){
      short8 bn0, bn1, bn2, bn3;
      if (t < 8){
        const int b2 = bb + 256;
        bn0 = wb3[b2]; bn1 = wb3[b2+64]; bn2 = wb3[b2+128]; bn3 = wb3[b2+192];
      }
      const int dy = t/3, dx = t - dy*3;
      #pragma unroll
      for (int i = 0; i < 5; ++i){
        const int mt = wv*5 + i;
        const int r = mt >> 1, h = mt & 1;
        const int px = h*16 + l15 + dx;
        const int py = r + dy;
        const int g = quad ^ (px & 3);
        short8 a = *(const short8*)&tb[(py*34 + px)*32 + g*8];
        acc[i][0] = __builtin_amdgcn_mfma_f32_16x16x32_bf16(a, bc0, acc[i][0], 0, 0, 0);
        acc[i][1] = __builtin_amdgcn_mfma_f32_16x16x32_bf16(a, bc1, acc[i][1], 0, 0, 0);
        acc[i][2] = __builtin_amdgcn_mfma_f32_16x16x32_bf16(a, bc2, acc[i][2], 0, 0, 0);
        acc[i][3] = __builtin_amdgcn_mfma_f32_16x16x32_bf16(a, bc3, acc[i][3], 0, 0, 0);
      }
      if (t < 8){ bc0 = bn0; bc1 = bn1; bc2 = bn2; bc3 = bn3; bb += 256; }
    }
  };

  stage_dT(0, DB0);
  __syncthreads();

  stage_dT(1, DB1);
  __builtin_amdgcn_sched_barrier(0);
  compute_D(0, DB0);
  __syncthreads();

  stage_e1(0, EB0);
  stage_e1(1, EB1);
  __builtin_amdgcn_sched_barrier(0);
  compute_D(1, DB1);
  __syncthreads();

  compute_E(0, EB0);
  compute_E(1, EB1);

  __syncthreads();   // staging dead -> msh[10][32][64] (swizzled groups)
  // conv3 epilogue: relu + border-zero, write msh
  #pragma unroll
  for (int i = 0; i < 5; ++i){
    const int mt = wv*5 + i;
    const int r = mt >> 1, h = mt & 1;
    const int gym = gy0 - 1 + r;
    #pragma unroll
    for (int reg = 0; reg < 4; ++reg){
      const int mxd = h*16 + quad*4 + reg;
      const int gxm = gx0 - 1 + mxd;
      const bool inim = ((unsigned)gym < 512u) && ((unsigned)gxm < 512u);
      const int key = (mxd & 7) << 3;
      #pragma unroll
      for (int n = 0; n < 4; ++n){
        float v = inim ? fmaxf(acc[i][n][reg], 0.f) : 0.f;
        int c = n*16 + l15;
        lds[(r*32 + mxd)*64 + (c ^ key)] = f2bfs(v);
      }
    }
  }
  __syncthreads();

  // conv4 on MFMA: wave wv owns M-tiles {wv*4..wv*4+3} = (row ly, half h)
  f32x4 a4[4];
  #pragma unroll
  for (int ii = 0; ii < 4; ++ii) a4[ii] = (f32x4){0.f,0.f,0.f,0.f};
  for (int kc = 0; kc < 2; ++kc){
    for (int t = 0; t < 9; ++t){
      short8 bh = wb4[((kc*9) + t)*64 + lane];        // hl=0
      short8 bl = wb4[(((2 + kc)*9) + t)*64 + lane];  // hl=1
      const int dy = t/3, dx = t - dy*3;
      #pragma unroll
      for (int ii = 0; ii < 4; ++ii){
        const int mt4 = wv*4 + ii;
        const int ly = mt4 >> 1, h = mt4 & 1;
        const int r = ly + dy;                 // msh row 0..9
        const int mxd = h*16 + l15 + dx;       // cols >31 read stale LDS; rows masked at store
        const int sg = (kc*4 + quad) ^ (mxd & 7);
        short8 a = *(const short8*)&lds[(r*32 + mxd)*64 + sg*8];
        a4[ii] = __builtin_amdgcn_mfma_f32_16x16x32_bf16(a, bh, a4[ii], 0, 0, 0);
        a4[ii] = __builtin_amdgcn_mfma_f32_16x16x32_bf16(a, bl, a4[ii], 0, 0, 0);
      }
    }
  }
  // store: channel = l15 (0..2), rows = out x; residual already in out
  if (l15 < 3){
    #pragma unroll
    for (int ii = 0; ii < 4; ++ii){
      const int mt4 = wv*4 + ii;
      const int ly = mt4 >> 1, h = mt4 & 1;
      const int oy = gy0 + ly;
      float* op = outb + (((size_t)l15) << 18) + ((size_t)oy << 9);
      #pragma unroll
      for (int reg = 0; reg < 4; ++reg){
        const int lx = h*16 + quad*4 + reg;
        const int ox = gx0 + lx;
        if (lx < 30 && ox < 512)
          op[ox] += a4[ii][reg];
      }
    }
  }
}

static const void* find_by_size(void* const* d_in, const int* in_sizes, int n_in,
                                int want, int occurrence, int fallback_idx){
  int seen = 0;
  for (int i = 0; i < n_in; ++i){
    if (in_sizes[i] == want){
      if (seen == occurrence) return d_in[i];
      ++seen;
    }
  }
  return d_in[fallback_idx];
}

extern "C" void kernel_launch(void* const* d_in, const int* in_sizes, int n_in,
                              void* d_out, int out_size, void* d_ws, size_t ws_size,
                              hipStream_t stream) {
  const float* zbuf = (const float*)find_by_size(d_in, in_sizes, n_in, 1048576, 0, 0);
  const float* ray  = (const float*)find_by_size(d_in, in_sizes, n_in, 7340032, 0, 1);
  const float* w0   = (const float*)find_by_size(d_in, in_sizes, n_in, 768,     0, 4);
  const float* w1   = (const float*)find_by_size(d_in, in_sizes, n_in, 16384,   0, 6);
  const float* w2   = (const float*)find_by_size(d_in, in_sizes, n_in, 4096,    0, 8);
  const float* uk1  = (const float*)find_by_size(d_in, in_sizes, n_in, 16704,   0, 10);
  const float* uk2  = (const float*)find_by_size(d_in, in_sizes, n_in, 73728,   0, 11);
  const float* uk3  = (const float*)find_by_size(d_in, in_sizes, n_in, 110592,  0, 12);
  const float* uk4  = (const float*)find_by_size(d_in, in_sizes, n_in, 1728,    0, 13);

  uint8_t* ws = (uint8_t*)d_ws;
  const int batched = (ws_size >= 0xC000000UL + 0xB0000UL);
  const size_t dt_off = 0;
  const size_t e1_off = batched ? 0x4000000UL : 0x1000000UL;
  const size_t w_off  = batched ? 0xC000000UL : 0x3000000UL;

  bf16* fmapB = (bf16*)(ws + dt_off);      // fmap32 NHWC overlays dT slots
  bf16* dTB   = (bf16*)(ws + dt_off);
  bf16* e1B   = (bf16*)(ws + e1_off);
  short* wb1  = (short*)(ws + w_off + WB1_R);
  short* wb2  = (short*)(ws + w_off + WB2_R);
  short* wb3  = (short*)(ws + w_off + WB3_R);
  short* wb4  = (short*)(ws + w_off + WB4_R);
  unsigned short* wfmlp = (unsigned short*)(ws + w_off + WMLP_R);
  float* zp   = (float*)(ws + w_off + WZERO_R);
  float* outp = (float*)d_out;

  prep_kernel<<<1404, 256, 0, stream>>>(uk1, uk2, uk3, uk4, w0, w1, w2,
                                        wb1, wb2, wb3, wb4, wfmlp, zp);

  if (batched){
    mlp_mfma<<<8192, 256, 0, stream>>>(zbuf, ray, wfmlp, fmapB, outp, DT_BS, OUT_BS);
    conv1_mfma<<<8192, 256, 0, stream>>>(fmapB, (const short8*)wb1, e1B, zp, DT_BS, E1_BS);
    conv2_mfma<<<2048, 256, 0, stream>>>(e1B, (const short8*)wb2, dTB, zp, E1_BS, DT_BS);
    conv34_mfma<<<4608, 256, 0, stream>>>(dTB, e1B, (const short8*)wb3, (const short8*)wb4,
                                          outp, zp, DT_BS, E1_BS, OUT_BS);
  } else {
    for (int b = 0; b < 4; ++b){
      float* outb = outp + (size_t)b*OUT_BS;
      mlp_mfma<<<2048, 256, 0, stream>>>(zbuf + (size_t)b*262144,
                                         ray  + (size_t)b*262144*7,
                                         wfmlp, fmapB, outb, DT_BS, OUT_BS);
      conv1_mfma<<<2048, 256, 0, stream>>>(fmapB, (const short8*)wb1, e1B, zp, DT_BS, E1_BS);
      conv2_mfma<<<512, 256, 0, stream>>>(e1B, (const short8*)wb2, dTB, zp, E1_BS, DT_BS);
      conv34_mfma<<<1152, 256, 0, stream>>>(dTB, e1B, (const short8*)wb3, (const short8*)wb4,
                                            outb, zp, DT_BS, E1_BS, OUT_BS);
    }
  }
}

// Round 11
// 683.937 us; speedup vs baseline: 1.4928x; 1.0944x over previous
//
#include <hip/hip_runtime.h>
#include <hip/hip_bf16.h>
#include <stdint.h>

typedef __hip_bfloat16 bf16;
typedef __attribute__((ext_vector_type(8))) short short8;
typedef __attribute__((ext_vector_type(4))) float f32x4;
typedef __attribute__((ext_vector_type(16))) float f32x16;
typedef __attribute__((ext_vector_type(8))) _Float16 half8;

__device__ __forceinline__ float bf2f(bf16 x){ return __bfloat162float(x); }
__device__ __forceinline__ bf16  f2bf(float x){ return __float2bfloat16(x); }
__device__ __forceinline__ short f2bfs(float x){ union { bf16 h; short s; } u; u.h = f2bf(x); return u.s; }
__device__ __forceinline__ float bfs2f(short s){ union { bf16 h; short t; } u; u.t = s; return bf2f(u.h); }

// R21: fold upsample into conv3's D-part (parity trick). conv34 was MFMA-pipe-bound
// (52% MfmaUtil = 427K cyc of matrix work vs 770K total). upsample(d)*W3 multiplies
// each d value 4x; per output parity (py,px) it collapses to a 2x2 conv on d with
// SUMMED weights -> D MFMAs/wave 720->320, total 1224->824 (-33%).
// Each wave owns one parity class (5 rows x 16 cols of the 10x32 msh tile).
// E staged as one [12][34][64] buffer, slot = g ^ ((x>>1)&7) (2-way, free).
// LDS 78848B. Weight region grows to 835584B (fallback path needs only 51MB).
// Batched layout: dT[4]@0x0 (16MiB slots, fmap32 overlays), e1T[4]@0x4000000,
// weights@0xC000000. Fallback: dT/fmap@0x0, e1T@0x1000000, weights@0x3000000.
// Weight region: wb1|wb2|wbD|wbE|wb4|wfmlp|zpage
#define WB1_R   0UL                          // 2*9*4*64*8*2    = 73728
#define WB2_R   73728UL                      // 4*9*8*64*8*2    = 294912
#define WBD_R   368640UL                     // 4par*16*4*64*8*2= 262144
#define WBE_R   630784UL                     // 18*4*64*8*2     = 73728
#define WB4_R   704512UL                     // 4*9*64*8*2      = 36864
#define WMLP_R  741376UL                     // 45056 u16       = 90112
#define WZERO_R 831488UL                     // 4096 B zeros -> end 835584
#define W_TOTAL 835584UL
#define DT_BS   8388608UL                    // bf16 elems per batch slot (16 MiB)
#define E1_BS   16777216UL                   // bf16 elems per batch slot (32 MiB)
#define OUT_BS  786432UL                     // f32 elems per batch (3*512*512)

// ---------------- fused prep: wb1|wb2|wbD|wbE|wb4|mlp_frag|zero ----------------
__global__ void prep_kernel(const float* __restrict__ uk1, const float* __restrict__ uk2,
                            const float* __restrict__ uk3, const float* __restrict__ uk4,
                            const float* __restrict__ w0, const float* __restrict__ w1,
                            const float* __restrict__ w2,
                            short* __restrict__ wb1, short* __restrict__ wb2,
                            short* __restrict__ wbD, short* __restrict__ wbE,
                            short* __restrict__ wb4,
                            unsigned short* __restrict__ wfmlp, float* __restrict__ zp){
  int gidx = blockIdx.x*256 + threadIdx.x;
  if (gidx < 36864){
    int idx = gidx;
    int j = idx & 7, lane = (idx >> 3) & 63, n = (idx >> 9) & 3, ch = idx >> 11;
    int t = ch % 9, hl = ch / 9;
    int co = n*16 + (lane & 15);
    int ci = (lane >> 4)*8 + j;
    float val = (ci < 29) ? uk1[(co*29 + ci)*9 + t] : 0.f;
    short hi = f2bfs(val);
    wb1[idx] = hl ? f2bfs(val - bfs2f(hi)) : hi;
  } else if (gidx < 184320){
    int idx = gidx - 36864;
    int j    = idx & 7;
    int lane = (idx >> 3) & 63;
    int n    = (idx >> 9) & 7;
    int kt   = idx >> 12;            // kk*9 + t
    int t = kt % 9, kk = kt / 9;
    int co = n*16 + (lane & 15);
    int ci = (kk & 1)*32 + (lane >> 4)*8 + j;
    float val = uk2[(co*64 + ci)*9 + t];
    short hi = f2bfs(val);
    wb2[idx] = (kk < 2) ? hi : f2bfs(val - bfs2f(hi));
  } else if (gidx < 315392){
    // conv3 D-part parity-folded 2x2 weights:
    // wbD[((par*16+kD)*4+n)*64+lane][j], par=pr*2+pc, kD=((c*2+ks)*2+jy)*2+jx
    int idx = gidx - 184320;
    int j    = idx & 7;
    int lane = (idx >> 3) & 63;
    int n    = (idx >> 9) & 3;
    int kD   = (idx >> 11) & 15;
    int par  = idx >> 15;            // 0..3
    int pr = par >> 1, pc = par & 1;
    int jx = kD & 1, jy = (kD >> 1) & 1, ks = (kD >> 2) & 1, c = kD >> 3;
    int co = n*16 + (lane & 15);
    int ci = (c*2 + ks)*32 + (lane >> 4)*8 + j;
    int ty0, ty1, tx0, tx1;
    if (pr == 0){ ty0 = jy ? 1 : 0; ty1 = jy ? 2 : 0; }
    else        { ty0 = jy ? 2 : 0; ty1 = jy ? 2 : 1; }
    if (pc == 0){ tx0 = jx ? 1 : 0; tx1 = jx ? 2 : 0; }
    else        { tx0 = jx ? 2 : 0; tx1 = jx ? 2 : 1; }
    float val = 0.f;
    for (int ty = ty0; ty <= ty1; ++ty)
      for (int tx = tx0; tx <= tx1; ++tx)
        val += uk3[(co*192 + ci)*9 + ty*3 + tx];
    wbD[idx] = f2bfs(val);
  } else if (gidx < 352256){
    // conv3 E-part: wbE[((t*2+ks2)*4+n)*64+lane][j], ci = 128+ks2*32+...
    int idx = gidx - 315392;
    int j    = idx & 7;
    int lane = (idx >> 3) & 63;
    int n    = (idx >> 9) & 3;
    int chunk = idx >> 11;           // 0..17 = t*2+ks2
    int ks2 = chunk & 1, t = chunk >> 1;
    int co = n*16 + (lane & 15);
    int ci = 128 + ks2*32 + (lane >> 4)*8 + j;
    wbE[idx] = f2bfs(uk3[(co*192 + ci)*9 + t]);
  } else if (gidx < 370688){
    int idx = gidx - 352256;
    int j = idx & 7, lane = (idx >> 3) & 63, rt = idx >> 9;   // rt = (hl*2+kc)*9+t
    int t = rt % 9, r = rt / 9;
    int kc = r & 1, hl = r >> 1;
    int co = lane & 15;
    int ci = kc*32 + (lane >> 4)*8 + j;
    float val = (co < 3) ? uk4[(co*64 + ci)*9 + t] : 0.f;
    short hi = f2bfs(val);
    wb4[idx] = hl ? f2bfs(val - bfs2f(hi)) : hi;
  } else if (gidx < 415744){
    int idx = gidx - 370688;
    int j = idx & 7;
    int chunk = idx >> 3;
    int lane = chunk & 63;
    int hi5 = lane >> 5, l31 = lane & 31;
    int rest = chunk >> 6;
    float val; int hl;
    if (rest < 8){
      hl = rest & 1; int n = rest >> 1;
      int k = hi5*8 + j, co = n*32 + l31;
      val = (k < 6) ? w0[k*128 + co] : 0.f;
    } else if (rest < 72){
      int r = rest - 8; hl = r & 1; int n = (r>>1)&3, ks = r>>3;
      int k = ks*16 + hi5*8 + j, co = n*32 + l31;
      val = w1[k*128 + co];
    } else {
      int r = rest - 72; hl = r & 1; int ks = r>>1;
      int k = ks*16 + hi5*8 + j, co = l31;
      val = w2[k*32 + co];
    }
    _Float16 h = (_Float16)val;
    _Float16 o = hl ? (_Float16)(val - (float)h) : h;
    union { _Float16 f; unsigned short u; } cv; cv.f = o;
    wfmlp[idx] = cv.u;
  } else if (gidx < 416768){
    zp[gidx - 415744] = 0.f;
  }
}

// ---------------- per-pixel MLP on MFMA: 6 -> 128 -> 128 -> 32 (fmap NHWC-32) ----------------
__global__ __launch_bounds__(256,2) void mlp_mfma(
    const float* __restrict__ zbuf, const float* __restrict__ ray,
    const unsigned short* __restrict__ wf,
    bf16* __restrict__ fmap, float* __restrict__ outrgb,
    size_t fmap_bs, size_t out_bs){
  __shared__ __align__(16) float hbuf[4][32][140];     // 71680 B
  const int tid = threadIdx.x;
  const int wv = tid >> 6, lane = tid & 63, h5 = lane >> 5, l31 = lane & 31;
  const int mbase = (blockIdx.x*4 + wv)*32;
  const int bz = mbase >> 18;
  const int prel = mbase & 262143;

  const float* rp = ray + (size_t)(mbase + l31)*7;
  float z  = zbuf[mbase + l31];
  float d0 = rp[3], d1 = rp[4], d2 = rp[5];
  float inv = z / rp[6];
  half8 a1h = {}; half8 a1l = {};
  if (h5 == 0){
    float f[6] = { rp[0]+d0*inv, rp[1]+d1*inv, rp[2]+d2*inv, d0, d1, d2 };
    #pragma unroll
    for (int j = 0; j < 6; ++j){
      _Float16 hi = (_Float16)f[j];
      a1h[j] = hi;
      a1l[j] = (_Float16)(f[j] - (float)hi);
    }
  }
  hbuf[wv][l31][137] = z;

  // ---- layer 1
  f32x16 acc[4];
  #pragma unroll
  for (int n = 0; n < 4; ++n){
    half8 bh = *(const half8*)&wf[((n*2+0)*64 + lane)*8];
    half8 bl = *(const half8*)&wf[((n*2+1)*64 + lane)*8];
    f32x16 a = {};
    a = __builtin_amdgcn_mfma_f32_32x32x16_f16(a1h, bh, a, 0, 0, 0);
    a = __builtin_amdgcn_mfma_f32_32x32x16_f16(a1l, bh, a, 0, 0, 0);
    a = __builtin_amdgcn_mfma_f32_32x32x16_f16(a1h, bl, a, 0, 0, 0);
    acc[n] = a;
  }
  #pragma unroll
  for (int n = 0; n < 4; ++n)
    #pragma unroll
    for (int reg = 0; reg < 16; ++reg)
      hbuf[wv][(reg&3) + 8*(reg>>2) + 4*h5][n*32 + l31] = fmaxf(acc[n][reg], 0.f);

  // ---- layer 2
  f32x16 acc2[4];
  #pragma unroll
  for (int n = 0; n < 4; ++n) acc2[n] = (f32x16){};
  #pragma unroll
  for (int ks = 0; ks < 8; ++ks){
    const float4* hp = (const float4*)&hbuf[wv][l31][ks*16 + h5*8];
    float4 v0 = hp[0], v1 = hp[1];
    float hv[8] = { v0.x, v0.y, v0.z, v0.w, v1.x, v1.y, v1.z, v1.w };
    half8 ah, al;
    #pragma unroll
    for (int j = 0; j < 8; ++j){
      _Float16 hi = (_Float16)hv[j];
      ah[j] = hi;
      al[j] = (_Float16)(hv[j] - (float)hi);
    }
    #pragma unroll
    for (int n = 0; n < 4; ++n){
      half8 bh = *(const half8*)&wf[(512 + ((ks*4+n)*2+0)*64 + lane)*8];
      half8 bl = *(const half8*)&wf[(512 + ((ks*4+n)*2+1)*64 + lane)*8];
      acc2[n] = __builtin_amdgcn_mfma_f32_32x32x16_f16(ah, bh, acc2[n], 0, 0, 0);
      acc2[n] = __builtin_amdgcn_mfma_f32_32x32x16_f16(al, bh, acc2[n], 0, 0, 0);
      acc2[n] = __builtin_amdgcn_mfma_f32_32x32x16_f16(ah, bl, acc2[n], 0, 0, 0);
    }
  }
  #pragma unroll
  for (int n = 0; n < 4; ++n)
    #pragma unroll
    for (int reg = 0; reg < 16; ++reg)
      hbuf[wv][(reg&3) + 8*(reg>>2) + 4*h5][n*32 + l31] = fmaxf(acc2[n][reg], 0.f);

  // ---- layer 3
  f32x16 a3 = {};
  #pragma unroll
  for (int ks = 0; ks < 8; ++ks){
    const float4* hp = (const float4*)&hbuf[wv][l31][ks*16 + h5*8];
    float4 v0 = hp[0], v1 = hp[1];
    float hv[8] = { v0.x, v0.y, v0.z, v0.w, v1.x, v1.y, v1.z, v1.w };
    half8 ah, al;
    #pragma unroll
    for (int j = 0; j < 8; ++j){
      _Float16 hi = (_Float16)hv[j];
      ah[j] = hi;
      al[j] = (_Float16)(hv[j] - (float)hi);
    }
    half8 bh = *(const half8*)&wf[(4608 + (ks*2+0)*64 + lane)*8];
    half8 bl = *(const half8*)&wf[(4608 + (ks*2+1)*64 + lane)*8];
    a3 = __builtin_amdgcn_mfma_f32_32x32x16_f16(ah, bh, a3, 0, 0, 0);
    a3 = __builtin_amdgcn_mfma_f32_32x32x16_f16(al, bh, a3, 0, 0, 0);
    a3 = __builtin_amdgcn_mfma_f32_32x32x16_f16(ah, bl, a3, 0, 0, 0);
  }

  // ---- store: fmap NHWC-32 (c29..31 zero-padded), rgb residual to out
  bf16* fb = fmap + (size_t)bz*fmap_bs;
  float* ob = outrgb + (size_t)bz*out_bs;
  const int c = l31;
  #pragma unroll
  for (int g = 0; g < 4; ++g){
    const int r0 = 8*g + 4*h5;
    float vs[4];
    #pragma unroll
    for (int k = 0; k < 4; ++k){
      float zz = hbuf[wv][r0 + k][137];
      vs[k] = (zz > 0.f) ? a3[g*4 + k] : 1.0f;
    }
    const size_t p = (size_t)(prel + r0);
    if (c < 29){
      #pragma unroll
      for (int k = 0; k < 4; ++k)
        fb[(p + k)*32 + c] = f2bf(vs[k]);
    } else {
      float4 fv = { vs[0], vs[1], vs[2], vs[3] };
      *(float4*)(&ob[((size_t)(c - 29) << 18) + p]) = fv;
      #pragma unroll
      for (int k = 0; k < 4; ++k)
        fb[(p + k)*32 + c] = f2bf(0.f);
    }
  }
}

// ---------------- conv1 (MFMA): fmap NHWC-32 -> e1T NHWC-64, 3x3 pad1, relu ----------------
__global__ __launch_bounds__(256,2) void conv1_mfma(
    const bf16* __restrict__ fmap32, const short8* __restrict__ wb1,
    bf16* __restrict__ e1T, const float* __restrict__ zpage,
    size_t fmap_bs, size_t e1_bs){
  __shared__ short lds[8192];
  const int tid = threadIdx.x;
  const int wv = tid >> 6, lane = tid & 63;
  const int quad = lane >> 4, l15 = lane & 15;

  const int L = blockIdx.x;
  const int cpx = gridDim.x >> 3;
  const int o = (L & 7)*cpx + (L >> 3);
  const int bx = o & 31;
  const int r2 = o >> 5;
  const int by = r2 & 63;
  const int bz = r2 >> 6;

  const bf16* fb = fmap32 + (size_t)bz*fmap_bs;
  bf16* eb = e1T + (size_t)bz*e1_bs;
  const int oy0 = by*8, ox0 = bx*16;

  for (int r = 0; r < 3; ++r){
    const int d = r*256 + tid;
    const int pairI = d >> 3, slot = d & 7;
    const int sel = slot ^ (pairI & 7);
    const int p = pairI*2 + (sel >> 2);
    const int g = sel & 3;
    const int row = p / 18, col = p - row*18;
    const int gy = oy0 - 1 + row, gx = ox0 - 1 + col;
    const bool ok = (d < 720) && ((unsigned)gy < 512u) && ((unsigned)gx < 512u);
    const void* src = ok
      ? (const void*)&fb[((size_t)((gy<<9) + gx))*32 + g*8]
      : (const void*)zpage;
    __builtin_amdgcn_global_load_lds(
      (const __attribute__((address_space(1))) void*)src,
      (__attribute__((address_space(3))) void*)&lds[d*8],
      16, 0, 0);
  }
  __syncthreads();

  f32x4 acc[2][4];
  #pragma unroll
  for (int i=0;i<2;++i)
    #pragma unroll
    for (int n=0;n<4;++n) acc[i][n] = (f32x4){0.f,0.f,0.f,0.f};

  for (int t = 0; t < 9; ++t){
    const short8* bp = wb1 + ((0*9 + t)*4)*64 + lane;
    const short8* bq = wb1 + ((1*9 + t)*4)*64 + lane;
    short8 bh0 = bp[0], bh1 = bp[64], bh2 = bp[128], bh3 = bp[192];
    short8 bl0 = bq[0], bl1 = bq[64], bl2 = bq[128], bl3 = bq[192];
    const int dy = t/3, dx = t - dy*3;
    #pragma unroll
    for (int i = 0; i < 2; ++i){
      const int py = wv*2 + i + dy;
      const int px = l15 + dx;
      const int p = py*18 + px;
      const int slot = (quad + 4*(p & 1)) ^ ((p >> 1) & 7);
      short8 a = *(const short8*)&lds[((p >> 1)*8 + slot)*8];
      acc[i][0] = __builtin_amdgcn_mfma_f32_16x16x32_bf16(a, bh0, acc[i][0], 0, 0, 0);
      acc[i][1] = __builtin_amdgcn_mfma_f32_16x16x32_bf16(a, bh1, acc[i][1], 0, 0, 0);
      acc[i][2] = __builtin_amdgcn_mfma_f32_16x16x32_bf16(a, bh2, acc[i][2], 0, 0, 0);
      acc[i][3] = __builtin_amdgcn_mfma_f32_16x16x32_bf16(a, bh3, acc[i][3], 0, 0, 0);
      acc[i][0] = __builtin_amdgcn_mfma_f32_16x16x32_bf16(a, bl0, acc[i][0], 0, 0, 0);
      acc[i][1] = __builtin_amdgcn_mfma_f32_16x16x32_bf16(a, bl1, acc[i][1], 0, 0, 0);
      acc[i][2] = __builtin_amdgcn_mfma_f32_16x16x32_bf16(a, bl2, acc[i][2], 0, 0, 0);
      acc[i][3] = __builtin_amdgcn_mfma_f32_16x16x32_bf16(a, bl3, acc[i][3], 0, 0, 0);
    }
  }
  __syncthreads();

  #pragma unroll
  for (int i = 0; i < 2; ++i){
    const int rowp = wv*2 + i;
    #pragma unroll
    for (int n = 0; n < 4; ++n){
      const int gq = n*2 + (l15 >> 3);
      #pragma unroll
      for (int reg = 0; reg < 4; ++reg){
        const int px = rowp*16 + quad*4 + reg;
        const int slot = gq ^ (px & 7);
        lds[(px*8 + slot)*8 + (l15 & 7)] = f2bfs(fmaxf(acc[i][n][reg], 0.f));
      }
    }
  }
  __syncthreads();
  #pragma unroll
  for (int w = 0; w < 4; ++w){
    const int s = w*256 + tid;
    const int px = s >> 3, g8 = s & 7;
    const int slot = g8 ^ (px & 7);
    short8 v = *(const short8*)&lds[(px*8 + slot)*8];
    const int gy = oy0 + (px >> 4), gx = ox0 + (px & 15);
    *(short8*)((void*)&eb[((size_t)((gy<<9) + gx))*64 + g8*8]) = v;
  }
}

// ---------------- conv2 (MFMA): e1T NHWC -> dT NHWC, 3x3 stride2 SAME (pad_lo=0), relu ----------
__global__ __launch_bounds__(256,2) void conv2_mfma(
    const bf16* __restrict__ e1T, const short8* __restrict__ wb2,
    bf16* __restrict__ dT, const float* __restrict__ zpage,
    size_t e1_bs, size_t dt_bs){
  __shared__ short lds[36864];
  const int tid = threadIdx.x;
  const int wv = tid >> 6, lane = tid & 63;
  const int quad = lane >> 4, l15 = lane & 15;

  const int L = blockIdx.x;
  const int cpx = gridDim.x >> 3;
  const int o = (L & 7)*cpx + (L >> 3);
  const int bx = o & 15;
  const int r2 = o >> 4;
  const int by = r2 & 31;
  const int bz = r2 >> 5;

  const bf16* eb = e1T + (size_t)bz*e1_bs;
  bf16* db = dT + (size_t)bz*dt_bs;
  const int oy0 = by*8, ox0 = bx*16;
  const int iy0 = oy0*2, ix0 = ox0*2;

  for (int r = 0; r < 18; ++r){
    const int idx = r*256 + tid;
    const int g = idx & 7, p = idx >> 3;
    const int row = p / 33, col = p - row*33;
    const int gy = iy0 + row, gx = ix0 + col;
    const int gs = g ^ ((col >> 1) & 7);
    const bool ok = (p < 561) && (gy < 512) && (gx < 512);
    const void* src = ok
      ? (const void*)&eb[((size_t)((gy<<9) + gx))*64 + gs*8]
      : (const void*)zpage;
    __builtin_amdgcn_global_load_lds(
      (const __attribute__((address_space(1))) void*)src,
      (__attribute__((address_space(3))) void*)&lds[idx*8],
      16, 0, 0);
  }
  __syncthreads();

  f32x4 acc[2][8];
  #pragma unroll
  for (int i=0;i<2;++i)
    #pragma unroll
    for (int n=0;n<8;++n) acc[i][n] = (f32x4){0.f,0.f,0.f,0.f};

  for (int ks = 0; ks < 4; ++ks){
    const int cg = (ks & 1)*4 + quad;
    for (int t = 0; t < 9; ++t){
      const short8* bp = wb2 + ((ks*9 + t)*8)*64 + lane;
      short8 b0 = bp[0],   b1 = bp[64],  b2 = bp[128], b3 = bp[192];
      short8 b4 = bp[256], b5 = bp[320], b6 = bp[384], b7 = bp[448];
      const int dy = t/3, dx = t - dy*3;
      #pragma unroll
      for (int i = 0; i < 2; ++i){
        const int m = wv*2 + i;
        const int py = 2*m + dy;
        const int px = 2*l15 + dx;
        const int slot = cg ^ ((px >> 1) & 7);
        short8 a = *(const short8*)&lds[((py*33 + px)*8 + slot)*8];
        acc[i][0] = __builtin_amdgcn_mfma_f32_16x16x32_bf16(a, b0, acc[i][0], 0, 0, 0);
        acc[i][1] = __builtin_amdgcn_mfma_f32_16x16x32_bf16(a, b1, acc[i][1], 0, 0, 0);
        acc[i][2] = __builtin_amdgcn_mfma_f32_16x16x32_bf16(a, b2, acc[i][2], 0, 0, 0);
        acc[i][3] = __builtin_amdgcn_mfma_f32_16x16x32_bf16(a, b3, acc[i][3], 0, 0, 0);
        acc[i][4] = __builtin_amdgcn_mfma_f32_16x16x32_bf16(a, b4, acc[i][4], 0, 0, 0);
        acc[i][5] = __builtin_amdgcn_mfma_f32_16x16x32_bf16(a, b5, acc[i][5], 0, 0, 0);
        acc[i][6] = __builtin_amdgcn_mfma_f32_16x16x32_bf16(a, b6, acc[i][6], 0, 0, 0);
        acc[i][7] = __builtin_amdgcn_mfma_f32_16x16x32_bf16(a, b7, acc[i][7], 0, 0, 0);
      }
    }
  }
  __syncthreads();

  #pragma unroll
  for (int i = 0; i < 2; ++i){
    const int m = wv*2 + i;
    #pragma unroll
    for (int n = 0; n < 8; ++n){
      #pragma unroll
      for (int reg = 0; reg < 4; ++reg){
        const int col = quad*4 + reg;
        const int px = m*16 + col;
        const int g16 = n*2 + (l15 >> 3);
        const int slot = g16 ^ (px & 15);
        lds[(px*16 + slot)*8 + (l15 & 7)] = f2bfs(fmaxf(acc[i][n][reg], 0.f));
      }
    }
  }
  __syncthreads();
  #pragma unroll
  for (int w = 0; w < 8; ++w){
    const int s = w*256 + tid;
    const int px = s >> 4, g16 = s & 15;
    const int slot = g16 ^ (px & 15);
    short8 v = *(const short8*)&lds[(px*16 + slot)*8];
    const int gy = oy0 + (px >> 4), gx = ox0 + (px & 15);
    *(short8*)((void*)&db[((size_t)((gy<<8) + gx))*128 + g16*8]) = v;
  }
}

// ---------------- conv3 (parity-folded D + E) + conv4, all MFMA ----------------
// Wave wv = parity class (pr,pc) of global msh coords; owns 5 rows x 16 cols of the
// 10x32 msh tile. D: 2x2 conv on compact dT (buffer row = i+jy, col = l15+jx).
// E: 3x3 on e1 m-space [12][34][64], slot = g ^ ((x>>1)&7).
// LDS: DB0|DB1 (2x6656) + EB (26112) = 39424 shorts = 78848 B; msh reuse 20480.
__global__ __launch_bounds__(256,2) void conv34_mfma(
    const bf16* __restrict__ dT, const bf16* __restrict__ e1T,
    const short8* __restrict__ wbD, const short8* __restrict__ wbE,
    const short8* __restrict__ wb4,
    float* __restrict__ out, const float* __restrict__ zpage,
    size_t dt_bs, size_t e1_bs, size_t out_bs){
  __shared__ short lds[39424];   // 78848 B
  const int tid = threadIdx.x;
  const int wv = tid >> 6, lane = tid & 63;
  const int quad = lane >> 4, l15 = lane & 15;

  const int L = blockIdx.x;
  const int cpx = gridDim.x >> 3;              // gridDim.x % 8 == 0 (4608 or 1152)
  const int o = (L & 7)*cpx + (L >> 3);
  const int bx = o % 18;
  const int rem = o / 18;
  const int by = rem & 63;
  const int bz = rem >> 6;

  const bf16* dTb = dT + (size_t)bz*dt_bs;
  const bf16* e1b = e1T + (size_t)bz*e1_bs;
  float* outb = out + (size_t)bz*out_bs;
  const int gy0 = by * 8;              // out rows [gy0, gy0+8); gy0 even
  const int gx0 = bx * 30;             // out cols [gx0, gx0+30); gx0 even
  const int dy0 = (gy0 >> 1) - 1;
  const int dx0 = (gx0 >> 1) - 1;
  // wave parity class: msh tile origin (gy0-1, gx0-1) is odd/odd
  const int rm0 = (wv >> 1) ^ 1;       // tile row offset: r = 2i + rm0
  const int mx0 = (wv & 1) ^ 1;        // tile col offset: mxd = 2cc + mx0
  f32x4 acc[5][4];
  #pragma unroll
  for (int i=0;i<5;++i)
    #pragma unroll
    for (int n=0;n<4;++n) acc[i][n] = (f32x4){0.f,0.f,0.f,0.f};

  short* DB0 = lds;            // 6656 shorts
  short* DB1 = lds + 6656;
  short* EB  = lds + 13312;    // 26112 shorts: [12][34][64] slot-swizzled

  auto stage_dT = [&](int c, short* db){
    #pragma unroll
    for (int r = 0; r < 4; ++r){
      const int idxb = r*256 + wv*64;
      if (idxb >= 832) continue;
      const int idx = idxb + lane;
      const int p = idx >> 3, g = idx & 7;
      const int prow = p / 17, pcol = p - prow*17;
      const int gyD = dy0 + prow, gxD = dx0 + pcol;
      const int gs = g ^ (pcol & 7);
      const bool ok = (p < 102) && ((unsigned)gyD < 256u) && ((unsigned)gxD < 256u);
      const void* src = ok
        ? (const void*)&dTb[((size_t)((gyD<<8) + gxD))*128 + c*64 + gs*8]
        : (const void*)zpage;
      __builtin_amdgcn_global_load_lds(
        (const __attribute__((address_space(1))) void*)src,
        (__attribute__((address_space(3))) void*)&db[idxb*8],
        16, 0, 0);
    }
  };

  // stage e1 [12][34][64]: 3264 x 16B loads, slot = g ^ ((xx>>1)&7)
  auto stage_E = [&](short* eb){
    #pragma unroll
    for (int r = 0; r < 13; ++r){
      const int idxb = r*256 + wv*64;
      if (idxb >= 3264) continue;
      const int idx = idxb + lane;
      const int g = idx & 7, pos = idx >> 3;
      const int yy = pos / 34, xx = pos - yy*34;
      const int gy = gy0 - 2 + yy, gx = gx0 - 2 + xx;
      const int sg = g ^ ((xx >> 1) & 7);
      const bool ok = ((unsigned)gy < 512u) && ((unsigned)gx < 512u);
      const int pyc = gy & 511, pxc = gx & 511;
      const void* src = ok
        ? (const void*)&e1b[((size_t)((pyc<<9) + pxc))*64 + sg*8]
        : (const void*)zpage;
      __builtin_amdgcn_global_load_lds(
        (const __attribute__((address_space(1))) void*)src,
        (__attribute__((address_space(3))) void*)&eb[idxb*8],
        16, 0, 0);
    }
  };

  // D-part: parity-folded 2x2 conv on compact dT chunk c (64 ch)
  auto compute_Dc = [&](int c, const short* db){
    #pragma unroll
    for (int ks = 0; ks < 2; ++ks){
      #pragma unroll
      for (int jy = 0; jy < 2; ++jy){
        #pragma unroll
        for (int jx = 0; jx < 2; ++jx){
          const int kD = ((c*2 + ks)*2 + jy)*2 + jx;
          const short8* bp = wbD + ((size_t)(wv*16 + kD)*4)*64 + lane;
          short8 b0 = bp[0], b1 = bp[64], b2 = bp[128], b3 = bp[192];
          const int pcol = l15 + jx;
          const int g = (ks*4 + quad) ^ (pcol & 7);
          #pragma unroll
          for (int i = 0; i < 5; ++i){
            short8 a = *(const short8*)&db[((i + jy)*17 + pcol)*64 + g*8];
            acc[i][0] = __builtin_amdgcn_mfma_f32_16x16x32_bf16(a, b0, acc[i][0], 0, 0, 0);
            acc[i][1] = __builtin_amdgcn_mfma_f32_16x16x32_bf16(a, b1, acc[i][1], 0, 0, 0);
            acc[i][2] = __builtin_amdgcn_mfma_f32_16x16x32_bf16(a, b2, acc[i][2], 0, 0, 0);
            acc[i][3] = __builtin_amdgcn_mfma_f32_16x16x32_bf16(a, b3, acc[i][3], 0, 0, 0);
          }
        }
      }
    }
  };

  // E-part: 3x3 on e1 m-space, class pixels (stride-2 cols)
  auto compute_E = [&](const short* eb){
    for (int t = 0; t < 9; ++t){
      const int dy = t/3, dx = t - dy*3;
      #pragma unroll
      for (int ks2 = 0; ks2 < 2; ++ks2){
        const short8* bp = wbE + ((size_t)((t*2 + ks2)*4))*64 + lane;
        short8 b0 = bp[0], b1 = bp[64], b2 = bp[128], b3 = bp[192];
        const int px = 2*l15 + mx0 + dx;
        const int g = (ks2*4 + quad) ^ ((px >> 1) & 7);
        #pragma unroll
        for (int i = 0; i < 5; ++i){
          const int row = 2*i + rm0 + dy;
          short8 a = *(const short8*)&eb[(row*34 + px)*64 + g*8];
          acc[i][0] = __builtin_amdgcn_mfma_f32_16x16x32_bf16(a, b0, acc[i][0], 0, 0, 0);
          acc[i][1] = __builtin_amdgcn_mfma_f32_16x16x32_bf16(a, b1, acc[i][1], 0, 0, 0);
          acc[i][2] = __builtin_amdgcn_mfma_f32_16x16x32_bf16(a, b2, acc[i][2], 0, 0, 0);
          acc[i][3] = __builtin_amdgcn_mfma_f32_16x16x32_bf16(a, b3, acc[i][3], 0, 0, 0);
        }
      }
    }
  };

  stage_dT(0, DB0);
  __syncthreads();                              // D0 ready

  stage_dT(1, DB1);                             // prefetch D1
  __builtin_amdgcn_sched_barrier(0);
  compute_Dc(0, DB0);
  __syncthreads();                              // D1 ready

  stage_E(EB);                                  // prefetch full E (line-paired 64ch)
  __builtin_amdgcn_sched_barrier(0);
  compute_Dc(1, DB1);
  __syncthreads();                              // E ready

  compute_E(EB);

  __syncthreads();   // staging dead -> msh[10][32][64] (swizzled groups)
  // conv3 epilogue: relu + border-zero, write class pixels to msh
  #pragma unroll
  for (int i = 0; i < 5; ++i){
    const int r = 2*i + rm0;
    const int gym = gy0 - 1 + r;
    #pragma unroll
    for (int reg = 0; reg < 4; ++reg){
      const int mxd = 2*(quad*4 + reg) + mx0;
      const int gxm = gx0 - 1 + mxd;
      const bool inim = ((unsigned)gym < 512u) && ((unsigned)gxm < 512u);
      const int key = (mxd & 7) << 3;
      #pragma unroll
      for (int n = 0; n < 4; ++n){
        float v = inim ? fmaxf(acc[i][n][reg], 0.f) : 0.f;
        int c = n*16 + l15;
        lds[(r*32 + mxd)*64 + (c ^ key)] = f2bfs(v);
      }
    }
  }
  __syncthreads();

  // conv4 on MFMA: wave wv owns M-tiles {wv*4..wv*4+3} = (row ly, half h)
  f32x4 a4[4];
  #pragma unroll
  for (int ii = 0; ii < 4; ++ii) a4[ii] = (f32x4){0.f,0.f,0.f,0.f};
  for (int kc = 0; kc < 2; ++kc){
    for (int t = 0; t < 9; ++t){
      short8 bh = wb4[((kc*9) + t)*64 + lane];        // hl=0
      short8 bl = wb4[(((2 + kc)*9) + t)*64 + lane];  // hl=1
      const int dy = t/3, dx = t - dy*3;
      #pragma unroll
      for (int ii = 0; ii < 4; ++ii){
        const int mt4 = wv*4 + ii;
        const int ly = mt4 >> 1, h = mt4 & 1;
        const int r = ly + dy;
        const int mxd = h*16 + l15 + dx;       // cols >31 read stale LDS; masked at store
        const int sg = (kc*4 + quad) ^ (mxd & 7);
        short8 a = *(const short8*)&lds[(r*32 + mxd)*64 + sg*8];
        a4[ii] = __builtin_amdgcn_mfma_f32_16x16x32_bf16(a, bh, a4[ii], 0, 0, 0);
        a4[ii] = __builtin_amdgcn_mfma_f32_16x16x32_bf16(a, bl, a4[ii], 0, 0, 0);
      }
    }
  }
  if (l15 < 3){
    #pragma unroll
    for (int ii = 0; ii < 4; ++ii){
      const int mt4 = wv*4 + ii;
      const int ly = mt4 >> 1, h = mt4 & 1;
      const int oy = gy0 + ly;
      float* op = outb + (((size_t)l15) << 18) + ((size_t)oy << 9);
      #pragma unroll
      for (int reg = 0; reg < 4; ++reg){
        const int lx = h*16 + quad*4 + reg;
        const int ox = gx0 + lx;
        if (lx < 30 && ox < 512)
          op[ox] += a4[ii][reg];
      }
    }
  }
}

static const void* find_by_size(void* const* d_in, const int* in_sizes, int n_in,
                                int want, int occurrence, int fallback_idx){
  int seen = 0;
  for (int i = 0; i < n_in; ++i){
    if (in_sizes[i] == want){
      if (seen == occurrence) return d_in[i];
      ++seen;
    }
  }
  return d_in[fallback_idx];
}

extern "C" void kernel_launch(void* const* d_in, const int* in_sizes, int n_in,
                              void* d_out, int out_size, void* d_ws, size_t ws_size,
                              hipStream_t stream) {
  const float* zbuf = (const float*)find_by_size(d_in, in_sizes, n_in, 1048576, 0, 0);
  const float* ray  = (const float*)find_by_size(d_in, in_sizes, n_in, 7340032, 0, 1);
  const float* w0   = (const float*)find_by_size(d_in, in_sizes, n_in, 768,     0, 4);
  const float* w1   = (const float*)find_by_size(d_in, in_sizes, n_in, 16384,   0, 6);
  const float* w2   = (const float*)find_by_size(d_in, in_sizes, n_in, 4096,    0, 8);
  const float* uk1  = (const float*)find_by_size(d_in, in_sizes, n_in, 16704,   0, 10);
  const float* uk2  = (const float*)find_by_size(d_in, in_sizes, n_in, 73728,   0, 11);
  const float* uk3  = (const float*)find_by_size(d_in, in_sizes, n_in, 110592,  0, 12);
  const float* uk4  = (const float*)find_by_size(d_in, in_sizes, n_in, 1728,    0, 13);

  uint8_t* ws = (uint8_t*)d_ws;
  const int batched = (ws_size >= 0xC000000UL + W_TOTAL);
  const size_t dt_off = 0;
  const size_t e1_off = batched ? 0x4000000UL : 0x1000000UL;
  const size_t w_off  = batched ? 0xC000000UL : 0x3000000UL;

  bf16* fmapB = (bf16*)(ws + dt_off);      // fmap32 NHWC overlays dT slots
  bf16* dTB   = (bf16*)(ws + dt_off);
  bf16* e1B   = (bf16*)(ws + e1_off);
  short* wb1  = (short*)(ws + w_off + WB1_R);
  short* wb2  = (short*)(ws + w_off + WB2_R);
  short* wbD  = (short*)(ws + w_off + WBD_R);
  short* wbE  = (short*)(ws + w_off + WBE_R);
  short* wb4  = (short*)(ws + w_off + WB4_R);
  unsigned short* wfmlp = (unsigned short*)(ws + w_off + WMLP_R);
  float* zp   = (float*)(ws + w_off + WZERO_R);
  float* outp = (float*)d_out;

  prep_kernel<<<1628, 256, 0, stream>>>(uk1, uk2, uk3, uk4, w0, w1, w2,
                                        wb1, wb2, wbD, wbE, wb4, wfmlp, zp);

  if (batched){
    mlp_mfma<<<8192, 256, 0, stream>>>(zbuf, ray, wfmlp, fmapB, outp, DT_BS, OUT_BS);
    conv1_mfma<<<8192, 256, 0, stream>>>(fmapB, (const short8*)wb1, e1B, zp, DT_BS, E1_BS);
    conv2_mfma<<<2048, 256, 0, stream>>>(e1B, (const short8*)wb2, dTB, zp, E1_BS, DT_BS);
    conv34_mfma<<<4608, 256, 0, stream>>>(dTB, e1B, (const short8*)wbD, (const short8*)wbE,
                                          (const short8*)wb4, outp, zp, DT_BS, E1_BS, OUT_BS);
  } else {
    for (int b = 0; b < 4; ++b){
      float* outb = outp + (size_t)b*OUT_BS;
      mlp_mfma<<<2048, 256, 0, stream>>>(zbuf + (size_t)b*262144,
                                         ray  + (size_t)b*262144*7,
                                         wfmlp, fmapB, outb, DT_BS, OUT_BS);
      conv1_mfma<<<2048, 256, 0, stream>>>(fmapB, (const short8*)wb1, e1B, zp, DT_BS, E1_BS);
      conv2_mfma<<<512, 256, 0, stream>>>(e1B, (const short8*)wb2, dTB, zp, E1_BS, DT_BS);
      conv34_mfma<<<1152, 256, 0, stream>>>(dTB, e1B, (const short8*)wbD, (const short8*)wbE,
                                            (const short8*)wb4, outb, zp, DT_BS, E1_BS, OUT_BS);
    }
  }
}

// Round 13
// 549.190 us; speedup vs baseline: 1.8590x; 1.2454x over previous
//
#include <hip/hip_runtime.h>
#include <hip/hip_bf16.h>
#include <stdint.h>

typedef __hip_bfloat16 bf16;
typedef __attribute__((ext_vector_type(8))) short short8;
typedef __attribute__((ext_vector_type(4))) float f32x4;
typedef __attribute__((ext_vector_type(16))) float f32x16;
typedef __attribute__((ext_vector_type(8))) _Float16 half8;

__device__ __forceinline__ float bf2f(bf16 x){ return __bfloat162float(x); }
__device__ __forceinline__ bf16  f2bf(float x){ return __float2bfloat16(x); }
__device__ __forceinline__ short f2bfs(float x){ union { bf16 h; short s; } u; u.h = f2bf(x); return u.s; }
__device__ __forceinline__ float bfs2f(short s){ union { bf16 h; short t; } u; u.t = s; return bf2f(u.h); }

// R23: fix R22's prep_kernel range bug. R22's wbD branch covered 65536 indices but
// wbD has 131072 ELEMENTS (I sized in bytes): par=idx>>15 never reached {2,3}, so
// conv34 waves 2,3 multiplied uninitialized weights -> absmax 2.05. Same halving on
// wbE (18432 vs 36864). Ranges now element-correct; compute kernels UNCHANGED.
// (R22's actual change stands: single-bf16 weights for conv1/conv2/conv4, 2-term MLP.)
// Weight region: wb1|wb2|wbD|wbE|wb4|wfmlp|zpage
#define WB1_R   0UL                          // 9*4*64*8*2      = 36864 B
#define WB2_R   36864UL                      // 2*9*8*64*8*2    = 147456 B
#define WBD_R   184320UL                     // 4*16*4*64*8*2   = 262144 B
#define WBE_R   446464UL                     // 18*4*64*8*2     = 73728 B
#define WB4_R   520192UL                     // 2*9*64*8*2      = 18432 B
#define WMLP_R  538624UL                     // 22528 u16       = 45056 B
#define WZERO_R 583680UL                     // 4096 B zeros -> end 587776
#define W_TOTAL 587776UL
#define DT_BS   8388608UL                    // bf16 elems per batch slot (16 MiB)
#define E1_BS   16777216UL                   // bf16 elems per batch slot (32 MiB)
#define OUT_BS  786432UL                     // f32 elems per batch (3*512*512)

// ---------------- fused prep: wb1|wb2|wbD|wbE|wb4|mlp_frag|zero (element-indexed) ----------------
__global__ void prep_kernel(const float* __restrict__ uk1, const float* __restrict__ uk2,
                            const float* __restrict__ uk3, const float* __restrict__ uk4,
                            const float* __restrict__ w0, const float* __restrict__ w1,
                            const float* __restrict__ w2,
                            short* __restrict__ wb1, short* __restrict__ wb2,
                            short* __restrict__ wbD, short* __restrict__ wbE,
                            short* __restrict__ wb4,
                            unsigned short* __restrict__ wfmlp, float* __restrict__ zp){
  int gidx = blockIdx.x*256 + threadIdx.x;
  if (gidx < 18432){
    // conv1 B-frags (single bf16): wb1[((t*4)+n)*64+lane][j]   [18432 el]
    int idx = gidx;
    int j = idx & 7, lane = (idx >> 3) & 63, n = (idx >> 9) & 3, t = idx >> 11;
    int co = n*16 + (lane & 15);
    int ci = (lane >> 4)*8 + j;
    float val = (ci < 29) ? uk1[(co*29 + ci)*9 + t] : 0.f;
    wb1[idx] = f2bfs(val);
  } else if (gidx < 92160){
    // conv2 B-frags (single bf16): wb2[((ks*9+t)*8+n)*64+lane][j]   [73728 el]
    int idx = gidx - 18432;
    int j    = idx & 7;
    int lane = (idx >> 3) & 63;
    int n    = (idx >> 9) & 7;
    int kt   = idx >> 12;            // ks*9 + t, 0..17
    int t = kt % 9, ks = kt / 9;
    int co = n*16 + (lane & 15);
    int ci = ks*32 + (lane >> 4)*8 + j;
    wb2[idx] = f2bfs(uk2[(co*64 + ci)*9 + t]);
  } else if (gidx < 223232){
    // conv3 D-part parity-folded 2x2 weights (single bf16, summed in f32) [131072 el]
    int idx = gidx - 92160;
    int j    = idx & 7;
    int lane = (idx >> 3) & 63;
    int n    = (idx >> 9) & 3;
    int kD   = (idx >> 11) & 15;
    int par  = idx >> 15;            // 0..3
    int pr = par >> 1, pc = par & 1;
    int jx = kD & 1, jy = (kD >> 1) & 1, ks = (kD >> 2) & 1, c = kD >> 3;
    int co = n*16 + (lane & 15);
    int ci = (c*2 + ks)*32 + (lane >> 4)*8 + j;
    int ty0, ty1, tx0, tx1;
    if (pr == 0){ ty0 = jy ? 1 : 0; ty1 = jy ? 2 : 0; }
    else        { ty0 = jy ? 2 : 0; ty1 = jy ? 2 : 1; }
    if (pc == 0){ tx0 = jx ? 1 : 0; tx1 = jx ? 2 : 0; }
    else        { tx0 = jx ? 2 : 0; tx1 = jx ? 2 : 1; }
    float val = 0.f;
    for (int ty = ty0; ty <= ty1; ++ty)
      for (int tx = tx0; tx <= tx1; ++tx)
        val += uk3[(co*192 + ci)*9 + ty*3 + tx];
    wbD[idx] = f2bfs(val);
  } else if (gidx < 260096){
    // conv3 E-part: wbE[((t*2+ks2)*4+n)*64+lane][j]   [36864 el]
    int idx = gidx - 223232;
    int j    = idx & 7;
    int lane = (idx >> 3) & 63;
    int n    = (idx >> 9) & 3;
    int chunk = idx >> 11;           // 0..17 = t*2+ks2
    int ks2 = chunk & 1, t = chunk >> 1;
    int co = n*16 + (lane & 15);
    int ci = 128 + ks2*32 + (lane >> 4)*8 + j;
    wbE[idx] = f2bfs(uk3[(co*192 + ci)*9 + t]);
  } else if (gidx < 269312){
    // conv4 B-frags (single bf16): wb4[(kc*9+t)*64+lane][j]   [9216 el]
    int idx = gidx - 260096;
    int j = idx & 7, lane = (idx >> 3) & 63, rt = idx >> 9;   // rt = kc*9+t
    int t = rt % 9, kc = rt / 9;
    int co = lane & 15;
    int ci = kc*32 + (lane >> 4)*8 + j;
    float val = (co < 3) ? uk4[(co*64 + ci)*9 + t] : 0.f;
    wb4[idx] = f2bfs(val);
  } else if (gidx < 291840){
    // MLP single-f16 B-frags [22528 el]: chunk 0..3=w0(n), 4..35=w1(ks*4+n), 36..43=w2(ks)
    int idx = gidx - 269312;
    int j = idx & 7;
    int cl = idx >> 3;
    int lane = cl & 63;
    int chunk = cl >> 6;
    int hi5 = lane >> 5, l31 = lane & 31;
    float val;
    if (chunk < 4){
      int n = chunk;
      int k = hi5*8 + j, co = n*32 + l31;
      val = (k < 6) ? w0[k*128 + co] : 0.f;
    } else if (chunk < 36){
      int c = chunk - 4; int ks = c >> 2, n = c & 3;
      int k = ks*16 + hi5*8 + j, co = n*32 + l31;
      val = w1[k*128 + co];
    } else {
      int ks = chunk - 36;
      int k = ks*16 + hi5*8 + j, co = l31;
      val = w2[k*32 + co];
    }
    union { _Float16 f; unsigned short u; } cv; cv.f = (_Float16)val;
    wfmlp[idx] = cv.u;
  } else if (gidx < 292864){
    zp[gidx - 291840] = 0.f;
  }
}

// ---------------- per-pixel MLP on MFMA: 6 -> 128 -> 128 -> 32 (fmap NHWC-32) ----------------
// Activations split f16 hi/lo (2 MFMAs per GEMM); weights single f16 from global.
__global__ __launch_bounds__(256,2) void mlp_mfma(
    const float* __restrict__ zbuf, const float* __restrict__ ray,
    const unsigned short* __restrict__ wf,
    bf16* __restrict__ fmap, float* __restrict__ outrgb,
    size_t fmap_bs, size_t out_bs){
  __shared__ __align__(16) float hbuf[4][32][140];     // 71680 B
  const int tid = threadIdx.x;
  const int wv = tid >> 6, lane = tid & 63, h5 = lane >> 5, l31 = lane & 31;
  const int mbase = (blockIdx.x*4 + wv)*32;
  const int bz = mbase >> 18;
  const int prel = mbase & 262143;

  const float* rp = ray + (size_t)(mbase + l31)*7;
  float z  = zbuf[mbase + l31];
  float d0 = rp[3], d1 = rp[4], d2 = rp[5];
  float inv = z / rp[6];
  half8 a1h = {}; half8 a1l = {};
  if (h5 == 0){
    float f[6] = { rp[0]+d0*inv, rp[1]+d1*inv, rp[2]+d2*inv, d0, d1, d2 };
    #pragma unroll
    for (int j = 0; j < 6; ++j){
      _Float16 hi = (_Float16)f[j];
      a1h[j] = hi;
      a1l[j] = (_Float16)(f[j] - (float)hi);
    }
  }
  hbuf[wv][l31][137] = z;

  // ---- layer 1 (4 n-chunks x 2 MFMAs)
  f32x16 acc[4];
  #pragma unroll
  for (int n = 0; n < 4; ++n){
    half8 b = *(const half8*)&wf[(n*64 + lane)*8];
    f32x16 a = {};
    a = __builtin_amdgcn_mfma_f32_32x32x16_f16(a1h, b, a, 0, 0, 0);
    a = __builtin_amdgcn_mfma_f32_32x32x16_f16(a1l, b, a, 0, 0, 0);
    acc[n] = a;
  }
  #pragma unroll
  for (int n = 0; n < 4; ++n)
    #pragma unroll
    for (int reg = 0; reg < 16; ++reg)
      hbuf[wv][(reg&3) + 8*(reg>>2) + 4*h5][n*32 + l31] = fmaxf(acc[n][reg], 0.f);

  // ---- layer 2 (8 ks x 4 n x 2 MFMAs)
  f32x16 acc2[4];
  #pragma unroll
  for (int n = 0; n < 4; ++n) acc2[n] = (f32x16){};
  #pragma unroll
  for (int ks = 0; ks < 8; ++ks){
    const float4* hp = (const float4*)&hbuf[wv][l31][ks*16 + h5*8];
    float4 v0 = hp[0], v1 = hp[1];
    float hv[8] = { v0.x, v0.y, v0.z, v0.w, v1.x, v1.y, v1.z, v1.w };
    half8 ah, al;
    #pragma unroll
    for (int j = 0; j < 8; ++j){
      _Float16 hi = (_Float16)hv[j];
      ah[j] = hi;
      al[j] = (_Float16)(hv[j] - (float)hi);
    }
    #pragma unroll
    for (int n = 0; n < 4; ++n){
      half8 b = *(const half8*)&wf[((4 + ks*4 + n)*64 + lane)*8];
      acc2[n] = __builtin_amdgcn_mfma_f32_32x32x16_f16(ah, b, acc2[n], 0, 0, 0);
      acc2[n] = __builtin_amdgcn_mfma_f32_32x32x16_f16(al, b, acc2[n], 0, 0, 0);
    }
  }
  #pragma unroll
  for (int n = 0; n < 4; ++n)
    #pragma unroll
    for (int reg = 0; reg < 16; ++reg)
      hbuf[wv][(reg&3) + 8*(reg>>2) + 4*h5][n*32 + l31] = fmaxf(acc2[n][reg], 0.f);

  // ---- layer 3 (8 ks x 2 MFMAs)
  f32x16 a3 = {};
  #pragma unroll
  for (int ks = 0; ks < 8; ++ks){
    const float4* hp = (const float4*)&hbuf[wv][l31][ks*16 + h5*8];
    float4 v0 = hp[0], v1 = hp[1];
    float hv[8] = { v0.x, v0.y, v0.z, v0.w, v1.x, v1.y, v1.z, v1.w };
    half8 ah, al;
    #pragma unroll
    for (int j = 0; j < 8; ++j){
      _Float16 hi = (_Float16)hv[j];
      ah[j] = hi;
      al[j] = (_Float16)(hv[j] - (float)hi);
    }
    half8 b = *(const half8*)&wf[((36 + ks)*64 + lane)*8];
    a3 = __builtin_amdgcn_mfma_f32_32x32x16_f16(ah, b, a3, 0, 0, 0);
    a3 = __builtin_amdgcn_mfma_f32_32x32x16_f16(al, b, a3, 0, 0, 0);
  }

  // ---- store: fmap NHWC-32 (c29..31 zero-padded), rgb residual to out
  bf16* fb = fmap + (size_t)bz*fmap_bs;
  float* ob = outrgb + (size_t)bz*out_bs;
  const int c = l31;
  #pragma unroll
  for (int g = 0; g < 4; ++g){
    const int r0 = 8*g + 4*h5;
    float vs[4];
    #pragma unroll
    for (int k = 0; k < 4; ++k){
      float zz = hbuf[wv][r0 + k][137];
      vs[k] = (zz > 0.f) ? a3[g*4 + k] : 1.0f;
    }
    const size_t p = (size_t)(prel + r0);
    if (c < 29){
      #pragma unroll
      for (int k = 0; k < 4; ++k)
        fb[(p + k)*32 + c] = f2bf(vs[k]);
    } else {
      float4 fv = { vs[0], vs[1], vs[2], vs[3] };
      *(float4*)(&ob[((size_t)(c - 29) << 18) + p]) = fv;
      #pragma unroll
      for (int k = 0; k < 4; ++k)
        fb[(p + k)*32 + c] = f2bf(0.f);
    }
  }
}

// ---------------- conv1 (MFMA): fmap NHWC-32 -> e1T NHWC-64, 3x3 pad1, relu ----------------
__global__ __launch_bounds__(256,2) void conv1_mfma(
    const bf16* __restrict__ fmap32, const short8* __restrict__ wb1,
    bf16* __restrict__ e1T, const float* __restrict__ zpage,
    size_t fmap_bs, size_t e1_bs){
  __shared__ short lds[8192];
  const int tid = threadIdx.x;
  const int wv = tid >> 6, lane = tid & 63;
  const int quad = lane >> 4, l15 = lane & 15;

  const int L = blockIdx.x;
  const int cpx = gridDim.x >> 3;
  const int o = (L & 7)*cpx + (L >> 3);
  const int bx = o & 31;
  const int r2 = o >> 5;
  const int by = r2 & 63;
  const int bz = r2 >> 6;

  const bf16* fb = fmap32 + (size_t)bz*fmap_bs;
  bf16* eb = e1T + (size_t)bz*e1_bs;
  const int oy0 = by*8, ox0 = bx*16;

  for (int r = 0; r < 3; ++r){
    const int d = r*256 + tid;
    const int pairI = d >> 3, slot = d & 7;
    const int sel = slot ^ (pairI & 7);
    const int p = pairI*2 + (sel >> 2);
    const int g = sel & 3;
    const int row = p / 18, col = p - row*18;
    const int gy = oy0 - 1 + row, gx = ox0 - 1 + col;
    const bool ok = (d < 720) && ((unsigned)gy < 512u) && ((unsigned)gx < 512u);
    const void* src = ok
      ? (const void*)&fb[((size_t)((gy<<9) + gx))*32 + g*8]
      : (const void*)zpage;
    __builtin_amdgcn_global_load_lds(
      (const __attribute__((address_space(1))) void*)src,
      (__attribute__((address_space(3))) void*)&lds[d*8],
      16, 0, 0);
  }
  __syncthreads();

  f32x4 acc[2][4];
  #pragma unroll
  for (int i=0;i<2;++i)
    #pragma unroll
    for (int n=0;n<4;++n) acc[i][n] = (f32x4){0.f,0.f,0.f,0.f};

  for (int t = 0; t < 9; ++t){
    const short8* bp = wb1 + (t*4)*64 + lane;
    short8 b0 = bp[0], b1 = bp[64], b2 = bp[128], b3 = bp[192];
    const int dy = t/3, dx = t - dy*3;
    #pragma unroll
    for (int i = 0; i < 2; ++i){
      const int py = wv*2 + i + dy;
      const int px = l15 + dx;
      const int p = py*18 + px;
      const int slot = (quad + 4*(p & 1)) ^ ((p >> 1) & 7);
      short8 a = *(const short8*)&lds[((p >> 1)*8 + slot)*8];
      acc[i][0] = __builtin_amdgcn_mfma_f32_16x16x32_bf16(a, b0, acc[i][0], 0, 0, 0);
      acc[i][1] = __builtin_amdgcn_mfma_f32_16x16x32_bf16(a, b1, acc[i][1], 0, 0, 0);
      acc[i][2] = __builtin_amdgcn_mfma_f32_16x16x32_bf16(a, b2, acc[i][2], 0, 0, 0);
      acc[i][3] = __builtin_amdgcn_mfma_f32_16x16x32_bf16(a, b3, acc[i][3], 0, 0, 0);
    }
  }
  __syncthreads();

  #pragma unroll
  for (int i = 0; i < 2; ++i){
    const int rowp = wv*2 + i;
    #pragma unroll
    for (int n = 0; n < 4; ++n){
      const int gq = n*2 + (l15 >> 3);
      #pragma unroll
      for (int reg = 0; reg < 4; ++reg){
        const int px = rowp*16 + quad*4 + reg;
        const int slot = gq ^ (px & 7);
        lds[(px*8 + slot)*8 + (l15 & 7)] = f2bfs(fmaxf(acc[i][n][reg], 0.f));
      }
    }
  }
  __syncthreads();
  #pragma unroll
  for (int w = 0; w < 4; ++w){
    const int s = w*256 + tid;
    const int px = s >> 3, g8 = s & 7;
    const int slot = g8 ^ (px & 7);
    short8 v = *(const short8*)&lds[(px*8 + slot)*8];
    const int gy = oy0 + (px >> 4), gx = ox0 + (px & 15);
    *(short8*)((void*)&eb[((size_t)((gy<<9) + gx))*64 + g8*8]) = v;
  }
}

// ---------------- conv2 (MFMA): e1T NHWC -> dT NHWC, 3x3 stride2 SAME (pad_lo=0), relu ----------
__global__ __launch_bounds__(256,2) void conv2_mfma(
    const bf16* __restrict__ e1T, const short8* __restrict__ wb2,
    bf16* __restrict__ dT, const float* __restrict__ zpage,
    size_t e1_bs, size_t dt_bs){
  __shared__ short lds[36864];
  const int tid = threadIdx.x;
  const int wv = tid >> 6, lane = tid & 63;
  const int quad = lane >> 4, l15 = lane & 15;

  const int L = blockIdx.x;
  const int cpx = gridDim.x >> 3;
  const int o = (L & 7)*cpx + (L >> 3);
  const int bx = o & 15;
  const int r2 = o >> 4;
  const int by = r2 & 31;
  const int bz = r2 >> 5;

  const bf16* eb = e1T + (size_t)bz*e1_bs;
  bf16* db = dT + (size_t)bz*dt_bs;
  const int oy0 = by*8, ox0 = bx*16;
  const int iy0 = oy0*2, ix0 = ox0*2;

  for (int r = 0; r < 18; ++r){
    const int idx = r*256 + tid;
    const int g = idx & 7, p = idx >> 3;
    const int row = p / 33, col = p - row*33;
    const int gy = iy0 + row, gx = ix0 + col;
    const int gs = g ^ ((col >> 1) & 7);
    const bool ok = (p < 561) && (gy < 512) && (gx < 512);
    const void* src = ok
      ? (const void*)&eb[((size_t)((gy<<9) + gx))*64 + gs*8]
      : (const void*)zpage;
    __builtin_amdgcn_global_load_lds(
      (const __attribute__((address_space(1))) void*)src,
      (__attribute__((address_space(3))) void*)&lds[idx*8],
      16, 0, 0);
  }
  __syncthreads();

  f32x4 acc[2][8];
  #pragma unroll
  for (int i=0;i<2;++i)
    #pragma unroll
    for (int n=0;n<8;++n) acc[i][n] = (f32x4){0.f,0.f,0.f,0.f};

  for (int ks = 0; ks < 2; ++ks){
    const int cg = ks*4 + quad;
    for (int t = 0; t < 9; ++t){
      const short8* bp = wb2 + ((ks*9 + t)*8)*64 + lane;
      short8 b0 = bp[0],   b1 = bp[64],  b2 = bp[128], b3 = bp[192];
      short8 b4 = bp[256], b5 = bp[320], b6 = bp[384], b7 = bp[448];
      const int dy = t/3, dx = t - dy*3;
      #pragma unroll
      for (int i = 0; i < 2; ++i){
        const int m = wv*2 + i;
        const int py = 2*m + dy;
        const int px = 2*l15 + dx;
        const int slot = cg ^ ((px >> 1) & 7);
        short8 a = *(const short8*)&lds[((py*33 + px)*8 + slot)*8];
        acc[i][0] = __builtin_amdgcn_mfma_f32_16x16x32_bf16(a, b0, acc[i][0], 0, 0, 0);
        acc[i][1] = __builtin_amdgcn_mfma_f32_16x16x32_bf16(a, b1, acc[i][1], 0, 0, 0);
        acc[i][2] = __builtin_amdgcn_mfma_f32_16x16x32_bf16(a, b2, acc[i][2], 0, 0, 0);
        acc[i][3] = __builtin_amdgcn_mfma_f32_16x16x32_bf16(a, b3, acc[i][3], 0, 0, 0);
        acc[i][4] = __builtin_amdgcn_mfma_f32_16x16x32_bf16(a, b4, acc[i][4], 0, 0, 0);
        acc[i][5] = __builtin_amdgcn_mfma_f32_16x16x32_bf16(a, b5, acc[i][5], 0, 0, 0);
        acc[i][6] = __builtin_amdgcn_mfma_f32_16x16x32_bf16(a, b6, acc[i][6], 0, 0, 0);
        acc[i][7] = __builtin_amdgcn_mfma_f32_16x16x32_bf16(a, b7, acc[i][7], 0, 0, 0);
      }
    }
  }
  __syncthreads();

  #pragma unroll
  for (int i = 0; i < 2; ++i){
    const int m = wv*2 + i;
    #pragma unroll
    for (int n = 0; n < 8; ++n){
      #pragma unroll
      for (int reg = 0; reg < 4; ++reg){
        const int col = quad*4 + reg;
        const int px = m*16 + col;
        const int g16 = n*2 + (l15 >> 3);
        const int slot = g16 ^ (px & 15);
        lds[(px*16 + slot)*8 + (l15 & 7)] = f2bfs(fmaxf(acc[i][n][reg], 0.f));
      }
    }
  }
  __syncthreads();
  #pragma unroll
  for (int w = 0; w < 8; ++w){
    const int s = w*256 + tid;
    const int px = s >> 4, g16 = s & 15;
    const int slot = g16 ^ (px & 15);
    short8 v = *(const short8*)&lds[(px*16 + slot)*8];
    const int gy = oy0 + (px >> 4), gx = ox0 + (px & 15);
    *(short8*)((void*)&db[((size_t)((gy<<8) + gx))*128 + g16*8]) = v;
  }
}

// ---------------- conv3 (parity-folded D + E) + conv4, all MFMA ----------------
__global__ __launch_bounds__(256,2) void conv34_mfma(
    const bf16* __restrict__ dT, const bf16* __restrict__ e1T,
    const short8* __restrict__ wbD, const short8* __restrict__ wbE,
    const short8* __restrict__ wb4,
    float* __restrict__ out, const float* __restrict__ zpage,
    size_t dt_bs, size_t e1_bs, size_t out_bs){
  __shared__ short lds[39424];   // 78848 B
  const int tid = threadIdx.x;
  const int wv = tid >> 6, lane = tid & 63;
  const int quad = lane >> 4, l15 = lane & 15;

  const int L = blockIdx.x;
  const int cpx = gridDim.x >> 3;              // gridDim.x % 8 == 0 (4608 or 1152)
  const int o = (L & 7)*cpx + (L >> 3);
  const int bx = o % 18;
  const int rem = o / 18;
  const int by = rem & 63;
  const int bz = rem >> 6;

  const bf16* dTb = dT + (size_t)bz*dt_bs;
  const bf16* e1b = e1T + (size_t)bz*e1_bs;
  float* outb = out + (size_t)bz*out_bs;
  const int gy0 = by * 8;
  const int gx0 = bx * 30;
  const int dy0 = (gy0 >> 1) - 1;
  const int dx0 = (gx0 >> 1) - 1;
  const int rm0 = (wv >> 1) ^ 1;
  const int mx0 = (wv & 1) ^ 1;
  f32x4 acc[5][4];
  #pragma unroll
  for (int i=0;i<5;++i)
    #pragma unroll
    for (int n=0;n<4;++n) acc[i][n] = (f32x4){0.f,0.f,0.f,0.f};

  short* DB0 = lds;
  short* DB1 = lds + 6656;
  short* EB  = lds + 13312;

  auto stage_dT = [&](int c, short* db){
    #pragma unroll
    for (int r = 0; r < 4; ++r){
      const int idxb = r*256 + wv*64;
      if (idxb >= 832) continue;
      const int idx = idxb + lane;
      const int p = idx >> 3, g = idx & 7;
      const int prow = p / 17, pcol = p - prow*17;
      const int gyD = dy0 + prow, gxD = dx0 + pcol;
      const int gs = g ^ (pcol & 7);
      const bool ok = (p < 102) && ((unsigned)gyD < 256u) && ((unsigned)gxD < 256u);
      const void* src = ok
        ? (const void*)&dTb[((size_t)((gyD<<8) + gxD))*128 + c*64 + gs*8]
        : (const void*)zpage;
      __builtin_amdgcn_global_load_lds(
        (const __attribute__((address_space(1))) void*)src,
        (__attribute__((address_space(3))) void*)&db[idxb*8],
        16, 0, 0);
    }
  };

  auto stage_E = [&](short* eb){
    #pragma unroll
    for (int r = 0; r < 13; ++r){
      const int idxb = r*256 + wv*64;
      if (idxb >= 3264) continue;
      const int idx = idxb + lane;
      const int g = idx & 7, pos = idx >> 3;
      const int yy = pos / 34, xx = pos - yy*34;
      const int gy = gy0 - 2 + yy, gx = gx0 - 2 + xx;
      const int sg = g ^ ((xx >> 1) & 7);
      const bool ok = ((unsigned)gy < 512u) && ((unsigned)gx < 512u);
      const int pyc = gy & 511, pxc = gx & 511;
      const void* src = ok
        ? (const void*)&e1b[((size_t)((pyc<<9) + pxc))*64 + sg*8]
        : (const void*)zpage;
      __builtin_amdgcn_global_load_lds(
        (const __attribute__((address_space(1))) void*)src,
        (__attribute__((address_space(3))) void*)&eb[idxb*8],
        16, 0, 0);
    }
  };

  auto compute_Dc = [&](int c, const short* db){
    #pragma unroll
    for (int ks = 0; ks < 2; ++ks){
      #pragma unroll
      for (int jy = 0; jy < 2; ++jy){
        #pragma unroll
        for (int jx = 0; jx < 2; ++jx){
          const int kD = ((c*2 + ks)*2 + jy)*2 + jx;
          const short8* bp = wbD + ((size_t)(wv*16 + kD)*4)*64 + lane;
          short8 b0 = bp[0], b1 = bp[64], b2 = bp[128], b3 = bp[192];
          const int pcol = l15 + jx;
          const int g = (ks*4 + quad) ^ (pcol & 7);
          #pragma unroll
          for (int i = 0; i < 5; ++i){
            short8 a = *(const short8*)&db[((i + jy)*17 + pcol)*64 + g*8];
            acc[i][0] = __builtin_amdgcn_mfma_f32_16x16x32_bf16(a, b0, acc[i][0], 0, 0, 0);
            acc[i][1] = __builtin_amdgcn_mfma_f32_16x16x32_bf16(a, b1, acc[i][1], 0, 0, 0);
            acc[i][2] = __builtin_amdgcn_mfma_f32_16x16x32_bf16(a, b2, acc[i][2], 0, 0, 0);
            acc[i][3] = __builtin_amdgcn_mfma_f32_16x16x32_bf16(a, b3, acc[i][3], 0, 0, 0);
          }
        }
      }
    }
  };

  auto compute_E = [&](const short* eb){
    for (int t = 0; t < 9; ++t){
      const int dy = t/3, dx = t - dy*3;
      #pragma unroll
      for (int ks2 = 0; ks2 < 2; ++ks2){
        const short8* bp = wbE + ((size_t)((t*2 + ks2)*4))*64 + lane;
        short8 b0 = bp[0], b1 = bp[64], b2 = bp[128], b3 = bp[192];
        const int px = 2*l15 + mx0 + dx;
        const int g = (ks2*4 + quad) ^ ((px >> 1) & 7);
        #pragma unroll
        for (int i = 0; i < 5; ++i){
          const int row = 2*i + rm0 + dy;
          short8 a = *(const short8*)&eb[(row*34 + px)*64 + g*8];
          acc[i][0] = __builtin_amdgcn_mfma_f32_16x16x32_bf16(a, b0, acc[i][0], 0, 0, 0);
          acc[i][1] = __builtin_amdgcn_mfma_f32_16x16x32_bf16(a, b1, acc[i][1], 0, 0, 0);
          acc[i][2] = __builtin_amdgcn_mfma_f32_16x16x32_bf16(a, b2, acc[i][2], 0, 0, 0);
          acc[i][3] = __builtin_amdgcn_mfma_f32_16x16x32_bf16(a, b3, acc[i][3], 0, 0, 0);
        }
      }
    }
  };

  stage_dT(0, DB0);
  __syncthreads();

  stage_dT(1, DB1);
  __builtin_amdgcn_sched_barrier(0);
  compute_Dc(0, DB0);
  __syncthreads();

  stage_E(EB);
  __builtin_amdgcn_sched_barrier(0);
  compute_Dc(1, DB1);
  __syncthreads();

  compute_E(EB);

  __syncthreads();   // staging dead -> msh[10][32][64] (swizzled groups)
  #pragma unroll
  for (int i = 0; i < 5; ++i){
    const int r = 2*i + rm0;
    const int gym = gy0 - 1 + r;
    #pragma unroll
    for (int reg = 0; reg < 4; ++reg){
      const int mxd = 2*(quad*4 + reg) + mx0;
      const int gxm = gx0 - 1 + mxd;
      const bool inim = ((unsigned)gym < 512u) && ((unsigned)gxm < 512u);
      const int key = (mxd & 7) << 3;
      #pragma unroll
      for (int n = 0; n < 4; ++n){
        float v = inim ? fmaxf(acc[i][n][reg], 0.f) : 0.f;
        int c = n*16 + l15;
        lds[(r*32 + mxd)*64 + (c ^ key)] = f2bfs(v);
      }
    }
  }
  __syncthreads();

  // conv4 on MFMA (single bf16 weights): wave wv owns M-tiles {wv*4..wv*4+3}
  f32x4 a4[4];
  #pragma unroll
  for (int ii = 0; ii < 4; ++ii) a4[ii] = (f32x4){0.f,0.f,0.f,0.f};
  for (int kc = 0; kc < 2; ++kc){
    for (int t = 0; t < 9; ++t){
      short8 b = wb4[(kc*9 + t)*64 + lane];
      const int dy = t/3, dx = t - dy*3;
      #pragma unroll
      for (int ii = 0; ii < 4; ++ii){
        const int mt4 = wv*4 + ii;
        const int ly = mt4 >> 1, h = mt4 & 1;
        const int r = ly + dy;
        const int mxd = h*16 + l15 + dx;       // cols >31 read stale LDS; masked at store
        const int sg = (kc*4 + quad) ^ (mxd & 7);
        short8 a = *(const short8*)&lds[(r*32 + mxd)*64 + sg*8];
        a4[ii] = __builtin_amdgcn_mfma_f32_16x16x32_bf16(a, b, a4[ii], 0, 0, 0);
      }
    }
  }
  if (l15 < 3){
    #pragma unroll
    for (int ii = 0; ii < 4; ++ii){
      const int mt4 = wv*4 + ii;
      const int ly = mt4 >> 1, h = mt4 & 1;
      const int oy = gy0 + ly;
      float* op = outb + (((size_t)l15) << 18) + ((size_t)oy << 9);
      #pragma unroll
      for (int reg = 0; reg < 4; ++reg){
        const int lx = h*16 + quad*4 + reg;
        const int ox = gx0 + lx;
        if (lx < 30 && ox < 512)
          op[ox] += a4[ii][reg];
      }
    }
  }
}

static const void* find_by_size(void* const* d_in, const int* in_sizes, int n_in,
                                int want, int occurrence, int fallback_idx){
  int seen = 0;
  for (int i = 0; i < n_in; ++i){
    if (in_sizes[i] == want){
      if (seen == occurrence) return d_in[i];
      ++seen;
    }
  }
  return d_in[fallback_idx];
}

extern "C" void kernel_launch(void* const* d_in, const int* in_sizes, int n_in,
                              void* d_out, int out_size, void* d_ws, size_t ws_size,
                              hipStream_t stream) {
  const float* zbuf = (const float*)find_by_size(d_in, in_sizes, n_in, 1048576, 0, 0);
  const float* ray  = (const float*)find_by_size(d_in, in_sizes, n_in, 7340032, 0, 1);
  const float* w0   = (const float*)find_by_size(d_in, in_sizes, n_in, 768,     0, 4);
  const float* w1   = (const float*)find_by_size(d_in, in_sizes, n_in, 16384,   0, 6);
  const float* w2   = (const float*)find_by_size(d_in, in_sizes, n_in, 4096,    0, 8);
  const float* uk1  = (const float*)find_by_size(d_in, in_sizes, n_in, 16704,   0, 10);
  const float* uk2  = (const float*)find_by_size(d_in, in_sizes, n_in, 73728,   0, 11);
  const float* uk3  = (const float*)find_by_size(d_in, in_sizes, n_in, 110592,  0, 12);
  const float* uk4  = (const float*)find_by_size(d_in, in_sizes, n_in, 1728,    0, 13);

  uint8_t* ws = (uint8_t*)d_ws;
  const int batched = (ws_size >= 0xC000000UL + W_TOTAL);
  const size_t dt_off = 0;
  const size_t e1_off = batched ? 0x4000000UL : 0x1000000UL;
  const size_t w_off  = batched ? 0xC000000UL : 0x3000000UL;

  bf16* fmapB = (bf16*)(ws + dt_off);      // fmap32 NHWC overlays dT slots
  bf16* dTB   = (bf16*)(ws + dt_off);
  bf16* e1B   = (bf16*)(ws + e1_off);
  short* wb1  = (short*)(ws + w_off + WB1_R);
  short* wb2  = (short*)(ws + w_off + WB2_R);
  short* wbD  = (short*)(ws + w_off + WBD_R);
  short* wbE  = (short*)(ws + w_off + WBE_R);
  short* wb4  = (short*)(ws + w_off + WB4_R);
  unsigned short* wfmlp = (unsigned short*)(ws + w_off + WMLP_R);
  float* zp   = (float*)(ws + w_off + WZERO_R);
  float* outp = (float*)d_out;

  prep_kernel<<<1144, 256, 0, stream>>>(uk1, uk2, uk3, uk4, w0, w1, w2,
                                        wb1, wb2, wbD, wbE, wb4, wfmlp, zp);

  if (batched){
    mlp_mfma<<<8192, 256, 0, stream>>>(zbuf, ray, wfmlp, fmapB, outp, DT_BS, OUT_BS);
    conv1_mfma<<<8192, 256, 0, stream>>>(fmapB, (const short8*)wb1, e1B, zp, DT_BS, E1_BS);
    conv2_mfma<<<2048, 256, 0, stream>>>(e1B, (const short8*)wb2, dTB, zp, E1_BS, DT_BS);
    conv34_mfma<<<4608, 256, 0, stream>>>(dTB, e1B, (const short8*)wbD, (const short8*)wbE,
                                          (const short8*)wb4, outp, zp, DT_BS, E1_BS, OUT_BS);
  } else {
    for (int b = 0; b < 4; ++b){
      float* outb = outp + (size_t)b*OUT_BS;
      mlp_mfma<<<2048, 256, 0, stream>>>(zbuf + (size_t)b*262144,
                                         ray  + (size_t)b*262144*7,
                                         wfmlp, fmapB, outb, DT_BS, OUT_BS);
      conv1_mfma<<<2048, 256, 0, stream>>>(fmapB, (const short8*)wb1, e1B, zp, DT_BS, E1_BS);
      conv2_mfma<<<512, 256, 0, stream>>>(e1B, (const short8*)wb2, dTB, zp, E1_BS, DT_BS);
      conv34_mfma<<<1152, 256, 0, stream>>>(dTB, e1B, (const short8*)wbD, (const short8*)wbE,
                                            (const short8*)wb4, outb, zp, DT_BS, E1_BS, OUT_BS);
    }
  }
}

// Round 14
// 500.887 us; speedup vs baseline: 2.0383x; 1.0964x over previous
//
#include <hip/hip_runtime.h>
#include <hip/hip_bf16.h>
#include <stdint.h>

typedef __hip_bfloat16 bf16;
typedef __attribute__((ext_vector_type(8))) short short8;
typedef __attribute__((ext_vector_type(4))) float f32x4;
typedef __attribute__((ext_vector_type(16))) float f32x16;
typedef __attribute__((ext_vector_type(8))) _Float16 half8;

__device__ __forceinline__ float bf2f(bf16 x){ return __bfloat162float(x); }
__device__ __forceinline__ bf16  f2bf(float x){ return __float2bfloat16(x); }
__device__ __forceinline__ short f2bfs(float x){ union { bf16 h; short s; } u; u.h = f2bf(x); return u.s; }
__device__ __forceinline__ float bfs2f(short s){ union { bf16 h; short t; } u; u.t = s; return bf2f(u.h); }
__device__ __forceinline__ unsigned short f2hs(float x){ union { _Float16 f; unsigned short u; } c; c.f = (_Float16)x; return c.u; }

// R24: mlp f16-LDS rewrite. h activations stored as f16 in LDS (downstream conv path
// quantizes fmap to bf16 = 2^-8 grain; f16 = 2^-11 is strictly finer -> invisible,
// same argument R22/R23 proved for weights). This removes ALL hi/lo split VALU,
// halves mlp MFMAs 88->44/wave, and shrinks LDS 71.7KB -> 33.3KB -> 4 blocks/CU.
// hbuf [4][32][128] f16 with 8-col-group XOR swizzle (g' = g ^ (row&7)):
// transpose writes 2-way (free), GEMM A-reads perfectly bank-balanced.
// conv1/conv2/conv34/prep byte-identical to R23 (conv34 proven 240us).
// Weight region: wb1|wb2|wbD|wbE|wb4|wfmlp|zpage
#define WB1_R   0UL                          // 9*4*64*8*2      = 36864 B
#define WB2_R   36864UL                      // 2*9*8*64*8*2    = 147456 B
#define WBD_R   184320UL                     // 4*16*4*64*8*2   = 262144 B
#define WBE_R   446464UL                     // 18*4*64*8*2     = 73728 B
#define WB4_R   520192UL                     // 2*9*64*8*2      = 18432 B
#define WMLP_R  538624UL                     // 22528 u16       = 45056 B
#define WZERO_R 583680UL                     // 4096 B zeros -> end 587776
#define W_TOTAL 587776UL
#define DT_BS   8388608UL                    // bf16 elems per batch slot (16 MiB)
#define E1_BS   16777216UL                   // bf16 elems per batch slot (32 MiB)
#define OUT_BS  786432UL                     // f32 elems per batch (3*512*512)

// ---------------- fused prep: wb1|wb2|wbD|wbE|wb4|mlp_frag|zero (element-indexed) ----------------
__global__ void prep_kernel(const float* __restrict__ uk1, const float* __restrict__ uk2,
                            const float* __restrict__ uk3, const float* __restrict__ uk4,
                            const float* __restrict__ w0, const float* __restrict__ w1,
                            const float* __restrict__ w2,
                            short* __restrict__ wb1, short* __restrict__ wb2,
                            short* __restrict__ wbD, short* __restrict__ wbE,
                            short* __restrict__ wb4,
                            unsigned short* __restrict__ wfmlp, float* __restrict__ zp){
  int gidx = blockIdx.x*256 + threadIdx.x;
  if (gidx < 18432){
    int idx = gidx;
    int j = idx & 7, lane = (idx >> 3) & 63, n = (idx >> 9) & 3, t = idx >> 11;
    int co = n*16 + (lane & 15);
    int ci = (lane >> 4)*8 + j;
    float val = (ci < 29) ? uk1[(co*29 + ci)*9 + t] : 0.f;
    wb1[idx] = f2bfs(val);
  } else if (gidx < 92160){
    int idx = gidx - 18432;
    int j    = idx & 7;
    int lane = (idx >> 3) & 63;
    int n    = (idx >> 9) & 7;
    int kt   = idx >> 12;            // ks*9 + t, 0..17
    int t = kt % 9, ks = kt / 9;
    int co = n*16 + (lane & 15);
    int ci = ks*32 + (lane >> 4)*8 + j;
    wb2[idx] = f2bfs(uk2[(co*64 + ci)*9 + t]);
  } else if (gidx < 223232){
    // conv3 D-part parity-folded 2x2 weights (single bf16, summed in f32) [131072 el]
    int idx = gidx - 92160;
    int j    = idx & 7;
    int lane = (idx >> 3) & 63;
    int n    = (idx >> 9) & 3;
    int kD   = (idx >> 11) & 15;
    int par  = idx >> 15;            // 0..3
    int pr = par >> 1, pc = par & 1;
    int jx = kD & 1, jy = (kD >> 1) & 1, ks = (kD >> 2) & 1, c = kD >> 3;
    int co = n*16 + (lane & 15);
    int ci = (c*2 + ks)*32 + (lane >> 4)*8 + j;
    int ty0, ty1, tx0, tx1;
    if (pr == 0){ ty0 = jy ? 1 : 0; ty1 = jy ? 2 : 0; }
    else        { ty0 = jy ? 2 : 0; ty1 = jy ? 2 : 1; }
    if (pc == 0){ tx0 = jx ? 1 : 0; tx1 = jx ? 2 : 0; }
    else        { tx0 = jx ? 2 : 0; tx1 = jx ? 2 : 1; }
    float val = 0.f;
    for (int ty = ty0; ty <= ty1; ++ty)
      for (int tx = tx0; tx <= tx1; ++tx)
        val += uk3[(co*192 + ci)*9 + ty*3 + tx];
    wbD[idx] = f2bfs(val);
  } else if (gidx < 260096){
    // conv3 E-part [36864 el]
    int idx = gidx - 223232;
    int j    = idx & 7;
    int lane = (idx >> 3) & 63;
    int n    = (idx >> 9) & 3;
    int chunk = idx >> 11;           // 0..17 = t*2+ks2
    int ks2 = chunk & 1, t = chunk >> 1;
    int co = n*16 + (lane & 15);
    int ci = 128 + ks2*32 + (lane >> 4)*8 + j;
    wbE[idx] = f2bfs(uk3[(co*192 + ci)*9 + t]);
  } else if (gidx < 269312){
    // conv4 B-frags [9216 el]
    int idx = gidx - 260096;
    int j = idx & 7, lane = (idx >> 3) & 63, rt = idx >> 9;   // rt = kc*9+t
    int t = rt % 9, kc = rt / 9;
    int co = lane & 15;
    int ci = kc*32 + (lane >> 4)*8 + j;
    float val = (co < 3) ? uk4[(co*64 + ci)*9 + t] : 0.f;
    wb4[idx] = f2bfs(val);
  } else if (gidx < 291840){
    // MLP single-f16 B-frags [22528 el]
    int idx = gidx - 269312;
    int j = idx & 7;
    int cl = idx >> 3;
    int lane = cl & 63;
    int chunk = cl >> 6;
    int hi5 = lane >> 5, l31 = lane & 31;
    float val;
    if (chunk < 4){
      int n = chunk;
      int k = hi5*8 + j, co = n*32 + l31;
      val = (k < 6) ? w0[k*128 + co] : 0.f;
    } else if (chunk < 36){
      int c = chunk - 4; int ks = c >> 2, n = c & 3;
      int k = ks*16 + hi5*8 + j, co = n*32 + l31;
      val = w1[k*128 + co];
    } else {
      int ks = chunk - 36;
      int k = ks*16 + hi5*8 + j, co = l31;
      val = w2[k*32 + co];
    }
    union { _Float16 f; unsigned short u; } cv; cv.f = (_Float16)val;
    wfmlp[idx] = cv.u;
  } else if (gidx < 292864){
    zp[gidx - 291840] = 0.f;
  }
}

// ---------------- per-pixel MLP on MFMA: 6 -> 128 -> 128 -> 32 (fmap NHWC-32) ----------------
// h activations f16 in LDS (XOR-swizzled col groups); A-frags read directly as half8.
// 44 MFMAs/wave; LDS 33.3KB -> 4 blocks/CU.
__global__ __launch_bounds__(256,3) void mlp_mfma(
    const float* __restrict__ zbuf, const float* __restrict__ ray,
    const unsigned short* __restrict__ wf,
    bf16* __restrict__ fmap, float* __restrict__ outrgb,
    size_t fmap_bs, size_t out_bs){
  __shared__ __align__(16) unsigned short hsh[4][32][128];  // 32768 B
  __shared__ float zsh[4][32];                              // 512 B
  const int tid = threadIdx.x;
  const int wv = tid >> 6, lane = tid & 63, h5 = lane >> 5, l31 = lane & 31;
  const int mbase = (blockIdx.x*4 + wv)*32;
  const int bz = mbase >> 18;
  const int prel = mbase & 262143;

  const float* rp = ray + (size_t)(mbase + l31)*7;
  float z  = zbuf[mbase + l31];
  float d0 = rp[3], d1 = rp[4], d2 = rp[5];
  float inv = z / rp[6];
  half8 a1 = {};
  if (h5 == 0){
    float f[6] = { rp[0]+d0*inv, rp[1]+d1*inv, rp[2]+d2*inv, d0, d1, d2 };
    #pragma unroll
    for (int j = 0; j < 6; ++j) a1[j] = (_Float16)f[j];
    zsh[wv][l31] = z;
  }

  // swizzled f16 store: row, col -> hsh[wv][row][ (colg^(row&7))*8 + (col&7) ]
  auto hstore = [&](int row, int col, float v){
    int g = (col >> 3) ^ (row & 7);
    hsh[wv][row][g*8 + (col & 7)] = f2hs(v);
  };
  // swizzled half8 A-read: lane reads its row l31, k-group = ks*2+h5
  auto hread = [&](int ks) -> half8 {
    int g = (ks*2 + h5) ^ (l31 & 7);
    return *(const half8*)&hsh[wv][l31][g*8];
  };

  // ---- layer 1 (4 MFMAs)
  f32x16 acc[4];
  #pragma unroll
  for (int n = 0; n < 4; ++n){
    half8 b = *(const half8*)&wf[(n*64 + lane)*8];
    f32x16 a = {};
    acc[n] = __builtin_amdgcn_mfma_f32_32x32x16_f16(a1, b, a, 0, 0, 0);
  }
  #pragma unroll
  for (int n = 0; n < 4; ++n)
    #pragma unroll
    for (int reg = 0; reg < 16; ++reg)
      hstore((reg&3) + 8*(reg>>2) + 4*h5, n*32 + l31, fmaxf(acc[n][reg], 0.f));

  // ---- layer 2 (32 MFMAs)
  f32x16 acc2[4];
  #pragma unroll
  for (int n = 0; n < 4; ++n) acc2[n] = (f32x16){};
  #pragma unroll
  for (int ks = 0; ks < 8; ++ks){
    half8 ah = hread(ks);
    #pragma unroll
    for (int n = 0; n < 4; ++n){
      half8 b = *(const half8*)&wf[((4 + ks*4 + n)*64 + lane)*8];
      acc2[n] = __builtin_amdgcn_mfma_f32_32x32x16_f16(ah, b, acc2[n], 0, 0, 0);
    }
  }
  #pragma unroll
  for (int n = 0; n < 4; ++n)
    #pragma unroll
    for (int reg = 0; reg < 16; ++reg)
      hstore((reg&3) + 8*(reg>>2) + 4*h5, n*32 + l31, fmaxf(acc2[n][reg], 0.f));

  // ---- layer 3 (8 MFMAs)
  f32x16 a3 = {};
  #pragma unroll
  for (int ks = 0; ks < 8; ++ks){
    half8 ah = hread(ks);
    half8 b = *(const half8*)&wf[((36 + ks)*64 + lane)*8];
    a3 = __builtin_amdgcn_mfma_f32_32x32x16_f16(ah, b, a3, 0, 0, 0);
  }

  // ---- store: fmap NHWC-32 (c29..31 zero-padded), rgb residual to out
  bf16* fb = fmap + (size_t)bz*fmap_bs;
  float* ob = outrgb + (size_t)bz*out_bs;
  const int c = l31;
  #pragma unroll
  for (int g = 0; g < 4; ++g){
    const int r0 = 8*g + 4*h5;
    float vs[4];
    #pragma unroll
    for (int k = 0; k < 4; ++k){
      float zz = zsh[wv][r0 + k];
      vs[k] = (zz > 0.f) ? a3[g*4 + k] : 1.0f;
    }
    const size_t p = (size_t)(prel + r0);
    if (c < 29){
      #pragma unroll
      for (int k = 0; k < 4; ++k)
        fb[(p + k)*32 + c] = f2bf(vs[k]);
    } else {
      float4 fv = { vs[0], vs[1], vs[2], vs[3] };
      *(float4*)(&ob[((size_t)(c - 29) << 18) + p]) = fv;
      #pragma unroll
      for (int k = 0; k < 4; ++k)
        fb[(p + k)*32 + c] = f2bf(0.f);
    }
  }
}

// ---------------- conv1 (MFMA): fmap NHWC-32 -> e1T NHWC-64, 3x3 pad1, relu ----------------
__global__ __launch_bounds__(256,2) void conv1_mfma(
    const bf16* __restrict__ fmap32, const short8* __restrict__ wb1,
    bf16* __restrict__ e1T, const float* __restrict__ zpage,
    size_t fmap_bs, size_t e1_bs){
  __shared__ short lds[8192];
  const int tid = threadIdx.x;
  const int wv = tid >> 6, lane = tid & 63;
  const int quad = lane >> 4, l15 = lane & 15;

  const int L = blockIdx.x;
  const int cpx = gridDim.x >> 3;
  const int o = (L & 7)*cpx + (L >> 3);
  const int bx = o & 31;
  const int r2 = o >> 5;
  const int by = r2 & 63;
  const int bz = r2 >> 6;

  const bf16* fb = fmap32 + (size_t)bz*fmap_bs;
  bf16* eb = e1T + (size_t)bz*e1_bs;
  const int oy0 = by*8, ox0 = bx*16;

  for (int r = 0; r < 3; ++r){
    const int d = r*256 + tid;
    const int pairI = d >> 3, slot = d & 7;
    const int sel = slot ^ (pairI & 7);
    const int p = pairI*2 + (sel >> 2);
    const int g = sel & 3;
    const int row = p / 18, col = p - row*18;
    const int gy = oy0 - 1 + row, gx = ox0 - 1 + col;
    const bool ok = (d < 720) && ((unsigned)gy < 512u) && ((unsigned)gx < 512u);
    const void* src = ok
      ? (const void*)&fb[((size_t)((gy<<9) + gx))*32 + g*8]
      : (const void*)zpage;
    __builtin_amdgcn_global_load_lds(
      (const __attribute__((address_space(1))) void*)src,
      (__attribute__((address_space(3))) void*)&lds[d*8],
      16, 0, 0);
  }
  __syncthreads();

  f32x4 acc[2][4];
  #pragma unroll
  for (int i=0;i<2;++i)
    #pragma unroll
    for (int n=0;n<4;++n) acc[i][n] = (f32x4){0.f,0.f,0.f,0.f};

  for (int t = 0; t < 9; ++t){
    const short8* bp = wb1 + (t*4)*64 + lane;
    short8 b0 = bp[0], b1 = bp[64], b2 = bp[128], b3 = bp[192];
    const int dy = t/3, dx = t - dy*3;
    #pragma unroll
    for (int i = 0; i < 2; ++i){
      const int py = wv*2 + i + dy;
      const int px = l15 + dx;
      const int p = py*18 + px;
      const int slot = (quad + 4*(p & 1)) ^ ((p >> 1) & 7);
      short8 a = *(const short8*)&lds[((p >> 1)*8 + slot)*8];
      acc[i][0] = __builtin_amdgcn_mfma_f32_16x16x32_bf16(a, b0, acc[i][0], 0, 0, 0);
      acc[i][1] = __builtin_amdgcn_mfma_f32_16x16x32_bf16(a, b1, acc[i][1], 0, 0, 0);
      acc[i][2] = __builtin_amdgcn_mfma_f32_16x16x32_bf16(a, b2, acc[i][2], 0, 0, 0);
      acc[i][3] = __builtin_amdgcn_mfma_f32_16x16x32_bf16(a, b3, acc[i][3], 0, 0, 0);
    }
  }
  __syncthreads();

  #pragma unroll
  for (int i = 0; i < 2; ++i){
    const int rowp = wv*2 + i;
    #pragma unroll
    for (int n = 0; n < 4; ++n){
      const int gq = n*2 + (l15 >> 3);
      #pragma unroll
      for (int reg = 0; reg < 4; ++reg){
        const int px = rowp*16 + quad*4 + reg;
        const int slot = gq ^ (px & 7);
        lds[(px*8 + slot)*8 + (l15 & 7)] = f2bfs(fmaxf(acc[i][n][reg], 0.f));
      }
    }
  }
  __syncthreads();
  #pragma unroll
  for (int w = 0; w < 4; ++w){
    const int s = w*256 + tid;
    const int px = s >> 3, g8 = s & 7;
    const int slot = g8 ^ (px & 7);
    short8 v = *(const short8*)&lds[(px*8 + slot)*8];
    const int gy = oy0 + (px >> 4), gx = ox0 + (px & 15);
    *(short8*)((void*)&eb[((size_t)((gy<<9) + gx))*64 + g8*8]) = v;
  }
}

// ---------------- conv2 (MFMA): e1T NHWC -> dT NHWC, 3x3 stride2 SAME (pad_lo=0), relu ----------
__global__ __launch_bounds__(256,2) void conv2_mfma(
    const bf16* __restrict__ e1T, const short8* __restrict__ wb2,
    bf16* __restrict__ dT, const float* __restrict__ zpage,
    size_t e1_bs, size_t dt_bs){
  __shared__ short lds[36864];
  const int tid = threadIdx.x;
  const int wv = tid >> 6, lane = tid & 63;
  const int quad = lane >> 4, l15 = lane & 15;

  const int L = blockIdx.x;
  const int cpx = gridDim.x >> 3;
  const int o = (L & 7)*cpx + (L >> 3);
  const int bx = o & 15;
  const int r2 = o >> 4;
  const int by = r2 & 31;
  const int bz = r2 >> 5;

  const bf16* eb = e1T + (size_t)bz*e1_bs;
  bf16* db = dT + (size_t)bz*dt_bs;
  const int oy0 = by*8, ox0 = bx*16;
  const int iy0 = oy0*2, ix0 = ox0*2;

  for (int r = 0; r < 18; ++r){
    const int idx = r*256 + tid;
    const int g = idx & 7, p = idx >> 3;
    const int row = p / 33, col = p - row*33;
    const int gy = iy0 + row, gx = ix0 + col;
    const int gs = g ^ ((col >> 1) & 7);
    const bool ok = (p < 561) && (gy < 512) && (gx < 512);
    const void* src = ok
      ? (const void*)&eb[((size_t)((gy<<9) + gx))*64 + gs*8]
      : (const void*)zpage;
    __builtin_amdgcn_global_load_lds(
      (const __attribute__((address_space(1))) void*)src,
      (__attribute__((address_space(3))) void*)&lds[idx*8],
      16, 0, 0);
  }
  __syncthreads();

  f32x4 acc[2][8];
  #pragma unroll
  for (int i=0;i<2;++i)
    #pragma unroll
    for (int n=0;n<8;++n) acc[i][n] = (f32x4){0.f,0.f,0.f,0.f};

  for (int ks = 0; ks < 2; ++ks){
    const int cg = ks*4 + quad;
    for (int t = 0; t < 9; ++t){
      const short8* bp = wb2 + ((ks*9 + t)*8)*64 + lane;
      short8 b0 = bp[0],   b1 = bp[64],  b2 = bp[128], b3 = bp[192];
      short8 b4 = bp[256], b5 = bp[320], b6 = bp[384], b7 = bp[448];
      const int dy = t/3, dx = t - dy*3;
      #pragma unroll
      for (int i = 0; i < 2; ++i){
        const int m = wv*2 + i;
        const int py = 2*m + dy;
        const int px = 2*l15 + dx;
        const int slot = cg ^ ((px >> 1) & 7);
        short8 a = *(const short8*)&lds[((py*33 + px)*8 + slot)*8];
        acc[i][0] = __builtin_amdgcn_mfma_f32_16x16x32_bf16(a, b0, acc[i][0], 0, 0, 0);
        acc[i][1] = __builtin_amdgcn_mfma_f32_16x16x32_bf16(a, b1, acc[i][1], 0, 0, 0);
        acc[i][2] = __builtin_amdgcn_mfma_f32_16x16x32_bf16(a, b2, acc[i][2], 0, 0, 0);
        acc[i][3] = __builtin_amdgcn_mfma_f32_16x16x32_bf16(a, b3, acc[i][3], 0, 0, 0);
        acc[i][4] = __builtin_amdgcn_mfma_f32_16x16x32_bf16(a, b4, acc[i][4], 0, 0, 0);
        acc[i][5] = __builtin_amdgcn_mfma_f32_16x16x32_bf16(a, b5, acc[i][5], 0, 0, 0);
        acc[i][6] = __builtin_amdgcn_mfma_f32_16x16x32_bf16(a, b6, acc[i][6], 0, 0, 0);
        acc[i][7] = __builtin_amdgcn_mfma_f32_16x16x32_bf16(a, b7, acc[i][7], 0, 0, 0);
      }
    }
  }
  __syncthreads();

  #pragma unroll
  for (int i = 0; i < 2; ++i){
    const int m = wv*2 + i;
    #pragma unroll
    for (int n = 0; n < 8; ++n){
      #pragma unroll
      for (int reg = 0; reg < 4; ++reg){
        const int col = quad*4 + reg;
        const int px = m*16 + col;
        const int g16 = n*2 + (l15 >> 3);
        const int slot = g16 ^ (px & 15);
        lds[(px*16 + slot)*8 + (l15 & 7)] = f2bfs(fmaxf(acc[i][n][reg], 0.f));
      }
    }
  }
  __syncthreads();
  #pragma unroll
  for (int w = 0; w < 8; ++w){
    const int s = w*256 + tid;
    const int px = s >> 4, g16 = s & 15;
    const int slot = g16 ^ (px & 15);
    short8 v = *(const short8*)&lds[(px*16 + slot)*8];
    const int gy = oy0 + (px >> 4), gx = ox0 + (px & 15);
    *(short8*)((void*)&db[((size_t)((gy<<8) + gx))*128 + g16*8]) = v;
  }
}

// ---------------- conv3 (parity-folded D + E) + conv4, all MFMA ----------------
__global__ __launch_bounds__(256,2) void conv34_mfma(
    const bf16* __restrict__ dT, const bf16* __restrict__ e1T,
    const short8* __restrict__ wbD, const short8* __restrict__ wbE,
    const short8* __restrict__ wb4,
    float* __restrict__ out, const float* __restrict__ zpage,
    size_t dt_bs, size_t e1_bs, size_t out_bs){
  __shared__ short lds[39424];   // 78848 B
  const int tid = threadIdx.x;
  const int wv = tid >> 6, lane = tid & 63;
  const int quad = lane >> 4, l15 = lane & 15;

  const int L = blockIdx.x;
  const int cpx = gridDim.x >> 3;              // gridDim.x % 8 == 0 (4608 or 1152)
  const int o = (L & 7)*cpx + (L >> 3);
  const int bx = o % 18;
  const int rem = o / 18;
  const int by = rem & 63;
  const int bz = rem >> 6;

  const bf16* dTb = dT + (size_t)bz*dt_bs;
  const bf16* e1b = e1T + (size_t)bz*e1_bs;
  float* outb = out + (size_t)bz*out_bs;
  const int gy0 = by * 8;
  const int gx0 = bx * 30;
  const int dy0 = (gy0 >> 1) - 1;
  const int dx0 = (gx0 >> 1) - 1;
  const int rm0 = (wv >> 1) ^ 1;
  const int mx0 = (wv & 1) ^ 1;
  f32x4 acc[5][4];
  #pragma unroll
  for (int i=0;i<5;++i)
    #pragma unroll
    for (int n=0;n<4;++n) acc[i][n] = (f32x4){0.f,0.f,0.f,0.f};

  short* DB0 = lds;
  short* DB1 = lds + 6656;
  short* EB  = lds + 13312;

  auto stage_dT = [&](int c, short* db){
    #pragma unroll
    for (int r = 0; r < 4; ++r){
      const int idxb = r*256 + wv*64;
      if (idxb >= 832) continue;
      const int idx = idxb + lane;
      const int p = idx >> 3, g = idx & 7;
      const int prow = p / 17, pcol = p - prow*17;
      const int gyD = dy0 + prow, gxD = dx0 + pcol;
      const int gs = g ^ (pcol & 7);
      const bool ok = (p < 102) && ((unsigned)gyD < 256u) && ((unsigned)gxD < 256u);
      const void* src = ok
        ? (const void*)&dTb[((size_t)((gyD<<8) + gxD))*128 + c*64 + gs*8]
        : (const void*)zpage;
      __builtin_amdgcn_global_load_lds(
        (const __attribute__((address_space(1))) void*)src,
        (__attribute__((address_space(3))) void*)&db[idxb*8],
        16, 0, 0);
    }
  };

  auto stage_E = [&](short* eb){
    #pragma unroll
    for (int r = 0; r < 13; ++r){
      const int idxb = r*256 + wv*64;
      if (idxb >= 3264) continue;
      const int idx = idxb + lane;
      const int g = idx & 7, pos = idx >> 3;
      const int yy = pos / 34, xx = pos - yy*34;
      const int gy = gy0 - 2 + yy, gx = gx0 - 2 + xx;
      const int sg = g ^ ((xx >> 1) & 7);
      const bool ok = ((unsigned)gy < 512u) && ((unsigned)gx < 512u);
      const int pyc = gy & 511, pxc = gx & 511;
      const void* src = ok
        ? (const void*)&e1b[((size_t)((pyc<<9) + pxc))*64 + sg*8]
        : (const void*)zpage;
      __builtin_amdgcn_global_load_lds(
        (const __attribute__((address_space(1))) void*)src,
        (__attribute__((address_space(3))) void*)&eb[idxb*8],
        16, 0, 0);
    }
  };

  auto compute_Dc = [&](int c, const short* db){
    #pragma unroll
    for (int ks = 0; ks < 2; ++ks){
      #pragma unroll
      for (int jy = 0; jy < 2; ++jy){
        #pragma unroll
        for (int jx = 0; jx < 2; ++jx){
          const int kD = ((c*2 + ks)*2 + jy)*2 + jx;
          const short8* bp = wbD + ((size_t)(wv*16 + kD)*4)*64 + lane;
          short8 b0 = bp[0], b1 = bp[64], b2 = bp[128], b3 = bp[192];
          const int pcol = l15 + jx;
          const int g = (ks*4 + quad) ^ (pcol & 7);
          #pragma unroll
          for (int i = 0; i < 5; ++i){
            short8 a = *(const short8*)&db[((i + jy)*17 + pcol)*64 + g*8];
            acc[i][0] = __builtin_amdgcn_mfma_f32_16x16x32_bf16(a, b0, acc[i][0], 0, 0, 0);
            acc[i][1] = __builtin_amdgcn_mfma_f32_16x16x32_bf16(a, b1, acc[i][1], 0, 0, 0);
            acc[i][2] = __builtin_amdgcn_mfma_f32_16x16x32_bf16(a, b2, acc[i][2], 0, 0, 0);
            acc[i][3] = __builtin_amdgcn_mfma_f32_16x16x32_bf16(a, b3, acc[i][3], 0, 0, 0);
          }
        }
      }
    }
  };

  auto compute_E = [&](const short* eb){
    for (int t = 0; t < 9; ++t){
      const int dy = t/3, dx = t - dy*3;
      #pragma unroll
      for (int ks2 = 0; ks2 < 2; ++ks2){
        const short8* bp = wbE + ((size_t)((t*2 + ks2)*4))*64 + lane;
        short8 b0 = bp[0], b1 = bp[64], b2 = bp[128], b3 = bp[192];
        const int px = 2*l15 + mx0 + dx;
        const int g = (ks2*4 + quad) ^ ((px >> 1) & 7);
        #pragma unroll
        for (int i = 0; i < 5; ++i){
          const int row = 2*i + rm0 + dy;
          short8 a = *(const short8*)&eb[(row*34 + px)*64 + g*8];
          acc[i][0] = __builtin_amdgcn_mfma_f32_16x16x32_bf16(a, b0, acc[i][0], 0, 0, 0);
          acc[i][1] = __builtin_amdgcn_mfma_f32_16x16x32_bf16(a, b1, acc[i][1], 0, 0, 0);
          acc[i][2] = __builtin_amdgcn_mfma_f32_16x16x32_bf16(a, b2, acc[i][2], 0, 0, 0);
          acc[i][3] = __builtin_amdgcn_mfma_f32_16x16x32_bf16(a, b3, acc[i][3], 0, 0, 0);
        }
      }
    }
  };

  stage_dT(0, DB0);
  __syncthreads();

  stage_dT(1, DB1);
  __builtin_amdgcn_sched_barrier(0);
  compute_Dc(0, DB0);
  __syncthreads();

  stage_E(EB);
  __builtin_amdgcn_sched_barrier(0);
  compute_Dc(1, DB1);
  __syncthreads();

  compute_E(EB);

  __syncthreads();   // staging dead -> msh[10][32][64] (swizzled groups)
  #pragma unroll
  for (int i = 0; i < 5; ++i){
    const int r = 2*i + rm0;
    const int gym = gy0 - 1 + r;
    #pragma unroll
    for (int reg = 0; reg < 4; ++reg){
      const int mxd = 2*(quad*4 + reg) + mx0;
      const int gxm = gx0 - 1 + mxd;
      const bool inim = ((unsigned)gym < 512u) && ((unsigned)gxm < 512u);
      const int key = (mxd & 7) << 3;
      #pragma unroll
      for (int n = 0; n < 4; ++n){
        float v = inim ? fmaxf(acc[i][n][reg], 0.f) : 0.f;
        int c = n*16 + l15;
        lds[(r*32 + mxd)*64 + (c ^ key)] = f2bfs(v);
      }
    }
  }
  __syncthreads();

  // conv4 on MFMA (single bf16 weights): wave wv owns M-tiles {wv*4..wv*4+3}
  f32x4 a4[4];
  #pragma unroll
  for (int ii = 0; ii < 4; ++ii) a4[ii] = (f32x4){0.f,0.f,0.f,0.f};
  for (int kc = 0; kc < 2; ++kc){
    for (int t = 0; t < 9; ++t){
      short8 b = wb4[(kc*9 + t)*64 + lane];
      const int dy = t/3, dx = t - dy*3;
      #pragma unroll
      for (int ii = 0; ii < 4; ++ii){
        const int mt4 = wv*4 + ii;
        const int ly = mt4 >> 1, h = mt4 & 1;
        const int r = ly + dy;
        const int mxd = h*16 + l15 + dx;       // cols >31 read stale LDS; masked at store
        const int sg = (kc*4 + quad) ^ (mxd & 7);
        short8 a = *(const short8*)&lds[(r*32 + mxd)*64 + sg*8];
        a4[ii] = __builtin_amdgcn_mfma_f32_16x16x32_bf16(a, b, a4[ii], 0, 0, 0);
      }
    }
  }
  if (l15 < 3){
    #pragma unroll
    for (int ii = 0; ii < 4; ++ii){
      const int mt4 = wv*4 + ii;
      const int ly = mt4 >> 1, h = mt4 & 1;
      const int oy = gy0 + ly;
      float* op = outb + (((size_t)l15) << 18) + ((size_t)oy << 9);
      #pragma unroll
      for (int reg = 0; reg < 4; ++reg){
        const int lx = h*16 + quad*4 + reg;
        const int ox = gx0 + lx;
        if (lx < 30 && ox < 512)
          op[ox] += a4[ii][reg];
      }
    }
  }
}

static const void* find_by_size(void* const* d_in, const int* in_sizes, int n_in,
                                int want, int occurrence, int fallback_idx){
  int seen = 0;
  for (int i = 0; i < n_in; ++i){
    if (in_sizes[i] == want){
      if (seen == occurrence) return d_in[i];
      ++seen;
    }
  }
  return d_in[fallback_idx];
}

extern "C" void kernel_launch(void* const* d_in, const int* in_sizes, int n_in,
                              void* d_out, int out_size, void* d_ws, size_t ws_size,
                              hipStream_t stream) {
  const float* zbuf = (const float*)find_by_size(d_in, in_sizes, n_in, 1048576, 0, 0);
  const float* ray  = (const float*)find_by_size(d_in, in_sizes, n_in, 7340032, 0, 1);
  const float* w0   = (const float*)find_by_size(d_in, in_sizes, n_in, 768,     0, 4);
  const float* w1   = (const float*)find_by_size(d_in, in_sizes, n_in, 16384,   0, 6);
  const float* w2   = (const float*)find_by_size(d_in, in_sizes, n_in, 4096,    0, 8);
  const float* uk1  = (const float*)find_by_size(d_in, in_sizes, n_in, 16704,   0, 10);
  const float* uk2  = (const float*)find_by_size(d_in, in_sizes, n_in, 73728,   0, 11);
  const float* uk3  = (const float*)find_by_size(d_in, in_sizes, n_in, 110592,  0, 12);
  const float* uk4  = (const float*)find_by_size(d_in, in_sizes, n_in, 1728,    0, 13);

  uint8_t* ws = (uint8_t*)d_ws;
  const int batched = (ws_size >= 0xC000000UL + W_TOTAL);
  const size_t dt_off = 0;
  const size_t e1_off = batched ? 0x4000000UL : 0x1000000UL;
  const size_t w_off  = batched ? 0xC000000UL : 0x3000000UL;

  bf16* fmapB = (bf16*)(ws + dt_off);      // fmap32 NHWC overlays dT slots
  bf16* dTB   = (bf16*)(ws + dt_off);
  bf16* e1B   = (bf16*)(ws + e1_off);
  short* wb1  = (short*)(ws + w_off + WB1_R);
  short* wb2  = (short*)(ws + w_off + WB2_R);
  short* wbD  = (short*)(ws + w_off + WBD_R);
  short* wbE  = (short*)(ws + w_off + WBE_R);
  short* wb4  = (short*)(ws + w_off + WB4_R);
  unsigned short* wfmlp = (unsigned short*)(ws + w_off + WMLP_R);
  float* zp   = (float*)(ws + w_off + WZERO_R);
  float* outp = (float*)d_out;

  prep_kernel<<<1144, 256, 0, stream>>>(uk1, uk2, uk3, uk4, w0, w1, w2,
                                        wb1, wb2, wbD, wbE, wb4, wfmlp, zp);

  if (batched){
    mlp_mfma<<<8192, 256, 0, stream>>>(zbuf, ray, wfmlp, fmapB, outp, DT_BS, OUT_BS);
    conv1_mfma<<<8192, 256, 0, stream>>>(fmapB, (const short8*)wb1, e1B, zp, DT_BS, E1_BS);
    conv2_mfma<<<2048, 256, 0, stream>>>(e1B, (const short8*)wb2, dTB, zp, E1_BS, DT_BS);
    conv34_mfma<<<4608, 256, 0, stream>>>(dTB, e1B, (const short8*)wbD, (const short8*)wbE,
                                          (const short8*)wb4, outp, zp, DT_BS, E1_BS, OUT_BS);
  } else {
    for (int b = 0; b < 4; ++b){
      float* outb = outp + (size_t)b*OUT_BS;
      mlp_mfma<<<2048, 256, 0, stream>>>(zbuf + (size_t)b*262144,
                                         ray  + (size_t)b*262144*7,
                                         wfmlp, fmapB, outb, DT_BS, OUT_BS);
      conv1_mfma<<<2048, 256, 0, stream>>>(fmapB, (const short8*)wb1, e1B, zp, DT_BS, E1_BS);
      conv2_mfma<<<512, 256, 0, stream>>>(e1B, (const short8*)wb2, dTB, zp, E1_BS, DT_BS);
      conv34_mfma<<<1152, 256, 0, stream>>>(dTB, e1B, (const short8*)wbD, (const short8*)wbE,
                                            (const short8*)wb4, outb, zp, DT_BS, E1_BS, OUT_BS);
    }
  }
}